// Round 10
// baseline (1681.634 us; speedup 1.0000x reference)
//
#include <hip/hip_runtime.h>

#define WAVE 64
#define CDIV(a,b) (((a)+(b)-1)/(b))

typedef float f32x16 __attribute__((ext_vector_type(16)));
typedef unsigned short u16x8 __attribute__((ext_vector_type(8)));

// ---------- bf16 helpers: hi = truncate, lo = rne(residual) ----------
__device__ __forceinline__ unsigned short f2bf_rne(float f) {
    unsigned u = __float_as_uint(f);
    unsigned r = (u + 0x7FFFu + ((u >> 16) & 1u)) >> 16;
    return (unsigned short)r;
}
__device__ __forceinline__ float bf2f(unsigned short h) {
    return __uint_as_float(((unsigned)h) << 16);
}
__device__ __forceinline__ float4 bf42f(ushort4 u) {
    float4 r; r.x = bf2f(u.x); r.y = bf2f(u.y); r.z = bf2f(u.z); r.w = bf2f(u.w); return r;
}
__device__ __forceinline__ ushort4 f2bf4(float4 v) {
    ushort4 r; r.x = f2bf_rne(v.x); r.y = f2bf_rne(v.y); r.z = f2bf_rne(v.z); r.w = f2bf_rne(v.w);
    return r;
}
__device__ __forceinline__ void split4(float4 o, ushort4& h, ushort4& l) {
    unsigned ux = __float_as_uint(o.x), uy = __float_as_uint(o.y);
    unsigned uz = __float_as_uint(o.z), uw = __float_as_uint(o.w);
    h.x = (unsigned short)(ux >> 16); h.y = (unsigned short)(uy >> 16);
    h.z = (unsigned short)(uz >> 16); h.w = (unsigned short)(uw >> 16);
    l.x = f2bf_rne(o.x - bf2f(h.x)); l.y = f2bf_rne(o.y - bf2f(h.y));
    l.z = f2bf_rne(o.z - bf2f(h.z)); l.w = f2bf_rne(o.w - bf2f(h.w));
}
__device__ __forceinline__ float sigm(float x) { return 1.0f / (1.0f + expf(-x)); }

#define FMA4(acc, wgt, v) { acc.x += (wgt)*(v).x; acc.y += (wgt)*(v).y; \
                            acc.z += (wgt)*(v).z; acc.w += (wgt)*(v).w; }
#define DOT4(a, b) ((a).x*(b).x + (a).y*(b).y + (a).z*(b).z + (a).w*(b).w)

#define MFMA32(acc, a, b) \
    asm volatile("v_mfma_f32_32x32x16_bf16 %0, %1, %2, %0" : "+v"(acc) : "v"(a), "v"(b))

// ---------- monotonic float<->uint encoding for atomicMax on floats ----------
__device__ __forceinline__ unsigned f2mono(float f) {
    unsigned u = __float_as_uint(f);
    return (u & 0x80000000u) ? ~u : (u | 0x80000000u);
}
__device__ __forceinline__ float mono2f(unsigned u) {
    return (u & 0x80000000u) ? __uint_as_float(u & 0x7fffffffu) : __uint_as_float(~u);
}
__device__ __forceinline__ float leaky(float v) { return (v > 0.0f) ? v : 0.01f*v; }

// fragment-pack offset: matrix row r, col k -> packed short index.
__device__ __forceinline__ long fragoff(long r, int k, int npk) {
    return ((r >> 5) * (long)npk + (k >> 4)) * 512
         + (((k >> 3) & 1) << 8) + ((r & 31) << 3) + (k & 7);
}

// =========================================================================
// k_cvt_pack: f32 [rows][K] (stride ld) -> fragment-packed bf16 hi/lo at
// packed-row offset roff. k-pad (K..npk*16) zeroed.
// =========================================================================
__global__ void k_cvt_pack(const float* __restrict__ src, long ld, int rows, int K, int npk,
                           int roff,
                           unsigned short* __restrict__ hi, unsigned short* __restrict__ lo)
{
    int nc4 = npk << 2;
    long idx = (long)blockIdx.x*blockDim.x + threadIdx.x;
    if (idx >= (long)rows * nc4) return;
    long r = idx / nc4; int k = (int)(idx % nc4) << 2;
    float4 v = {0.0f, 0.0f, 0.0f, 0.0f};
    if (k + 4 <= K) v = *(const float4*)(src + r*ld + k);
    ushort4 h, l;
    split4(v, h, l);
    long off = fragoff(r + roff, k, npk);
    *(ushort4*)(hi + off) = h;
    *(ushort4*)(lo + off) = l;
}

// =========================================================================
// k_gemm_frag: C[M,620] (bf16) = A * B^T on fragment-packed bf16 hi/lo.
// NO LDS, NO barriers. XCD-ownership swizzle: lin%8 = XCD, each XCD owns
// whole row-panels and runs their 5 col-blocks back-to-back -> A panel
// stays in that XCD's L2, fetched from HBM once.
// Block 256 thr = 4 waves; wave = 32 rows x 128 cols.
// bf16x3: AhBh + AlBh + AhBl (~fp32 accuracy, bf16-rounded out).
// =========================================================================
__global__ __launch_bounds__(256, 3)
void k_gemm_frag(const unsigned short* __restrict__ Ahi, const unsigned short* __restrict__ Alo,
                 const unsigned short* __restrict__ Bhi, const unsigned short* __restrict__ Blo,
                 unsigned short* __restrict__ C, long ldc, int M, int N, int nk, int nrb)
{
    const int lane = threadIdx.x & 63;
    const int wid  = threadIdx.x >> 6;
    const int lin  = blockIdx.x;
    const int xcd  = lin & 7;
    const int m    = lin >> 3;
    const int col0 = (m % 5) * 128;
    const int rb   = xcd + ((m / 5) << 3);
    if (rb >= nrb) return;
    const int row0 = rb * 128 + wid * 32;

    const long cs = (long)nk * 512;                 // tile-row stride (shorts)
    const unsigned short* pAh = Ahi + (long)(row0 >> 5) * cs + lane * 8;
    const unsigned short* pAl = Alo + (long)(row0 >> 5) * cs + lane * 8;
    const unsigned short* pBh = Bhi + (long)(col0 >> 5) * cs + lane * 8;
    const unsigned short* pBl = Blo + (long)(col0 >> 5) * cs + lane * 8;

    f32x16 acc[4];
    #pragma unroll
    for (int c = 0; c < 4; ++c) acc[c] = (f32x16)0.0f;

    u16x8 pah, pal, pb0, pb1, pb2, pb3, pl0, pl1, pl2, pl3;
    u16x8 qah, qal, qb0, qb1, qb2, qb3, ql0, ql1, ql2, ql3;

    #define LOADP(t_) { long o = (long)(t_)*512;                                   \
        pah = *(const u16x8*)(pAh + o);        pal = *(const u16x8*)(pAl + o);     \
        pb0 = *(const u16x8*)(pBh + o);        pl0 = *(const u16x8*)(pBl + o);     \
        pb1 = *(const u16x8*)(pBh + cs + o);   pl1 = *(const u16x8*)(pBl + cs + o);\
        pb2 = *(const u16x8*)(pBh + 2*cs + o); pl2 = *(const u16x8*)(pBl + 2*cs + o);\
        pb3 = *(const u16x8*)(pBh + 3*cs + o); pl3 = *(const u16x8*)(pBl + 3*cs + o); }
    #define LOADQ(t_) { long o = (long)(t_)*512;                                   \
        qah = *(const u16x8*)(pAh + o);        qal = *(const u16x8*)(pAl + o);     \
        qb0 = *(const u16x8*)(pBh + o);        ql0 = *(const u16x8*)(pBl + o);     \
        qb1 = *(const u16x8*)(pBh + cs + o);   ql1 = *(const u16x8*)(pBl + cs + o);\
        qb2 = *(const u16x8*)(pBh + 2*cs + o); ql2 = *(const u16x8*)(pBl + 2*cs + o);\
        qb3 = *(const u16x8*)(pBh + 3*cs + o); ql3 = *(const u16x8*)(pBl + 3*cs + o); }
    #define STEPP {                                                                 \
        MFMA32(acc[0], pah, pb0); MFMA32(acc[1], pah, pb1);                         \
        MFMA32(acc[2], pah, pb2); MFMA32(acc[3], pah, pb3);                         \
        MFMA32(acc[0], pal, pb0); MFMA32(acc[1], pal, pb1);                         \
        MFMA32(acc[2], pal, pb2); MFMA32(acc[3], pal, pb3);                         \
        MFMA32(acc[0], pah, pl0); MFMA32(acc[1], pah, pl1);                         \
        MFMA32(acc[2], pah, pl2); MFMA32(acc[3], pah, pl3); }
    #define STEPQ {                                                                 \
        MFMA32(acc[0], qah, qb0); MFMA32(acc[1], qah, qb1);                         \
        MFMA32(acc[2], qah, qb2); MFMA32(acc[3], qah, qb3);                         \
        MFMA32(acc[0], qal, qb0); MFMA32(acc[1], qal, qb1);                         \
        MFMA32(acc[2], qal, qb2); MFMA32(acc[3], qal, qb3);                         \
        MFMA32(acc[0], qah, ql0); MFMA32(acc[1], qah, ql1);                         \
        MFMA32(acc[2], qah, ql2); MFMA32(acc[3], qah, ql3); }

    LOADP(0);
    int t = 0;
    for (;;) {
        bool m1 = (t + 1 < nk);
        if (m1) LOADQ(t + 1);
        STEPP;
        if (!m1) break;
        bool m2 = (t + 2 < nk);
        if (m2) LOADP(t + 2);
        STEPQ;
        if (!m2) break;
        t += 2;
    }
    #undef LOADP
    #undef LOADQ
    #undef STEPP
    #undef STEPQ

    const int crow0 = row0 + 4*(lane >> 5);
    const int ccol0 = col0 + (lane & 31);
    #pragma unroll
    for (int c = 0; c < 4; ++c) {
        int col = ccol0 + c*32;
        if (col >= N) continue;
        #pragma unroll
        for (int reg = 0; reg < 16; ++reg) {
            int row = crow0 + (reg & 3) + 8*(reg >> 2);
            if (row < M) C[(long)row*ldc + col] = f2bf_rne(acc[c][reg]);
        }
    }
}

// ---------- small f32 GEMM (tiny R x RH highway gate) ----------
#define GBM 64
#define GBN 64
#define GBK 16
__global__ __launch_bounds__(256)
void k_gemm(const float* __restrict__ A, long lda,
            const float* __restrict__ B, long ldb,
            float* __restrict__ C, long ldc,
            int M, int N, int K)
{
    __shared__ float As[GBK][GBM + 4];
    __shared__ float Bs[GBK][GBN + 4];
    const int tid = threadIdx.x;
    const int tx = tid & 15, ty = tid >> 4;
    const int row0 = blockIdx.y * GBM, col0 = blockIdx.x * GBN;
    float acc[4][4] = {};
    for (int kt = 0; kt < K; kt += GBK) {
        #pragma unroll
        for (int p = 0; p < 4; ++p) {
            int mn = (tid >> 4) + p * 16;
            int k  = tid & 15;
            int gk = kt + k;
            int gr = row0 + mn;
            As[k][mn] = (gr < M && gk < K) ? A[(long)gr * lda + gk] : 0.0f;
            int gc = col0 + mn;
            Bs[k][mn] = (gc < N && gk < K) ? B[(long)gc * ldb + gk] : 0.0f;
        }
        __syncthreads();
        #pragma unroll
        for (int kk = 0; kk < GBK; ++kk) {
            float a0 = As[kk][ty*4+0], a1 = As[kk][ty*4+1];
            float a2 = As[kk][ty*4+2], a3 = As[kk][ty*4+3];
            float b0 = Bs[kk][tx*4+0], b1 = Bs[kk][tx*4+1];
            float b2 = Bs[kk][tx*4+2], b3 = Bs[kk][tx*4+3];
            acc[0][0] += a0*b0; acc[0][1] += a0*b1; acc[0][2] += a0*b2; acc[0][3] += a0*b3;
            acc[1][0] += a1*b0; acc[1][1] += a1*b1; acc[1][2] += a1*b2; acc[1][3] += a1*b3;
            acc[2][0] += a2*b0; acc[2][1] += a2*b1; acc[2][2] += a2*b2; acc[2][3] += a2*b3;
            acc[3][0] += a3*b0; acc[3][1] += a3*b1; acc[3][2] += a3*b2; acc[3][3] += a3*b3;
        }
        __syncthreads();
    }
    #pragma unroll
    for (int i2 = 0; i2 < 4; ++i2)
        #pragma unroll
        for (int j2 = 0; j2 < 4; ++j2) {
            int r = row0 + ty*4 + i2, c = col0 + tx*4 + j2;
            if (r < M && c < N) C[(long)r*ldc + c] = acc[i2][j2];
        }
}

// ================= CSR build: histogram -> scan -> fill =================
__global__ void k_hist(const int* __restrict__ key, int* __restrict__ cnt, int E) {
    int e = blockIdx.x*blockDim.x + threadIdx.x;
    if (e < E) atomicAdd(&cnt[key[e]], 1);
}
__global__ void k_scan1(const int* __restrict__ in, int* __restrict__ out,
                        int* __restrict__ bsum, int n) {
    __shared__ int sh[256];
    int gid = blockIdx.x*256 + threadIdx.x;
    int v = (gid < n) ? in[gid] : 0;
    sh[threadIdx.x] = v; __syncthreads();
    for (int o = 1; o < 256; o <<= 1) {
        int t = (threadIdx.x >= o) ? sh[threadIdx.x - o] : 0;
        __syncthreads();
        sh[threadIdx.x] += t;
        __syncthreads();
    }
    if (gid < n) out[gid] = sh[threadIdx.x] - v;      // exclusive
    if (threadIdx.x == 255) bsum[blockIdx.x] = sh[255];
}
__global__ void k_scan2(int* __restrict__ bsum, int nb) {   // single block, nb <= 1024
    __shared__ int sh[1024];
    int v = (threadIdx.x < nb) ? bsum[threadIdx.x] : 0;
    sh[threadIdx.x] = v; __syncthreads();
    for (int o = 1; o < 1024; o <<= 1) {
        int t = (threadIdx.x >= o) ? sh[threadIdx.x - o] : 0;
        __syncthreads();
        sh[threadIdx.x] += t;
        __syncthreads();
    }
    if (threadIdx.x < nb) bsum[threadIdx.x] = sh[threadIdx.x] - v;  // exclusive
}
__global__ void k_scan3(int* __restrict__ out, const int* __restrict__ bsum, int n) {
    int gid = blockIdx.x*256 + threadIdx.x;
    if (gid < n) out[gid] += bsum[blockIdx.x];
}
__global__ void k_fill(const int* __restrict__ key, const int* __restrict__ rowptr,
                       int* __restrict__ cursor, int* __restrict__ perm, int E) {
    int e = blockIdx.x*blockDim.x + threadIdx.x;
    if (e >= E) return;
    int k = key[e];
    int p = rowptr[k] + atomicAdd(&cursor[k], 1);
    perm[p] = e;
}
__global__ void k_dinv_cnt(const int* __restrict__ cnt, float* __restrict__ dinv, int n) {
    int i = blockIdx.x*blockDim.x + threadIdx.x;
    if (i < n) { int c = cnt[i]; dinv[i] = (c > 0) ? rsqrtf((float)c) : 0.0f; }
}

// ---------- CSR-order pre-permutation ----------
__global__ void k_prep_gcn(const int* __restrict__ perm, const int* __restrict__ jA,
                           const int* __restrict__ iA, const float* __restrict__ dinv,
                           int* __restrict__ jp, float* __restrict__ nm, int E) {
    int p = blockIdx.x*blockDim.x + threadIdx.x;
    if (p >= E) return;
    int e = perm[p];
    int j = jA[e];
    jp[p] = j;
    nm[p] = dinv[iA[e]] * dinv[j];
}
__global__ void k_permute_i32(const int* __restrict__ src, const int* __restrict__ perm,
                              int* __restrict__ dst, int E) {
    int p = blockIdx.x*blockDim.x + threadIdx.x;
    if (p < E) dst[p] = src[perm[p]];
}
__global__ void k_permute_mod(const int* __restrict__ src, const int* __restrict__ perm,
                              int* __restrict__ dst, int E, int mod) {
    int p = blockIdx.x*blockDim.x + threadIdx.x;
    if (p < E) dst[p] = src[perm[p]] % mod;
}

// =========================================================================
// k_gather_hw: fused GCN gather (bf16 src, ushort4-wide) + relu + highway
// + extras. Chunk0 = cols 4*lane (0..255, all lanes); chunk1 = cols
// 256+4*lane (lane<11 -> 256..299).
// =========================================================================
__global__ void k_gather_hw(const unsigned short* __restrict__ xg, long ldx,
                            const unsigned short* __restrict__ gl,
                            const float* __restrict__ x1, long ld1,
                            const float* __restrict__ bias,
                            const int* __restrict__ jp, const float* __restrict__ nm,
                            const int* __restrict__ rowptr, const int* __restrict__ cnt,
                            float* __restrict__ out, long ldo,
                            unsigned short* __restrict__ hi, unsigned short* __restrict__ lo,
                            unsigned short* __restrict__ xbf,
                            const float* __restrict__ ai, const float* __restrict__ aj,
                            float* __restrict__ sa, float* __restrict__ sb,
                            int npk, int n)
{
    int w = (blockIdx.x*blockDim.x + threadIdx.x) >> 6;
    int lane = threadIdx.x & 63;
    if (w >= n) return;
    int beg = rowptr[w], end = beg + cnt[w];
    const bool t1 = (lane < 11);
    float4 a0 = {0,0,0,0}, a1 = {0,0,0,0};
    int e = beg;
    for (; e + 4 <= end; e += 4) {
        long j0 = jp[e], j1 = jp[e+1], j2 = jp[e+2], j3 = jp[e+3];
        float w0 = nm[e], w1 = nm[e+1], w2 = nm[e+2], w3 = nm[e+3];
        float4 v;
        v = bf42f(((const ushort4*)(xg + j0*ldx))[lane]); FMA4(a0, w0, v);
        v = bf42f(((const ushort4*)(xg + j1*ldx))[lane]); FMA4(a0, w1, v);
        v = bf42f(((const ushort4*)(xg + j2*ldx))[lane]); FMA4(a0, w2, v);
        v = bf42f(((const ushort4*)(xg + j3*ldx))[lane]); FMA4(a0, w3, v);
        if (t1) {
            v = bf42f(((const ushort4*)(xg + j0*ldx + 256))[lane]); FMA4(a1, w0, v);
            v = bf42f(((const ushort4*)(xg + j1*ldx + 256))[lane]); FMA4(a1, w1, v);
            v = bf42f(((const ushort4*)(xg + j2*ldx + 256))[lane]); FMA4(a1, w2, v);
            v = bf42f(((const ushort4*)(xg + j3*ldx + 256))[lane]); FMA4(a1, w3, v);
        }
    }
    for (; e < end; ++e) {
        long j0 = jp[e]; float w0 = nm[e];
        float4 v = bf42f(((const ushort4*)(xg + j0*ldx))[lane]); FMA4(a0, w0, v);
        if (t1) { v = bf42f(((const ushort4*)(xg + j0*ldx + 256))[lane]); FMA4(a1, w0, v); }
    }
    // highway: o = sig(gl+b)*relu(acc) + (1-sig)*x1
    float4 o0, o1 = {0,0,0,0};
    {
        float4 gv = bf42f(((const ushort4*)(gl + (long)w*ldx))[lane]);
        float4 xv = ((const float4*)(x1 + (long)w*ld1))[lane];
        float4 bv = ((const float4*)bias)[lane];
        float g;
        g = sigm(gv.x + bv.x); o0.x = g*fmaxf(a0.x,0.0f) + (1.0f-g)*xv.x;
        g = sigm(gv.y + bv.y); o0.y = g*fmaxf(a0.y,0.0f) + (1.0f-g)*xv.y;
        g = sigm(gv.z + bv.z); o0.z = g*fmaxf(a0.z,0.0f) + (1.0f-g)*xv.z;
        g = sigm(gv.w + bv.w); o0.w = g*fmaxf(a0.w,0.0f) + (1.0f-g)*xv.w;
        ((float4*)(out + (long)w*ldo))[lane] = o0;
    }
    if (t1) {
        float4 gv = bf42f(((const ushort4*)(gl + (long)w*ldx + 256))[lane]);
        float4 xv = ((const float4*)(x1 + (long)w*ld1 + 256))[lane];
        float4 bv = ((const float4*)(bias + 256))[lane];
        float g;
        g = sigm(gv.x + bv.x); o1.x = g*fmaxf(a1.x,0.0f) + (1.0f-g)*xv.x;
        g = sigm(gv.y + bv.y); o1.y = g*fmaxf(a1.y,0.0f) + (1.0f-g)*xv.y;
        g = sigm(gv.z + bv.z); o1.z = g*fmaxf(a1.z,0.0f) + (1.0f-g)*xv.z;
        g = sigm(gv.w + bv.w); o1.w = g*fmaxf(a1.w,0.0f) + (1.0f-g)*xv.w;
        ((float4*)(out + (long)w*ldo + 256))[lane] = o1;
    }
    if (hi) {   // fragment-pack o as bf16 hi/lo for the next GEMM's A
        ushort4 h4, l4;
        split4(o0, h4, l4);
        long off = fragoff(w, 4*lane, npk);
        *(ushort4*)(hi + off) = h4; *(ushort4*)(lo + off) = l4;
        if (t1) {
            split4(o1, h4, l4);
            off = fragoff(w, 256 + 4*lane, npk);
            *(ushort4*)(hi + off) = h4; *(ushort4*)(lo + off) = l4;
        } else if (lane == 11) {   // zero-fill pad cols 300..303
            long offp = fragoff(w, 300, npk);
            ushort4 z = {0,0,0,0};
            *(ushort4*)(hi + offp) = z; *(ushort4*)(lo + offp) = z;
        }
    }
    if (xbf) {  // row-major bf16 copy (stride 304 shorts) for GAT gather
        ((ushort4*)(xbf + (long)w*304))[lane] = f2bf4(o0);
        if (t1) ((ushort4*)(xbf + (long)w*304 + 256))[lane] = f2bf4(o1);
    }
    if (sa) {   // GAT score dots: sa[w] = o·ai, sb[w] = o·aj
        float4 A0 = ((const float4*)ai)[lane];
        float4 J0 = ((const float4*)aj)[lane];
        float sva = DOT4(o0, A0);
        float svb = DOT4(o0, J0);
        if (t1) {
            float4 A1 = ((const float4*)(ai + 256))[lane];
            float4 J1 = ((const float4*)(aj + 256))[lane];
            sva += DOT4(o1, A1);
            svb += DOT4(o1, J1);
        }
        #pragma unroll
        for (int o = 32; o > 0; o >>= 1) {
            sva += __shfl_down(sva, o);
            svb += __shfl_down(svb, o);
        }
        if (lane == 0) { sa[w] = sva; sb[w] = svb; }
    }
}

// =========================================================================
// k_gat300: fused edge score + segment softmax + weighted gather (bf16,
// ushort4-wide) + relu -> out cols 300..599, PLUS r2e score dots.
// =========================================================================
__global__ void k_gat300(const unsigned short* __restrict__ xbf,
                         const float* __restrict__ sA, const float* __restrict__ sB,
                         const float* __restrict__ rsc,
                         const int* __restrict__ jp, const int* __restrict__ relp,
                         const int* __restrict__ rowptr, const int* __restrict__ cnt,
                         float* __restrict__ out, long ldo,
                         const float* __restrict__ ah, const float* __restrict__ at,
                         float* __restrict__ sh, float* __restrict__ st,
                         int n)
{
    int w = (blockIdx.x*blockDim.x + threadIdx.x) >> 6;
    int lane = threadIdx.x & 63;
    if (w >= n) return;
    int beg = rowptr[w], c = cnt[w];
    const bool t1 = (lane < 11);
    float4 a0 = {0,0,0,0}, a1 = {0,0,0,0};
    if (c > 0) {
        float base = sA[w];
        int   jc = 0;
        float sval = -3.4e38f;
        if (lane < c) {
            jc = jp[beg + lane];
            sval = leaky(base + sB[jc] + rsc[relp[beg + lane]]);
        }
        float mx = sval;
        for (int t = 64 + lane; t < c; t += 64)
            mx = fmaxf(mx, leaky(base + sB[jp[beg+t]] + rsc[relp[beg+t]]));
        #pragma unroll
        for (int o = 32; o > 0; o >>= 1) mx = fmaxf(mx, __shfl_xor(mx, o));
        float pexp = (lane < c) ? expf(sval - mx) : 0.0f;
        float ss = pexp;
        for (int t = 64 + lane; t < c; t += 64)
            ss += expf(leaky(base + sB[jp[beg+t]] + rsc[relp[beg+t]]) - mx);
        #pragma unroll
        for (int o = 32; o > 0; o >>= 1) ss += __shfl_xor(ss, o);
        float inv = 1.0f / (ss + 1e-16f);
        int q = 0;
        int cc = (c < 64) ? c : 64;
        for (; q + 4 <= cc; q += 4) {
            float al0 = __shfl(pexp, q)   * inv;
            float al1 = __shfl(pexp, q+1) * inv;
            float al2 = __shfl(pexp, q+2) * inv;
            float al3 = __shfl(pexp, q+3) * inv;
            long  j0 = __shfl(jc, q), j1 = __shfl(jc, q+1);
            long  j2 = __shfl(jc, q+2), j3 = __shfl(jc, q+3);
            float4 v;
            v = bf42f(((const ushort4*)(xbf + j0*304))[lane]); FMA4(a0, al0, v);
            v = bf42f(((const ushort4*)(xbf + j1*304))[lane]); FMA4(a0, al1, v);
            v = bf42f(((const ushort4*)(xbf + j2*304))[lane]); FMA4(a0, al2, v);
            v = bf42f(((const ushort4*)(xbf + j3*304))[lane]); FMA4(a0, al3, v);
            if (t1) {
                v = bf42f(((const ushort4*)(xbf + j0*304 + 256))[lane]); FMA4(a1, al0, v);
                v = bf42f(((const ushort4*)(xbf + j1*304 + 256))[lane]); FMA4(a1, al1, v);
                v = bf42f(((const ushort4*)(xbf + j2*304 + 256))[lane]); FMA4(a1, al2, v);
                v = bf42f(((const ushort4*)(xbf + j3*304 + 256))[lane]); FMA4(a1, al3, v);
            }
        }
        for (; q < c; ++q) {
            float al; long j0;
            if (q < 64) { al = __shfl(pexp, q) * inv; j0 = __shfl(jc, q); }
            else {
                j0 = jp[beg + q];
                al = expf(leaky(base + sB[(int)j0] + rsc[relp[beg+q]]) - mx) * inv;
            }
            float4 v = bf42f(((const ushort4*)(xbf + j0*304))[lane]); FMA4(a0, al, v);
            if (t1) { v = bf42f(((const ushort4*)(xbf + j0*304 + 256))[lane]); FMA4(a1, al, v); }
        }
    }
    // relu + write
    a0.x = fmaxf(a0.x, 0.0f); a0.y = fmaxf(a0.y, 0.0f);
    a0.z = fmaxf(a0.z, 0.0f); a0.w = fmaxf(a0.w, 0.0f);
    a1.x = fmaxf(a1.x, 0.0f); a1.y = fmaxf(a1.y, 0.0f);
    a1.z = fmaxf(a1.z, 0.0f); a1.w = fmaxf(a1.w, 0.0f);
    ((float4*)(out + (long)w*ldo))[lane] = a0;
    if (t1) ((float4*)(out + (long)w*ldo + 256))[lane] = a1;
    // r2e score dots over x6 = [x(0..299) from xbf row w, gat output]
    {
        float4 x0 = bf42f(((const ushort4*)(xbf + (long)w*304))[lane]);
        float svh = DOT4(x0, ((const float4*)ah)[lane])
                  + DOT4(a0, ((const float4*)(ah + 300))[lane]);
        float svt = DOT4(x0, ((const float4*)at)[lane])
                  + DOT4(a0, ((const float4*)(at + 300))[lane]);
        if (t1) {
            float4 x1v = bf42f(((const ushort4*)(xbf + (long)w*304 + 256))[lane]);
            svh += DOT4(x1v, ((const float4*)(ah + 256))[lane])
                 + DOT4(a1,  ((const float4*)(ah + 556))[lane]);
            svt += DOT4(x1v, ((const float4*)(at + 256))[lane])
                 + DOT4(a1,  ((const float4*)(at + 556))[lane]);
        }
        #pragma unroll
        for (int o = 32; o > 0; o >>= 1) {
            svh += __shfl_down(svh, o);
            svt += __shfl_down(svt, o);
        }
        if (lane == 0) { sh[w] = svh; st[w] = svt; }
    }
}

// r2e (both h and t halves in one launch): fused score + softmax + gather (F=100)
__global__ void k_gather_rel2(const float* __restrict__ xr,
                              const float* __restrict__ sH, const float* __restrict__ sT,
                              const float* __restrict__ srel,
                              const int* __restrict__ relpH, const int* __restrict__ rowptrH,
                              const int* __restrict__ cntH,
                              const int* __restrict__ relpT, const int* __restrict__ rowptrT,
                              const int* __restrict__ cntT,
                              float* __restrict__ out, long ldo, int n)
{
    int gw = (blockIdx.x*blockDim.x + threadIdx.x) >> 6;
    int lane = threadIdx.x & 63;
    if (gw >= 2*n) return;
    const bool isT = (gw >= n);
    const int w = isT ? gw - n : gw;
    const float* snode = isT ? sT : sH;
    const int* relp   = isT ? relpT   : relpH;
    const int* rowptr = isT ? rowptrT : rowptrH;
    const int* cnt    = isT ? cntT    : cntH;
    float* dst = out + (isT ? 700 : 600) + (long)w*ldo;
    int beg = rowptr[w], c = cnt[w];
    const bool t0 = (lane < 25);
    float4 a0 = {0,0,0,0};
    if (c > 0) {
        float base = snode[w];
        int   rc = 0;
        float sval = -3.4e38f;
        if (lane < c) {
            rc = relp[beg + lane];
            sval = leaky(base + srel[rc]);
        }
        float mx = sval;
        for (int t = 64 + lane; t < c; t += 64)
            mx = fmaxf(mx, leaky(base + srel[relp[beg+t]]));
        #pragma unroll
        for (int o = 32; o > 0; o >>= 1) mx = fmaxf(mx, __shfl_xor(mx, o));
        float pexp = (lane < c) ? expf(sval - mx) : 0.0f;
        float ss = pexp;
        for (int t = 64 + lane; t < c; t += 64)
            ss += expf(leaky(base + srel[relp[beg+t]]) - mx);
        #pragma unroll
        for (int o = 32; o > 0; o >>= 1) ss += __shfl_xor(ss, o);
        float inv = 1.0f / (ss + 1e-16f);
        int q = 0;
        int cc = (c < 64) ? c : 64;
        for (; q + 4 <= cc; q += 4) {
            float al0 = __shfl(pexp, q)   * inv;
            float al1 = __shfl(pexp, q+1) * inv;
            float al2 = __shfl(pexp, q+2) * inv;
            float al3 = __shfl(pexp, q+3) * inv;
            long r0i = __shfl(rc, q), r1i = __shfl(rc, q+1);
            long r2i = __shfl(rc, q+2), r3i = __shfl(rc, q+3);
            if (t0) {
                float4 v;
                v = ((const float4*)(xr + r0i*100))[lane]; FMA4(a0, al0, v);
                v = ((const float4*)(xr + r1i*100))[lane]; FMA4(a0, al1, v);
                v = ((const float4*)(xr + r2i*100))[lane]; FMA4(a0, al2, v);
                v = ((const float4*)(xr + r3i*100))[lane]; FMA4(a0, al3, v);
            }
        }
        for (; q < c; ++q) {
            float al; long r0i;
            if (q < 64) { al = __shfl(pexp, q) * inv; r0i = __shfl(rc, q); }
            else {
                r0i = relp[beg + q];
                al = expf(leaky(base + srel[(int)r0i]) - mx) * inv;
            }
            if (t0) {
                float4 v = ((const float4*)(xr + r0i*100))[lane];
                FMA4(a0, al, v);
            }
        }
    }
    if (t0) ((float4*)dst)[lane] = a0;
}

// ---------- highway combine (small R x RH path) ----------
__global__ void k_highway(const float* __restrict__ x1, long ld1,
                          const float* __restrict__ gl, long ldg,
                          const float* __restrict__ x2, long ld2,
                          const float* __restrict__ bias,
                          float* __restrict__ out, long ldo,
                          long rows, int F, int relu_x2)
{
    long idx = (long)blockIdx.x*blockDim.x + threadIdx.x;
    if (idx >= rows * (long)F) return;
    long r = idx / F; int c = (int)(idx % F);
    float g = 1.0f / (1.0f + expf(-(gl[r*ldg+c] + bias[c])));
    float v2 = x2[r*ld2+c]; if (relu_x2) v2 = fmaxf(v2, 0.0f);
    float v1 = x1[r*ld1+c];
    out[r*ldo+c] = g*v2 + (1.0f-g)*v1;
}

// ---------- segment softmax building blocks (small l_gat path only) ----------
__global__ void k_segmax(const float* __restrict__ ev, const int* __restrict__ idx,
                         unsigned* __restrict__ m, int E) {
    int e = blockIdx.x*blockDim.x + threadIdx.x;
    if (e < E) atomicMax(&m[idx[e]], f2mono(ev[e]));
}
__global__ void k_segsumexp(const float* __restrict__ ev, const int* __restrict__ idx,
                            const unsigned* __restrict__ m, float* __restrict__ s, int E) {
    int e = blockIdx.x*blockDim.x + threadIdx.x;
    if (e < E) atomicAdd(&s[idx[e]], expf(ev[e] - mono2f(m[idx[e]])));
}
__global__ void k_lgat_vsum(const float* __restrict__ val,
                            const int* __restrict__ jj, const int* __restrict__ ii,
                            const unsigned* __restrict__ mi, const float* __restrict__ si,
                            const unsigned* __restrict__ mj, const float* __restrict__ sj,
                            float* __restrict__ vsum, int E)
{
    int e = blockIdx.x*blockDim.x + threadIdx.x;
    if (e >= E) return;
    float v = val[e];
    int i = ii[e], j = jj[e];
    float pi = expf(v - mono2f(mi[i])) / (si[i] + 1e-16f);
    float pj = expf(v - mono2f(mj[j])) / (sj[j] + 1e-16f);
    vsum[e] = pi + pj;
}
__global__ void k_edge_agg(const float* __restrict__ ev,
                           const unsigned* __restrict__ m, const float* __restrict__ s,
                           const int* __restrict__ ka, const int* __restrict__ ko,
                           const int* __restrict__ ks,
                           const float* __restrict__ x, long ldx,
                           float* __restrict__ out, long ldo,
                           int E, int F)
{
    int w = (blockIdx.x*blockDim.x + threadIdx.x) >> 6;
    int lane = threadIdx.x & 63;
    if (w >= E) return;
    int a = ka[w];
    float alpha = expf(ev[w] - mono2f(m[a])) / (s[a] + 1e-16f);
    const float4* src = (const float4*)(x + (long)ks[w]*ldx);
    float* dst = out + (long)ko[w]*ldo;
    int nf4 = F >> 2;
    for (int f = lane; f < nf4; f += WAVE) {
        float4 v = src[f];
        atomicAdd(&dst[f*4+0], alpha*v.x);
        atomicAdd(&dst[f*4+1], alpha*v.y);
        atomicAdd(&dst[f*4+2], alpha*v.z);
        atomicAdd(&dst[f*4+3], alpha*v.w);
    }
}
__global__ void k_relu2d(float* __restrict__ p, long rows, int cols, long ld) {
    long idx = (long)blockIdx.x*blockDim.x + threadIdx.x;
    if (idx >= rows*(long)cols) return;
    long r = idx / cols; int c = (int)(idx % cols);
    float v = p[r*ld+c];
    p[r*ld+c] = fmaxf(v, 0.0f);
}

// ---------- row dots (small path: srel) ----------
__global__ void k_rowdot2(const float* __restrict__ x, long ldx, int rows, int K,
                          const float* __restrict__ a, const float* __restrict__ b,
                          float* __restrict__ oa, float* __restrict__ ob)
{
    int w = (blockIdx.x*blockDim.x + threadIdx.x) >> 6;
    int lane = threadIdx.x & 63;
    if (w >= rows) return;
    const float* xr = x + (long)w*ldx;
    float sa = 0.0f, sb = 0.0f;
    for (int k = lane; k < K; k += WAVE) {
        float v = xr[k];
        sa += v * a[k];
        if (b) sb += v * b[k];
    }
    #pragma unroll
    for (int off = 32; off > 0; off >>= 1) {
        sa += __shfl_down(sa, off);
        if (b) sb += __shfl_down(sb, off);
    }
    if (lane == 0) { oa[w] = sa; if (ob) ob[w] = sb; }
}

// ---------- relscore[r] = merge[r]·ar[0:RH] + tri[r]·ar[RH:2RH] ----------
__global__ void k_relscore(const float* __restrict__ mg, const float* __restrict__ tr,
                           const float* __restrict__ ar, float* __restrict__ out, int R, int RH)
{
    int w = (blockIdx.x*blockDim.x + threadIdx.x) >> 6;
    int lane = threadIdx.x & 63;
    if (w >= R) return;
    float s = 0.0f;
    for (int k = lane; k < RH; k += WAVE)
        s += mg[(long)w*RH+k]*ar[k] + tr[(long)w*RH+k]*ar[RH+k];
    #pragma unroll
    for (int off = 32; off > 0; off >>= 1) s += __shfl_down(s, off);
    if (lane == 0) out[w] = s;
}

extern "C" void kernel_launch(void* const* d_in, const int* in_sizes, int n_in,
                              void* d_out, int out_size, void* d_ws, size_t ws_size,
                              hipStream_t stream)
{
    const float* x_e   = (const float*)d_in[0];
    const float* mval  = (const float*)d_in[1];
    const float* tval  = (const float*)d_in[2];
    const float* g1w   = (const float*)d_in[3];
    const float* h1w   = (const float*)d_in[4];
    const float* h1b   = (const float*)d_in[5];
    const float* g2w   = (const float*)d_in[6];
    const float* h2w   = (const float*)d_in[7];
    const float* h2b   = (const float*)d_in[8];
    const float* remb1 = (const float*)d_in[9];
    const float* remb2 = (const float*)d_in[10];
    const float* hrw   = (const float*)d_in[11];
    const float* hrb   = (const float*)d_in[12];
    const float* gat_ai= (const float*)d_in[13];
    const float* gat_aj= (const float*)d_in[14];
    const float* gat_ar= (const float*)d_in[15];
    const float* g2e_ah= (const float*)d_in[16];
    const float* g2e_at= (const float*)d_in[17];
    const float* g2e_ar= (const float*)d_in[18];
    const int* edge_index     = (const int*)d_in[19];
    const int* rel            = (const int*)d_in[20];
    const int* edge_index_all = (const int*)d_in[21];
    const int* rel_all        = (const int*)d_in[22];
    const int* lg_merge       = (const int*)d_in[23];
    const int* lg_tri         = (const int*)d_in[24];

    const int F    = 300;
    const int RH   = 100;
    const int Kp   = 304;                  // padded K
    const int npk  = Kp / 16;              // 19 k-steps
    const int N    = in_sizes[0] / F;      // 100000 (multiple of 32)
    const int E    = in_sizes[20];         // 400000
    const int EA   = in_sizes[22];         // 800000
    const int LGE  = in_sizes[1];          // 60000
    const int R    = in_sizes[9] / RH;     // 2000
    const long OUTC = 800;
    const int Mpad = CDIV(N, 128) * 128;   // 100096
    const int NB   = 640;                  // fused B rows: W_g @0..299, W_h @320..619
    const long LDC = 640;                  // Ascr stride (shorts)

    const int* jA = edge_index_all;
    const int* iA = edge_index_all + EA;
    const int* hE = edge_index;
    const int* tE = edge_index + E;
    const int* jM = lg_merge;  const int* iM = lg_merge + LGE;
    const int* jT = lg_tri;    const int* iT = lg_tri  + LGE;

    float* ws = (float*)d_ws;
    size_t off = 0;
    auto alloc = [&](size_t n) { float* p = ws + off; off += (n + 3) & ~(size_t)3; return p; };
    unsigned short* Ascr = (unsigned short*)alloc((size_t)N*NB/2);        // GEMM out bf16 [N,640]
    unsigned short* Axh = (unsigned short*)alloc((size_t)Mpad*Kp/2);      // A packed hi
    unsigned short* Axl = (unsigned short*)alloc((size_t)Mpad*Kp/2);      // A packed lo
    unsigned short* xbf = (unsigned short*)alloc((size_t)N*304/2);        // row-major bf16 x
    unsigned short* Wh[2]; unsigned short* Wl[2];
    for (int i = 0; i < 2; ++i) {
        Wh[i] = (unsigned short*)alloc((size_t)NB*Kp/2);
        Wl[i] = (unsigned short*)alloc((size_t)NB*Kp/2);
    }
    float*    dinv = alloc(N);
    float*    sA_  = alloc(N);
    float*    sB_  = alloc(N);
    float*    sH_  = alloc(N);
    float*    sT_  = alloc(N);
    float*    mrg  = alloc((size_t)R*RH);
    float*    tri  = alloc((size_t)R*RH);
    float*    xr   = alloc((size_t)R*RH);
    float*    xrg  = alloc((size_t)R*RH);
    unsigned* lmi  = (unsigned*)alloc(R);  float* lsi = alloc(R);
    unsigned* lmj  = (unsigned*)alloc(R);  float* lsj = alloc(R);
    unsigned* lm2  = (unsigned*)alloc(R);  float* ls2 = alloc(R);
    float*    vsum = alloc(LGE);
    float*    rsc  = alloc(R);
    float*    srel = alloc(R);
    int*   bsum    = (int*)alloc(1024);
    int*   cursor  = (int*)alloc(N);
    int*   rowptrA = (int*)alloc(N); int* cntA = (int*)alloc(N); int* permA = (int*)alloc(EA);
    int*   rowptrH = (int*)alloc(N); int* cntH = (int*)alloc(N); int* permH = (int*)alloc(E);
    int*   rowptrT = (int*)alloc(N); int* cntT = (int*)alloc(N); int* permT = (int*)alloc(E);
    int*   jpA     = (int*)alloc(EA);
    float* nmA     = alloc(EA);
    int*   relpA   = (int*)alloc(EA);
    int*   relpH   = (int*)alloc(E);
    int*   relpT   = (int*)alloc(E);

    float* out = (float*)d_out;              // [N, 800]

    const int  nb = CDIV(N, 256);
    const int  nrb = CDIV(N, 128);                 // 782 row panels
    const int  gemmBlocks = 8 * CDIV(nrb, 8) * 5;  // XCD-ownership swizzled grid
    const int gatherGrid = CDIV(N, 4);
    const int cvtBigGrid = CDIV((long)N * (Kp/4), 256);
    const int cvtWGrid   = CDIV(300 * (Kp/4), 256);

    auto build_csr = [&](const int* key, int E_, int* rowptr, int* cnt, int* perm) {
        hipMemsetAsync(cnt, 0, (size_t)N*4, stream);
        k_hist<<<CDIV(E_,256),256,0,stream>>>(key, cnt, E_);
        k_scan1<<<nb,256,0,stream>>>(cnt, rowptr, bsum, N);
        k_scan2<<<1,1024,0,stream>>>(bsum, nb);
        k_scan3<<<nb,256,0,stream>>>(rowptr, bsum, N);
        hipMemsetAsync(cursor, 0, (size_t)N*4, stream);
        k_fill<<<CDIV(E_,256),256,0,stream>>>(key, rowptr, cursor, perm, E_);
    };

    // ===== zero pads, then fragment-pack converts (fused W: g @0, h @320) =====
    for (int i = 0; i < 2; ++i) {
        hipMemsetAsync(Wh[i], 0, (size_t)NB*Kp*2, stream);
        hipMemsetAsync(Wl[i], 0, (size_t)NB*Kp*2, stream);
    }
    hipMemsetAsync(Axh + (size_t)N*Kp, 0, (size_t)(Mpad-N)*Kp*2, stream);
    hipMemsetAsync(Axl + (size_t)N*Kp, 0, (size_t)(Mpad-N)*Kp*2, stream);
    k_cvt_pack<<<cvtWGrid,256,0,stream>>>(g1w, 300, 300, 300, npk, 0,   Wh[0], Wl[0]);
    k_cvt_pack<<<cvtWGrid,256,0,stream>>>(h1w, 300, 300, 300, npk, 320, Wh[0], Wl[0]);
    k_cvt_pack<<<cvtWGrid,256,0,stream>>>(g2w, 300, 300, 300, npk, 0,   Wh[1], Wl[1]);
    k_cvt_pack<<<cvtWGrid,256,0,stream>>>(h2w, 300, 300, 300, npk, 320, Wh[1], Wl[1]);
    k_cvt_pack<<<cvtBigGrid,256,0,stream>>>(x_e, 300, N, 300, npk, 0, Axh, Axl);

    // ===== CSRs + pre-permutes =====
    build_csr(iA, EA, rowptrA, cntA, permA);
    build_csr(hE, E,  rowptrH, cntH, permH);
    build_csr(tE, E,  rowptrT, cntT, permT);
    k_dinv_cnt<<<CDIV(N,256),256,0,stream>>>(cntA, dinv, N);
    k_prep_gcn<<<CDIV(EA,256),256,0,stream>>>(permA, jA, iA, dinv, jpA, nmA, EA);
    k_permute_mod<<<CDIV(EA,256),256,0,stream>>>(rel_all, permA, relpA, EA, R);
    k_permute_i32<<<CDIV(E,256),256,0,stream>>>(rel, permH, relpH, E);
    k_permute_i32<<<CDIV(E,256),256,0,stream>>>(rel, permT, relpT, E);

    // ===== GCN layer 1: fused double-GEMM (bf16 out) + gather/highway/pack =====
    k_gemm_frag<<<gemmBlocks,256,0,stream>>>(Axh, Axl, Wh[0], Wl[0], Ascr, LDC, N, 620, npk, nrb);
    k_gather_hw<<<gatherGrid,256,0,stream>>>(Ascr, LDC, Ascr+320, x_e, 300, h1b,
                                             jpA, nmA, rowptrA, cntA,
                                             out, OUTC, Axh, Axl,
                                             (unsigned short*)nullptr,
                                             (const float*)nullptr, (const float*)nullptr,
                                             (float*)nullptr, (float*)nullptr, npk, N);

    // ===== GCN layer 2: + xbf emit + GAT score dots =====
    k_gemm_frag<<<gemmBlocks,256,0,stream>>>(Axh, Axl, Wh[1], Wl[1], Ascr, LDC, N, 620, npk, nrb);
    k_gather_hw<<<gatherGrid,256,0,stream>>>(Ascr, LDC, Ascr+320, out, OUTC, h2b,
                                             jpA, nmA, rowptrA, cntA,
                                             out, OUTC,
                                             (unsigned short*)nullptr, (unsigned short*)nullptr,
                                             xbf, gat_ai, gat_aj, sA_, sB_, npk, N);

    // ===== l_gat on the two line graphs (small; atomic path) =====
    auto lgat = [&](const float* xrel, const int* jjE, const int* iiE, const float* val, float* obuf) {
        hipMemsetAsync(lmi, 0, R*4, stream); hipMemsetAsync(lsi, 0, R*4, stream);
        hipMemsetAsync(lmj, 0, R*4, stream); hipMemsetAsync(lsj, 0, R*4, stream);
        hipMemsetAsync(lm2, 0, R*4, stream); hipMemsetAsync(ls2, 0, R*4, stream);
        hipMemsetAsync(obuf, 0, (size_t)R*RH*4, stream);
        k_segmax   <<<CDIV(LGE,256),256,0,stream>>>(val, iiE, lmi, LGE);
        k_segmax   <<<CDIV(LGE,256),256,0,stream>>>(val, jjE, lmj, LGE);
        k_segsumexp<<<CDIV(LGE,256),256,0,stream>>>(val, iiE, lmi, lsi, LGE);
        k_segsumexp<<<CDIV(LGE,256),256,0,stream>>>(val, jjE, lmj, lsj, LGE);
        k_lgat_vsum<<<CDIV(LGE,256),256,0,stream>>>(val, jjE, iiE, lmi, lsi, lmj, lsj, vsum, LGE);
        k_segmax   <<<CDIV(LGE,256),256,0,stream>>>(vsum, jjE, lm2, LGE);
        k_segsumexp<<<CDIV(LGE,256),256,0,stream>>>(vsum, jjE, lm2, ls2, LGE);
        k_edge_agg <<<(int)CDIV((long)LGE*64,256),256,0,stream>>>(vsum, lm2, ls2, jjE, iiE, jjE,
                                                                  xrel, RH, obuf, RH, LGE, RH);
        k_relu2d   <<<CDIV((long)R*RH,256),256,0,stream>>>(obuf, R, RH, RH);
    };
    lgat(remb1, jM, iM, mval, mrg);
    lgat(remb2, jT, iT, tval, tri);

    // ===== x_r = highway(mrg, tri, hrw, hrb) =====
    dim3 gridR(CDIV(RH,GBN), CDIV(R,GBM));
    k_gemm<<<gridR,256,0,stream>>>(mrg, RH, hrw, RH, xrg, RH, R, RH, RH);
    k_highway<<<CDIV((long)R*RH,256),256,0,stream>>>(mrg, RH, xrg, RH, tri, RH, hrb, xr, RH, R, RH, 0);

    // relscore[r] = rel_cat[r]·gat_ar
    k_relscore<<<CDIV((long)R*64,256),256,0,stream>>>(mrg, tri, gat_ar, rsc, R, RH);

    // ===== GAT -> out cols 300..599 + r2e score dots (fully fused) =====
    k_gat300<<<gatherGrid,256,0,stream>>>(xbf, sA_, sB_, rsc, jpA, relpA,
                                          rowptrA, cntA, out+300, OUTC,
                                          g2e_ah, g2e_at, sH_, sT_, N);

    // ===== gat_r_to_e over edge_index -> out cols 600..799 (h+t merged) =====
    k_rowdot2<<<CDIV((long)R*64,256),256,0,stream>>>(xr, RH, R, RH, g2e_ar, (const float*)nullptr,
                                                     srel, (float*)nullptr);
    k_gather_rel2<<<CDIV(2*N,4),256,0,stream>>>(xr, sH_, sT_, srel,
                                                relpH, rowptrH, cntH,
                                                relpT, rowptrT, cntT,
                                                out, OUTC, N);
}

// Round 11
// 1464.555 us; speedup vs baseline: 1.1482x; 1.1482x over previous
//
#include <hip/hip_runtime.h>

#define WAVE 64
#define CDIV(a,b) (((a)+(b)-1)/(b))

typedef float f32x16 __attribute__((ext_vector_type(16)));
typedef unsigned short u16x8 __attribute__((ext_vector_type(8)));

// ---------- bf16 helpers ----------
__device__ __forceinline__ unsigned short f2bf_rne(float f) {
    unsigned u = __float_as_uint(f);
    unsigned r = (u + 0x7FFFu + ((u >> 16) & 1u)) >> 16;
    return (unsigned short)r;
}
__device__ __forceinline__ float bf2f(unsigned short h) {
    return __uint_as_float(((unsigned)h) << 16);
}
__device__ __forceinline__ float2 bfp2f(ushort2 u) {
    float2 r; r.x = bf2f(u.x); r.y = bf2f(u.y); return r;
}
__device__ __forceinline__ float sigm(float x) { return 1.0f / (1.0f + expf(-x)); }

#define MFMA32(acc, a, b) \
    asm volatile("v_mfma_f32_32x32x16_bf16 %0, %1, %2, %0" : "+v"(acc) : "v"(a), "v"(b))

// ---------- monotonic float<->uint encoding for atomicMax on floats ----------
__device__ __forceinline__ unsigned f2mono(float f) {
    unsigned u = __float_as_uint(f);
    return (u & 0x80000000u) ? ~u : (u | 0x80000000u);
}
__device__ __forceinline__ float mono2f(unsigned u) {
    return (u & 0x80000000u) ? __uint_as_float(u & 0x7fffffffu) : __uint_as_float(~u);
}
__device__ __forceinline__ float leaky(float v) { return (v > 0.0f) ? v : 0.01f*v; }

// fragment-pack offset: matrix row r, col k -> packed short index.
__device__ __forceinline__ long fragoff(long r, int k, int npk) {
    return ((r >> 5) * (long)npk + (k >> 4)) * 512
         + (((k >> 3) & 1) << 8) + ((r & 31) << 3) + (k & 7);
}

// =========================================================================
// k_cvt_pack: f32 -> fragment-packed bf16 hi/lo (weights; roff row offset)
// =========================================================================
__global__ void k_cvt_pack(const float* __restrict__ src, long ld, int rows, int K, int npk,
                           int roff,
                           unsigned short* __restrict__ hi, unsigned short* __restrict__ lo)
{
    int nc4 = npk << 2;
    long idx = (long)blockIdx.x*blockDim.x + threadIdx.x;
    if (idx >= (long)rows * nc4) return;
    long r = idx / nc4; int k = (int)(idx % nc4) << 2;
    float4 v = {0.0f, 0.0f, 0.0f, 0.0f};
    if (k + 4 <= K) v = *(const float4*)(src + r*ld + k);
    float vv[4] = {v.x, v.y, v.z, v.w};
    ushort4 h, l;
    unsigned short hh[4], ll[4];
    #pragma unroll
    for (int i = 0; i < 4; ++i) {
        unsigned u = __float_as_uint(vv[i]);
        hh[i] = (unsigned short)(u >> 16);
        ll[i] = f2bf_rne(vv[i] - bf2f(hh[i]));
    }
    h.x = hh[0]; h.y = hh[1]; h.z = hh[2]; h.w = hh[3];
    l.x = ll[0]; l.y = ll[1]; l.z = ll[2]; l.w = ll[3];
    long off = fragoff(r + roff, k, npk);
    *(ushort4*)(hi + off) = h;
    *(ushort4*)(lo + off) = l;
}

// k_cvt_pack1: f32 -> fragment-packed single bf16 (rne) — for A/x side
__global__ void k_cvt_pack1(const float* __restrict__ src, long ld, int rows, int K, int npk,
                            unsigned short* __restrict__ dst)
{
    int nc4 = npk << 2;
    long idx = (long)blockIdx.x*blockDim.x + threadIdx.x;
    if (idx >= (long)rows * nc4) return;
    long r = idx / nc4; int k = (int)(idx % nc4) << 2;
    float4 v = {0.0f, 0.0f, 0.0f, 0.0f};
    if (k + 4 <= K) v = *(const float4*)(src + r*ld + k);
    ushort4 h;
    h.x = f2bf_rne(v.x); h.y = f2bf_rne(v.y); h.z = f2bf_rne(v.z); h.w = f2bf_rne(v.w);
    *(ushort4*)(dst + fragoff(r, k, npk)) = h;
}

// =========================================================================
// k_gemm_frag: C[M,620] (bf16) = A * B^T; A single bf16 (rne), B hi/lo
// split (weights, exact to ~2^-17). NO LDS, NO barriers. XCD-ownership
// swizzle: lin%8 = XCD owns whole row-panels; its 5 col-blocks run
// back-to-back out of its own L2 -> A fetched from HBM once.
// Block 256 thr = 4 waves; wave = 32 rows x 128 cols. 8 MFMA / k-step.
// =========================================================================
__global__ __launch_bounds__(256, 3)
void k_gemm_frag(const unsigned short* __restrict__ Ab,
                 const unsigned short* __restrict__ Bhi, const unsigned short* __restrict__ Blo,
                 unsigned short* __restrict__ C, long ldc, int M, int N, int nk, int nrb)
{
    const int lane = threadIdx.x & 63;
    const int wid  = threadIdx.x >> 6;
    const int lin  = blockIdx.x;
    const int xcd  = lin & 7;
    const int m    = lin >> 3;
    const int col0 = (m % 5) * 128;
    const int rb   = xcd + ((m / 5) << 3);
    if (rb >= nrb) return;
    const int row0 = rb * 128 + wid * 32;

    const long cs = (long)nk * 512;                 // tile-row stride (shorts)
    const unsigned short* pA  = Ab  + (long)(row0 >> 5) * cs + lane * 8;
    const unsigned short* pBh = Bhi + (long)(col0 >> 5) * cs + lane * 8;
    const unsigned short* pBl = Blo + (long)(col0 >> 5) * cs + lane * 8;

    f32x16 acc[4];
    #pragma unroll
    for (int c = 0; c < 4; ++c) acc[c] = (f32x16)0.0f;

    u16x8 pa, pb0, pb1, pb2, pb3, pl0, pl1, pl2, pl3;
    u16x8 qa, qb0, qb1, qb2, qb3, ql0, ql1, ql2, ql3;

    #define LOADP(t_) { long o = (long)(t_)*512;                                   \
        pa  = *(const u16x8*)(pA + o);                                             \
        pb0 = *(const u16x8*)(pBh + o);        pl0 = *(const u16x8*)(pBl + o);     \
        pb1 = *(const u16x8*)(pBh + cs + o);   pl1 = *(const u16x8*)(pBl + cs + o);\
        pb2 = *(const u16x8*)(pBh + 2*cs + o); pl2 = *(const u16x8*)(pBl + 2*cs + o);\
        pb3 = *(const u16x8*)(pBh + 3*cs + o); pl3 = *(const u16x8*)(pBl + 3*cs + o); }
    #define LOADQ(t_) { long o = (long)(t_)*512;                                   \
        qa  = *(const u16x8*)(pA + o);                                             \
        qb0 = *(const u16x8*)(pBh + o);        ql0 = *(const u16x8*)(pBl + o);     \
        qb1 = *(const u16x8*)(pBh + cs + o);   ql1 = *(const u16x8*)(pBl + cs + o);\
        qb2 = *(const u16x8*)(pBh + 2*cs + o); ql2 = *(const u16x8*)(pBl + 2*cs + o);\
        qb3 = *(const u16x8*)(pBh + 3*cs + o); ql3 = *(const u16x8*)(pBl + 3*cs + o); }
    #define STEPP {                                                                 \
        MFMA32(acc[0], pa, pb0); MFMA32(acc[1], pa, pb1);                           \
        MFMA32(acc[2], pa, pb2); MFMA32(acc[3], pa, pb3);                           \
        MFMA32(acc[0], pa, pl0); MFMA32(acc[1], pa, pl1);                           \
        MFMA32(acc[2], pa, pl2); MFMA32(acc[3], pa, pl3); }
    #define STEPQ {                                                                 \
        MFMA32(acc[0], qa, qb0); MFMA32(acc[1], qa, qb1);                           \
        MFMA32(acc[2], qa, qb2); MFMA32(acc[3], qa, qb3);                           \
        MFMA32(acc[0], qa, ql0); MFMA32(acc[1], qa, ql1);                           \
        MFMA32(acc[2], qa, ql2); MFMA32(acc[3], qa, ql3); }

    LOADP(0);
    int t = 0;
    for (;;) {
        bool m1 = (t + 1 < nk);
        if (m1) LOADQ(t + 1);
        STEPP;
        if (!m1) break;
        bool m2 = (t + 2 < nk);
        if (m2) LOADP(t + 2);
        STEPQ;
        if (!m2) break;
        t += 2;
    }
    #undef LOADP
    #undef LOADQ
    #undef STEPP
    #undef STEPQ

    const int crow0 = row0 + 4*(lane >> 5);
    const int ccol0 = col0 + (lane & 31);
    #pragma unroll
    for (int c = 0; c < 4; ++c) {
        int col = ccol0 + c*32;
        if (col >= N) continue;
        #pragma unroll
        for (int reg = 0; reg < 16; ++reg) {
            int row = crow0 + (reg & 3) + 8*(reg >> 2);
            if (row < M) C[(long)row*ldc + col] = f2bf_rne(acc[c][reg]);
        }
    }
}

// ---------- small f32 GEMM (tiny R x RH highway gate) ----------
#define GBM 64
#define GBN 64
#define GBK 16
__global__ __launch_bounds__(256)
void k_gemm(const float* __restrict__ A, long lda,
            const float* __restrict__ B, long ldb,
            float* __restrict__ C, long ldc,
            int M, int N, int K)
{
    __shared__ float As[GBK][GBM + 4];
    __shared__ float Bs[GBK][GBN + 4];
    const int tid = threadIdx.x;
    const int tx = tid & 15, ty = tid >> 4;
    const int row0 = blockIdx.y * GBM, col0 = blockIdx.x * GBN;
    float acc[4][4] = {};
    for (int kt = 0; kt < K; kt += GBK) {
        #pragma unroll
        for (int p = 0; p < 4; ++p) {
            int mn = (tid >> 4) + p * 16;
            int k  = tid & 15;
            int gk = kt + k;
            int gr = row0 + mn;
            As[k][mn] = (gr < M && gk < K) ? A[(long)gr * lda + gk] : 0.0f;
            int gc = col0 + mn;
            Bs[k][mn] = (gc < N && gk < K) ? B[(long)gc * ldb + gk] : 0.0f;
        }
        __syncthreads();
        #pragma unroll
        for (int kk = 0; kk < GBK; ++kk) {
            float a0 = As[kk][ty*4+0], a1 = As[kk][ty*4+1];
            float a2 = As[kk][ty*4+2], a3 = As[kk][ty*4+3];
            float b0 = Bs[kk][tx*4+0], b1 = Bs[kk][tx*4+1];
            float b2 = Bs[kk][tx*4+2], b3 = Bs[kk][tx*4+3];
            acc[0][0] += a0*b0; acc[0][1] += a0*b1; acc[0][2] += a0*b2; acc[0][3] += a0*b3;
            acc[1][0] += a1*b0; acc[1][1] += a1*b1; acc[1][2] += a1*b2; acc[1][3] += a1*b3;
            acc[2][0] += a2*b0; acc[2][1] += a2*b1; acc[2][2] += a2*b2; acc[2][3] += a2*b3;
            acc[3][0] += a3*b0; acc[3][1] += a3*b1; acc[3][2] += a3*b2; acc[3][3] += a3*b3;
        }
        __syncthreads();
    }
    #pragma unroll
    for (int i2 = 0; i2 < 4; ++i2)
        #pragma unroll
        for (int j2 = 0; j2 < 4; ++j2) {
            int r = row0 + ty*4 + i2, c = col0 + tx*4 + j2;
            if (r < M && c < N) C[(long)r*ldc + c] = acc[i2][j2];
        }
}

// ================= CSR build: histogram -> scan -> fill =================
__global__ void k_hist(const int* __restrict__ key, int* __restrict__ cnt, int E) {
    int e = blockIdx.x*blockDim.x + threadIdx.x;
    if (e < E) atomicAdd(&cnt[key[e]], 1);
}
__global__ void k_scan1(const int* __restrict__ in, int* __restrict__ out,
                        int* __restrict__ bsum, int n) {
    __shared__ int sh[256];
    int gid = blockIdx.x*256 + threadIdx.x;
    int v = (gid < n) ? in[gid] : 0;
    sh[threadIdx.x] = v; __syncthreads();
    for (int o = 1; o < 256; o <<= 1) {
        int t = (threadIdx.x >= o) ? sh[threadIdx.x - o] : 0;
        __syncthreads();
        sh[threadIdx.x] += t;
        __syncthreads();
    }
    if (gid < n) out[gid] = sh[threadIdx.x] - v;      // exclusive
    if (threadIdx.x == 255) bsum[blockIdx.x] = sh[255];
}
__global__ void k_scan2(int* __restrict__ bsum, int nb) {   // single block, nb <= 1024
    __shared__ int sh[1024];
    int v = (threadIdx.x < nb) ? bsum[threadIdx.x] : 0;
    sh[threadIdx.x] = v; __syncthreads();
    for (int o = 1; o < 1024; o <<= 1) {
        int t = (threadIdx.x >= o) ? sh[threadIdx.x - o] : 0;
        __syncthreads();
        sh[threadIdx.x] += t;
        __syncthreads();
    }
    if (threadIdx.x < nb) bsum[threadIdx.x] = sh[threadIdx.x] - v;  // exclusive
}
__global__ void k_scan3(int* __restrict__ out, const int* __restrict__ bsum, int n) {
    int gid = blockIdx.x*256 + threadIdx.x;
    if (gid < n) out[gid] += bsum[blockIdx.x];
}
__global__ void k_fill(const int* __restrict__ key, const int* __restrict__ rowptr,
                       int* __restrict__ cursor, int* __restrict__ perm, int E) {
    int e = blockIdx.x*blockDim.x + threadIdx.x;
    if (e >= E) return;
    int k = key[e];
    int p = rowptr[k] + atomicAdd(&cursor[k], 1);
    perm[p] = e;
}
__global__ void k_dinv_cnt(const int* __restrict__ cnt, float* __restrict__ dinv, int n) {
    int i = blockIdx.x*blockDim.x + threadIdx.x;
    if (i < n) { int c = cnt[i]; dinv[i] = (c > 0) ? rsqrtf((float)c) : 0.0f; }
}

// ---------- CSR-order pre-permutation ----------
__global__ void k_prep_gcn(const int* __restrict__ perm, const int* __restrict__ jA,
                           const int* __restrict__ iA, const float* __restrict__ dinv,
                           int* __restrict__ jp, float* __restrict__ nm, int E) {
    int p = blockIdx.x*blockDim.x + threadIdx.x;
    if (p >= E) return;
    int e = perm[p];
    int j = jA[e];
    jp[p] = j;
    nm[p] = dinv[iA[e]] * dinv[j];
}
__global__ void k_permute_i32(const int* __restrict__ src, const int* __restrict__ perm,
                              int* __restrict__ dst, int E) {
    int p = blockIdx.x*blockDim.x + threadIdx.x;
    if (p < E) dst[p] = src[perm[p]];
}
__global__ void k_permute_mod(const int* __restrict__ src, const int* __restrict__ perm,
                              int* __restrict__ dst, int E, int mod) {
    int p = blockIdx.x*blockDim.x + threadIdx.x;
    if (p < E) dst[p] = src[perm[p]] % mod;
}

// =========================================================================
// k_gather_hw: fused GCN gather (bf16 src, ushort2 3-chunk) + relu +
// highway + extras (single-bf16 fragment pack / xbf emit / GAT dots).
// =========================================================================
__global__ void k_gather_hw(const unsigned short* __restrict__ xg, long ldx,
                            const unsigned short* __restrict__ gl,
                            const float* __restrict__ x1, long ld1,
                            const float* __restrict__ bias,
                            const int* __restrict__ jp, const float* __restrict__ nm,
                            const int* __restrict__ rowptr, const int* __restrict__ cnt,
                            float* __restrict__ out, long ldo,
                            unsigned short* __restrict__ pk,
                            unsigned short* __restrict__ xbf,
                            const float* __restrict__ ai, const float* __restrict__ aj,
                            float* __restrict__ sa, float* __restrict__ sb,
                            int npk, int n)
{
    int w = (blockIdx.x*blockDim.x + threadIdx.x) >> 6;
    int lane = threadIdx.x & 63;
    if (w >= n) return;
    int beg = rowptr[w], end = beg + cnt[w];
    const int i0 = lane, i1 = lane + 64, i2 = lane + 128;
    const bool t3 = (lane < 22);
    float2 a0 = {0,0}, a1 = {0,0}, a2 = {0,0};
    int e = beg;
    for (; e + 4 <= end; e += 4) {
        const ushort2* r0 = (const ushort2*)(xg + (long)jp[e]  *ldx);
        const ushort2* r1 = (const ushort2*)(xg + (long)jp[e+1]*ldx);
        const ushort2* r2 = (const ushort2*)(xg + (long)jp[e+2]*ldx);
        const ushort2* r3 = (const ushort2*)(xg + (long)jp[e+3]*ldx);
        float w0 = nm[e], w1 = nm[e+1], w2 = nm[e+2], w3 = nm[e+3];
        float2 v;
        v = bfp2f(r0[i0]); a0.x += w0*v.x; a0.y += w0*v.y;
        v = bfp2f(r1[i0]); a0.x += w1*v.x; a0.y += w1*v.y;
        v = bfp2f(r2[i0]); a0.x += w2*v.x; a0.y += w2*v.y;
        v = bfp2f(r3[i0]); a0.x += w3*v.x; a0.y += w3*v.y;
        v = bfp2f(r0[i1]); a1.x += w0*v.x; a1.y += w0*v.y;
        v = bfp2f(r1[i1]); a1.x += w1*v.x; a1.y += w1*v.y;
        v = bfp2f(r2[i1]); a1.x += w2*v.x; a1.y += w2*v.y;
        v = bfp2f(r3[i1]); a1.x += w3*v.x; a1.y += w3*v.y;
        if (t3) {
            v = bfp2f(r0[i2]); a2.x += w0*v.x; a2.y += w0*v.y;
            v = bfp2f(r1[i2]); a2.x += w1*v.x; a2.y += w1*v.y;
            v = bfp2f(r2[i2]); a2.x += w2*v.x; a2.y += w2*v.y;
            v = bfp2f(r3[i2]); a2.x += w3*v.x; a2.y += w3*v.y;
        }
    }
    for (; e < end; ++e) {
        const ushort2* r0 = (const ushort2*)(xg + (long)jp[e]*ldx);
        float w0 = nm[e];
        float2 v;
        v = bfp2f(r0[i0]); a0.x += w0*v.x; a0.y += w0*v.y;
        v = bfp2f(r0[i1]); a1.x += w0*v.x; a1.y += w0*v.y;
        if (t3) { v = bfp2f(r0[i2]); a2.x += w0*v.x; a2.y += w0*v.y; }
    }
    // highway: o = sig(gl+b)*relu(acc) + (1-sig)*x1
    const ushort2* glr = (const ushort2*)(gl + (long)w*ldx);
    const float2*  x1r = (const float2*)(x1 + (long)w*ld1);
    const float2*  br  = (const float2*)bias;
    float2* dst = (float2*)(out + (long)w*ldo);
    float2 o0 = {0,0}, o1 = {0,0}, o2 = {0,0};
    {
        float2 gv = bfp2f(glr[i0]); float2 xv = x1r[i0], bv = br[i0];
        float g0 = sigm(gv.x + bv.x), g1 = sigm(gv.y + bv.y);
        o0.x = g0*fmaxf(a0.x,0.0f) + (1.0f-g0)*xv.x;
        o0.y = g1*fmaxf(a0.y,0.0f) + (1.0f-g1)*xv.y;
        dst[i0] = o0;
    }
    {
        float2 gv = bfp2f(glr[i1]); float2 xv = x1r[i1], bv = br[i1];
        float g0 = sigm(gv.x + bv.x), g1 = sigm(gv.y + bv.y);
        o1.x = g0*fmaxf(a1.x,0.0f) + (1.0f-g0)*xv.x;
        o1.y = g1*fmaxf(a1.y,0.0f) + (1.0f-g1)*xv.y;
        dst[i1] = o1;
    }
    if (t3) {
        float2 gv = bfp2f(glr[i2]); float2 xv = x1r[i2], bv = br[i2];
        float g0 = sigm(gv.x + bv.x), g1 = sigm(gv.y + bv.y);
        o2.x = g0*fmaxf(a2.x,0.0f) + (1.0f-g0)*xv.x;
        o2.y = g1*fmaxf(a2.y,0.0f) + (1.0f-g1)*xv.y;
        dst[i2] = o2;
    }
    if (pk) {   // single-bf16 fragment pack for the next GEMM's A
        auto pack2 = [&](int k, float2 o) {
            ushort2 hv; hv.x = f2bf_rne(o.x); hv.y = f2bf_rne(o.y);
            *(ushort2*)(pk + fragoff(w, k, npk)) = hv;
        };
        pack2(2*lane, o0);
        pack2(128 + 2*lane, o1);
        if (t3) pack2(256 + 2*lane, o2);
        else if (lane < 24) {   // lanes 22,23: zero-fill k = 300,302 (pad)
            ushort2 z = {0,0};
            *(ushort2*)(pk + fragoff(w, 256 + 2*lane, npk)) = z;
        }
    }
    if (xbf) {  // row-major bf16 copy (stride 304 shorts) for GAT gather
        ushort2* xw = (ushort2*)(xbf + (long)w*304);
        ushort2 t;
        t.x = f2bf_rne(o0.x); t.y = f2bf_rne(o0.y); xw[i0] = t;
        t.x = f2bf_rne(o1.x); t.y = f2bf_rne(o1.y); xw[i1] = t;
        if (t3) { t.x = f2bf_rne(o2.x); t.y = f2bf_rne(o2.y); xw[i2] = t; }
    }
    if (sa) {   // GAT score dots: sa[w] = o·ai, sb[w] = o·aj
        const float2* ai2 = (const float2*)ai;
        const float2* aj2 = (const float2*)aj;
        float2 A0 = ai2[i0], A1 = ai2[i1], J0 = aj2[i0], J1 = aj2[i1];
        float sva = o0.x*A0.x + o0.y*A0.y + o1.x*A1.x + o1.y*A1.y;
        float svb = o0.x*J0.x + o0.y*J0.y + o1.x*J1.x + o1.y*J1.y;
        if (t3) {
            float2 A2 = ai2[i2], J2 = aj2[i2];
            sva += o2.x*A2.x + o2.y*A2.y;
            svb += o2.x*J2.x + o2.y*J2.y;
        }
        #pragma unroll
        for (int o = 32; o > 0; o >>= 1) {
            sva += __shfl_down(sva, o);
            svb += __shfl_down(svb, o);
        }
        if (lane == 0) { sa[w] = sva; sb[w] = svb; }
    }
}

// =========================================================================
// k_gat300: fused edge score + segment softmax + weighted gather (bf16,
// ushort2 3-chunk) + relu -> out cols 300..599, PLUS r2e score dots.
// =========================================================================
__global__ void k_gat300(const unsigned short* __restrict__ xbf,
                         const float* __restrict__ sA, const float* __restrict__ sB,
                         const float* __restrict__ rsc,
                         const int* __restrict__ jp, const int* __restrict__ relp,
                         const int* __restrict__ rowptr, const int* __restrict__ cnt,
                         float* __restrict__ out, long ldo,
                         const float* __restrict__ ah, const float* __restrict__ at,
                         float* __restrict__ sh, float* __restrict__ st,
                         int n)
{
    int w = (blockIdx.x*blockDim.x + threadIdx.x) >> 6;
    int lane = threadIdx.x & 63;
    if (w >= n) return;
    int beg = rowptr[w], c = cnt[w];
    const int i0 = lane, i1 = lane + 64, i2 = lane + 128;
    const bool t3 = (lane < 22);
    float2 a0 = {0,0}, a1 = {0,0}, a2 = {0,0};
    if (c > 0) {
        float base = sA[w];
        int   jc = 0;
        float sval = -3.4e38f;
        if (lane < c) {
            jc = jp[beg + lane];
            sval = leaky(base + sB[jc] + rsc[relp[beg + lane]]);
        }
        float mx = sval;
        for (int t = 64 + lane; t < c; t += 64)
            mx = fmaxf(mx, leaky(base + sB[jp[beg+t]] + rsc[relp[beg+t]]));
        #pragma unroll
        for (int o = 32; o > 0; o >>= 1) mx = fmaxf(mx, __shfl_xor(mx, o));
        float pexp = (lane < c) ? expf(sval - mx) : 0.0f;
        float ss = pexp;
        for (int t = 64 + lane; t < c; t += 64)
            ss += expf(leaky(base + sB[jp[beg+t]] + rsc[relp[beg+t]]) - mx);
        #pragma unroll
        for (int o = 32; o > 0; o >>= 1) ss += __shfl_xor(ss, o);
        float inv = 1.0f / (ss + 1e-16f);
        int q = 0;
        int cc = (c < 64) ? c : 64;
        for (; q + 4 <= cc; q += 4) {
            float al0 = __shfl(pexp, q)   * inv;
            float al1 = __shfl(pexp, q+1) * inv;
            float al2 = __shfl(pexp, q+2) * inv;
            float al3 = __shfl(pexp, q+3) * inv;
            long  j0 = __shfl(jc, q), j1 = __shfl(jc, q+1);
            long  j2 = __shfl(jc, q+2), j3 = __shfl(jc, q+3);
            const ushort2* r0 = (const ushort2*)(xbf + j0*304);
            const ushort2* r1 = (const ushort2*)(xbf + j1*304);
            const ushort2* r2 = (const ushort2*)(xbf + j2*304);
            const ushort2* r3 = (const ushort2*)(xbf + j3*304);
            float2 v;
            v = bfp2f(r0[i0]); a0.x += al0*v.x; a0.y += al0*v.y;
            v = bfp2f(r1[i0]); a0.x += al1*v.x; a0.y += al1*v.y;
            v = bfp2f(r2[i0]); a0.x += al2*v.x; a0.y += al2*v.y;
            v = bfp2f(r3[i0]); a0.x += al3*v.x; a0.y += al3*v.y;
            v = bfp2f(r0[i1]); a1.x += al0*v.x; a1.y += al0*v.y;
            v = bfp2f(r1[i1]); a1.x += al1*v.x; a1.y += al1*v.y;
            v = bfp2f(r2[i1]); a1.x += al2*v.x; a1.y += al2*v.y;
            v = bfp2f(r3[i1]); a1.x += al3*v.x; a1.y += al3*v.y;
            if (t3) {
                v = bfp2f(r0[i2]); a2.x += al0*v.x; a2.y += al0*v.y;
                v = bfp2f(r1[i2]); a2.x += al1*v.x; a2.y += al1*v.y;
                v = bfp2f(r2[i2]); a2.x += al2*v.x; a2.y += al2*v.y;
                v = bfp2f(r3[i2]); a2.x += al3*v.x; a2.y += al3*v.y;
            }
        }
        for (; q < c; ++q) {
            float al; long j0;
            if (q < 64) { al = __shfl(pexp, q) * inv; j0 = __shfl(jc, q); }
            else {
                j0 = jp[beg + q];
                al = expf(leaky(base + sB[(int)j0] + rsc[relp[beg+q]]) - mx) * inv;
            }
            const ushort2* r0 = (const ushort2*)(xbf + j0*304);
            float2 v;
            v = bfp2f(r0[i0]); a0.x += al*v.x; a0.y += al*v.y;
            v = bfp2f(r0[i1]); a1.x += al*v.x; a1.y += al*v.y;
            if (t3) { v = bfp2f(r0[i2]); a2.x += al*v.x; a2.y += al*v.y; }
        }
    }
    // relu
    a0.x = fmaxf(a0.x, 0.0f); a0.y = fmaxf(a0.y, 0.0f);
    a1.x = fmaxf(a1.x, 0.0f); a1.y = fmaxf(a1.y, 0.0f);
    a2.x = fmaxf(a2.x, 0.0f); a2.y = fmaxf(a2.y, 0.0f);
    float2* dst = (float2*)(out + (long)w*ldo);
    dst[i0] = a0; dst[i1] = a1;
    if (t3) dst[i2] = a2;
    // r2e score dots over x6 = [x(0..299) from xbf row w, gat output]
    {
        const ushort2* xw = (const ushort2*)(xbf + (long)w*304);
        const float2* ahL = (const float2*)ah;            // cols 0..299
        const float2* atL = (const float2*)at;
        const float2* ahH = (const float2*)(ah + 300);    // cols 300..599
        const float2* atH = (const float2*)(at + 300);
        float2 x0 = bfp2f(xw[i0]), x1v = bfp2f(xw[i1]);
        float svh = x0.x*ahL[i0].x + x0.y*ahL[i0].y + x1v.x*ahL[i1].x + x1v.y*ahL[i1].y
                  + a0.x*ahH[i0].x + a0.y*ahH[i0].y + a1.x*ahH[i1].x + a1.y*ahH[i1].y;
        float svt = x0.x*atL[i0].x + x0.y*atL[i0].y + x1v.x*atL[i1].x + x1v.y*atL[i1].y
                  + a0.x*atH[i0].x + a0.y*atH[i0].y + a1.x*atH[i1].x + a1.y*atH[i1].y;
        if (t3) {
            float2 x2v = bfp2f(xw[i2]);
            svh += x2v.x*ahL[i2].x + x2v.y*ahL[i2].y + a2.x*ahH[i2].x + a2.y*ahH[i2].y;
            svt += x2v.x*atL[i2].x + x2v.y*atL[i2].y + a2.x*atH[i2].x + a2.y*atH[i2].y;
        }
        #pragma unroll
        for (int o = 32; o > 0; o >>= 1) {
            svh += __shfl_down(svh, o);
            svt += __shfl_down(svt, o);
        }
        if (lane == 0) { sh[w] = svh; st[w] = svt; }
    }
}

// r2e (both h and t halves in one launch): fused score + softmax + gather (F=100)
__global__ void k_gather_rel2(const float* __restrict__ xr,
                              const float* __restrict__ sH, const float* __restrict__ sT,
                              const float* __restrict__ srel,
                              const int* __restrict__ relpH, const int* __restrict__ rowptrH,
                              const int* __restrict__ cntH,
                              const int* __restrict__ relpT, const int* __restrict__ rowptrT,
                              const int* __restrict__ cntT,
                              float* __restrict__ out, long ldo, int n)
{
    int gw = (blockIdx.x*blockDim.x + threadIdx.x) >> 6;
    int lane = threadIdx.x & 63;
    if (gw >= 2*n) return;
    const bool isT = (gw >= n);
    const int w = isT ? gw - n : gw;
    const float* snode = isT ? sT : sH;
    const int* relp   = isT ? relpT   : relpH;
    const int* rowptr = isT ? rowptrT : rowptrH;
    const int* cnt    = isT ? cntT    : cntH;
    float* dst = out + (isT ? 700 : 600) + (long)w*ldo;
    int beg = rowptr[w], c = cnt[w];
    const bool t0 = (lane < 50);
    float2 a0 = {0,0};
    if (c > 0) {
        float base = snode[w];
        int   rc = 0;
        float sval = -3.4e38f;
        if (lane < c) {
            rc = relp[beg + lane];
            sval = leaky(base + srel[rc]);
        }
        float mx = sval;
        for (int t = 64 + lane; t < c; t += 64)
            mx = fmaxf(mx, leaky(base + srel[relp[beg+t]]));
        #pragma unroll
        for (int o = 32; o > 0; o >>= 1) mx = fmaxf(mx, __shfl_xor(mx, o));
        float pexp = (lane < c) ? expf(sval - mx) : 0.0f;
        float ss = pexp;
        for (int t = 64 + lane; t < c; t += 64)
            ss += expf(leaky(base + srel[relp[beg+t]]) - mx);
        #pragma unroll
        for (int o = 32; o > 0; o >>= 1) ss += __shfl_xor(ss, o);
        float inv = 1.0f / (ss + 1e-16f);
        int q = 0;
        int cc = (c < 64) ? c : 64;
        for (; q + 4 <= cc; q += 4) {
            float al0 = __shfl(pexp, q)   * inv;
            float al1 = __shfl(pexp, q+1) * inv;
            float al2 = __shfl(pexp, q+2) * inv;
            float al3 = __shfl(pexp, q+3) * inv;
            long r0i = __shfl(rc, q), r1i = __shfl(rc, q+1);
            long r2i = __shfl(rc, q+2), r3i = __shfl(rc, q+3);
            if (t0) {
                float2 v;
                v = ((const float2*)(xr + r0i*100))[lane]; a0.x += al0*v.x; a0.y += al0*v.y;
                v = ((const float2*)(xr + r1i*100))[lane]; a0.x += al1*v.x; a0.y += al1*v.y;
                v = ((const float2*)(xr + r2i*100))[lane]; a0.x += al2*v.x; a0.y += al2*v.y;
                v = ((const float2*)(xr + r3i*100))[lane]; a0.x += al3*v.x; a0.y += al3*v.y;
            }
        }
        for (; q < c; ++q) {
            float al; long r0i;
            if (q < 64) { al = __shfl(pexp, q) * inv; r0i = __shfl(rc, q); }
            else {
                r0i = relp[beg + q];
                al = expf(leaky(base + srel[(int)r0i]) - mx) * inv;
            }
            if (t0) {
                float2 v = ((const float2*)(xr + r0i*100))[lane];
                a0.x += al*v.x; a0.y += al*v.y;
            }
        }
    }
    if (t0) ((float2*)dst)[lane] = a0;
}

// ---------- highway combine (small R x RH path) ----------
__global__ void k_highway(const float* __restrict__ x1, long ld1,
                          const float* __restrict__ gl, long ldg,
                          const float* __restrict__ x2, long ld2,
                          const float* __restrict__ bias,
                          float* __restrict__ out, long ldo,
                          long rows, int F, int relu_x2)
{
    long idx = (long)blockIdx.x*blockDim.x + threadIdx.x;
    if (idx >= rows * (long)F) return;
    long r = idx / F; int c = (int)(idx % F);
    float g = 1.0f / (1.0f + expf(-(gl[r*ldg+c] + bias[c])));
    float v2 = x2[r*ld2+c]; if (relu_x2) v2 = fmaxf(v2, 0.0f);
    float v1 = x1[r*ld1+c];
    out[r*ldo+c] = g*v2 + (1.0f-g)*v1;
}

// ---------- segment softmax building blocks (small l_gat path only) ----------
__global__ void k_segmax(const float* __restrict__ ev, const int* __restrict__ idx,
                         unsigned* __restrict__ m, int E) {
    int e = blockIdx.x*blockDim.x + threadIdx.x;
    if (e < E) atomicMax(&m[idx[e]], f2mono(ev[e]));
}
__global__ void k_segsumexp(const float* __restrict__ ev, const int* __restrict__ idx,
                            const unsigned* __restrict__ m, float* __restrict__ s, int E) {
    int e = blockIdx.x*blockDim.x + threadIdx.x;
    if (e < E) atomicAdd(&s[idx[e]], expf(ev[e] - mono2f(m[idx[e]])));
}
__global__ void k_lgat_vsum(const float* __restrict__ val,
                            const int* __restrict__ jj, const int* __restrict__ ii,
                            const unsigned* __restrict__ mi, const float* __restrict__ si,
                            const unsigned* __restrict__ mj, const float* __restrict__ sj,
                            float* __restrict__ vsum, int E)
{
    int e = blockIdx.x*blockDim.x + threadIdx.x;
    if (e >= E) return;
    float v = val[e];
    int i = ii[e], j = jj[e];
    float pi = expf(v - mono2f(mi[i])) / (si[i] + 1e-16f);
    float pj = expf(v - mono2f(mj[j])) / (sj[j] + 1e-16f);
    vsum[e] = pi + pj;
}
__global__ void k_edge_agg(const float* __restrict__ ev,
                           const unsigned* __restrict__ m, const float* __restrict__ s,
                           const int* __restrict__ ka, const int* __restrict__ ko,
                           const int* __restrict__ ks,
                           const float* __restrict__ x, long ldx,
                           float* __restrict__ out, long ldo,
                           int E, int F)
{
    int w = (blockIdx.x*blockDim.x + threadIdx.x) >> 6;
    int lane = threadIdx.x & 63;
    if (w >= E) return;
    int a = ka[w];
    float alpha = expf(ev[w] - mono2f(m[a])) / (s[a] + 1e-16f);
    const float4* src = (const float4*)(x + (long)ks[w]*ldx);
    float* dst = out + (long)ko[w]*ldo;
    int nf4 = F >> 2;
    for (int f = lane; f < nf4; f += WAVE) {
        float4 v = src[f];
        atomicAdd(&dst[f*4+0], alpha*v.x);
        atomicAdd(&dst[f*4+1], alpha*v.y);
        atomicAdd(&dst[f*4+2], alpha*v.z);
        atomicAdd(&dst[f*4+3], alpha*v.w);
    }
}
__global__ void k_relu2d(float* __restrict__ p, long rows, int cols, long ld) {
    long idx = (long)blockIdx.x*blockDim.x + threadIdx.x;
    if (idx >= rows*(long)cols) return;
    long r = idx / cols; int c = (int)(idx % cols);
    float v = p[r*ld+c];
    p[r*ld+c] = fmaxf(v, 0.0f);
}

// ---------- row dots (small path: srel) ----------
__global__ void k_rowdot2(const float* __restrict__ x, long ldx, int rows, int K,
                          const float* __restrict__ a, const float* __restrict__ b,
                          float* __restrict__ oa, float* __restrict__ ob)
{
    int w = (blockIdx.x*blockDim.x + threadIdx.x) >> 6;
    int lane = threadIdx.x & 63;
    if (w >= rows) return;
    const float* xr = x + (long)w*ldx;
    float sa = 0.0f, sb = 0.0f;
    for (int k = lane; k < K; k += WAVE) {
        float v = xr[k];
        sa += v * a[k];
        if (b) sb += v * b[k];
    }
    #pragma unroll
    for (int off = 32; off > 0; off >>= 1) {
        sa += __shfl_down(sa, off);
        if (b) sb += __shfl_down(sb, off);
    }
    if (lane == 0) { oa[w] = sa; if (ob) ob[w] = sb; }
}

// ---------- relscore[r] = merge[r]·ar[0:RH] + tri[r]·ar[RH:2RH] ----------
__global__ void k_relscore(const float* __restrict__ mg, const float* __restrict__ tr,
                           const float* __restrict__ ar, float* __restrict__ out, int R, int RH)
{
    int w = (blockIdx.x*blockDim.x + threadIdx.x) >> 6;
    int lane = threadIdx.x & 63;
    if (w >= R) return;
    float s = 0.0f;
    for (int k = lane; k < RH; k += WAVE)
        s += mg[(long)w*RH+k]*ar[k] + tr[(long)w*RH+k]*ar[RH+k];
    #pragma unroll
    for (int off = 32; off > 0; off >>= 1) s += __shfl_down(s, off);
    if (lane == 0) out[w] = s;
}

extern "C" void kernel_launch(void* const* d_in, const int* in_sizes, int n_in,
                              void* d_out, int out_size, void* d_ws, size_t ws_size,
                              hipStream_t stream)
{
    const float* x_e   = (const float*)d_in[0];
    const float* mval  = (const float*)d_in[1];
    const float* tval  = (const float*)d_in[2];
    const float* g1w   = (const float*)d_in[3];
    const float* h1w   = (const float*)d_in[4];
    const float* h1b   = (const float*)d_in[5];
    const float* g2w   = (const float*)d_in[6];
    const float* h2w   = (const float*)d_in[7];
    const float* h2b   = (const float*)d_in[8];
    const float* remb1 = (const float*)d_in[9];
    const float* remb2 = (const float*)d_in[10];
    const float* hrw   = (const float*)d_in[11];
    const float* hrb   = (const float*)d_in[12];
    const float* gat_ai= (const float*)d_in[13];
    const float* gat_aj= (const float*)d_in[14];
    const float* gat_ar= (const float*)d_in[15];
    const float* g2e_ah= (const float*)d_in[16];
    const float* g2e_at= (const float*)d_in[17];
    const float* g2e_ar= (const float*)d_in[18];
    const int* edge_index     = (const int*)d_in[19];
    const int* rel            = (const int*)d_in[20];
    const int* edge_index_all = (const int*)d_in[21];
    const int* rel_all        = (const int*)d_in[22];
    const int* lg_merge       = (const int*)d_in[23];
    const int* lg_tri         = (const int*)d_in[24];

    const int F    = 300;
    const int RH   = 100;
    const int Kp   = 304;                  // padded K
    const int npk  = Kp / 16;              // 19 k-steps
    const int N    = in_sizes[0] / F;      // 100000 (multiple of 32)
    const int E    = in_sizes[20];         // 400000
    const int EA   = in_sizes[22];         // 800000
    const int LGE  = in_sizes[1];          // 60000
    const int R    = in_sizes[9] / RH;     // 2000
    const long OUTC = 800;
    const int Mpad = CDIV(N, 128) * 128;   // 100096
    const int NB   = 640;                  // fused B rows: W_g @0..299, W_h @320..619
    const long LDC = 640;                  // Ascr stride (shorts)

    const int* jA = edge_index_all;
    const int* iA = edge_index_all + EA;
    const int* hE = edge_index;
    const int* tE = edge_index + E;
    const int* jM = lg_merge;  const int* iM = lg_merge + LGE;
    const int* jT = lg_tri;    const int* iT = lg_tri  + LGE;

    float* ws = (float*)d_ws;
    size_t off = 0;
    auto alloc = [&](size_t n) { float* p = ws + off; off += (n + 3) & ~(size_t)3; return p; };
    unsigned short* Ascr = (unsigned short*)alloc((size_t)N*NB/2);        // GEMM out bf16 [N,640]
    unsigned short* Axb = (unsigned short*)alloc((size_t)Mpad*Kp/2);      // A packed single bf16
    unsigned short* xbf = (unsigned short*)alloc((size_t)N*304/2);        // row-major bf16 x
    unsigned short* Wh[2]; unsigned short* Wl[2];
    for (int i = 0; i < 2; ++i) {
        Wh[i] = (unsigned short*)alloc((size_t)NB*Kp/2);
        Wl[i] = (unsigned short*)alloc((size_t)NB*Kp/2);
    }
    float*    dinv = alloc(N);
    float*    sA_  = alloc(N);
    float*    sB_  = alloc(N);
    float*    sH_  = alloc(N);
    float*    sT_  = alloc(N);
    float*    mrg  = alloc((size_t)R*RH);
    float*    tri  = alloc((size_t)R*RH);
    float*    xr   = alloc((size_t)R*RH);
    float*    xrg  = alloc((size_t)R*RH);
    unsigned* lmi  = (unsigned*)alloc(R);  float* lsi = alloc(R);
    unsigned* lmj  = (unsigned*)alloc(R);  float* lsj = alloc(R);
    unsigned* lm2  = (unsigned*)alloc(R);  float* ls2 = alloc(R);
    float*    vsum = alloc(LGE);
    float*    rsc  = alloc(R);
    float*    srel = alloc(R);
    int*   bsum    = (int*)alloc(1024);
    int*   cursor  = (int*)alloc(N);
    int*   rowptrA = (int*)alloc(N); int* cntA = (int*)alloc(N); int* permA = (int*)alloc(EA);
    int*   rowptrH = (int*)alloc(N); int* cntH = (int*)alloc(N); int* permH = (int*)alloc(E);
    int*   rowptrT = (int*)alloc(N); int* cntT = (int*)alloc(N); int* permT = (int*)alloc(E);
    int*   jpA     = (int*)alloc(EA);
    float* nmA     = alloc(EA);
    int*   relpA   = (int*)alloc(EA);
    int*   relpH   = (int*)alloc(E);
    int*   relpT   = (int*)alloc(E);

    float* out = (float*)d_out;              // [N, 800]

    const int  nb = CDIV(N, 256);
    const int  nrb = CDIV(N, 128);                 // 782 row panels
    const int  gemmBlocks = 8 * CDIV(nrb, 8) * 5;  // XCD-ownership swizzled grid
    const int gatherGrid = CDIV(N, 4);
    const int cvtBigGrid = CDIV((long)N * (Kp/4), 256);
    const int cvtWGrid   = CDIV(300 * (Kp/4), 256);

    auto build_csr = [&](const int* key, int E_, int* rowptr, int* cnt, int* perm) {
        hipMemsetAsync(cnt, 0, (size_t)N*4, stream);
        k_hist<<<CDIV(E_,256),256,0,stream>>>(key, cnt, E_);
        k_scan1<<<nb,256,0,stream>>>(cnt, rowptr, bsum, N);
        k_scan2<<<1,1024,0,stream>>>(bsum, nb);
        k_scan3<<<nb,256,0,stream>>>(rowptr, bsum, N);
        hipMemsetAsync(cursor, 0, (size_t)N*4, stream);
        k_fill<<<CDIV(E_,256),256,0,stream>>>(key, rowptr, cursor, perm, E_);
    };

    // ===== zero pads, then fragment-pack converts (fused W: g @0, h @320) =====
    for (int i = 0; i < 2; ++i) {
        hipMemsetAsync(Wh[i], 0, (size_t)NB*Kp*2, stream);
        hipMemsetAsync(Wl[i], 0, (size_t)NB*Kp*2, stream);
    }
    hipMemsetAsync(Axb + (size_t)N*Kp, 0, (size_t)(Mpad-N)*Kp*2, stream);
    k_cvt_pack<<<cvtWGrid,256,0,stream>>>(g1w, 300, 300, 300, npk, 0,   Wh[0], Wl[0]);
    k_cvt_pack<<<cvtWGrid,256,0,stream>>>(h1w, 300, 300, 300, npk, 320, Wh[0], Wl[0]);
    k_cvt_pack<<<cvtWGrid,256,0,stream>>>(g2w, 300, 300, 300, npk, 0,   Wh[1], Wl[1]);
    k_cvt_pack<<<cvtWGrid,256,0,stream>>>(h2w, 300, 300, 300, npk, 320, Wh[1], Wl[1]);
    k_cvt_pack1<<<cvtBigGrid,256,0,stream>>>(x_e, 300, N, 300, npk, Axb);

    // ===== CSRs + pre-permutes =====
    build_csr(iA, EA, rowptrA, cntA, permA);
    build_csr(hE, E,  rowptrH, cntH, permH);
    build_csr(tE, E,  rowptrT, cntT, permT);
    k_dinv_cnt<<<CDIV(N,256),256,0,stream>>>(cntA, dinv, N);
    k_prep_gcn<<<CDIV(EA,256),256,0,stream>>>(permA, jA, iA, dinv, jpA, nmA, EA);
    k_permute_mod<<<CDIV(EA,256),256,0,stream>>>(rel_all, permA, relpA, EA, R);
    k_permute_i32<<<CDIV(E,256),256,0,stream>>>(rel, permH, relpH, E);
    k_permute_i32<<<CDIV(E,256),256,0,stream>>>(rel, permT, relpT, E);

    // ===== GCN layer 1: fused double-GEMM (bf16 out) + gather/highway/pack =====
    k_gemm_frag<<<gemmBlocks,256,0,stream>>>(Axb, Wh[0], Wl[0], Ascr, LDC, N, 620, npk, nrb);
    k_gather_hw<<<gatherGrid,256,0,stream>>>(Ascr, LDC, Ascr+320, x_e, 300, h1b,
                                             jpA, nmA, rowptrA, cntA,
                                             out, OUTC, Axb,
                                             (unsigned short*)nullptr,
                                             (const float*)nullptr, (const float*)nullptr,
                                             (float*)nullptr, (float*)nullptr, npk, N);

    // ===== GCN layer 2: + xbf emit + GAT score dots =====
    k_gemm_frag<<<gemmBlocks,256,0,stream>>>(Axb, Wh[1], Wl[1], Ascr, LDC, N, 620, npk, nrb);
    k_gather_hw<<<gatherGrid,256,0,stream>>>(Ascr, LDC, Ascr+320, out, OUTC, h2b,
                                             jpA, nmA, rowptrA, cntA,
                                             out, OUTC,
                                             (unsigned short*)nullptr,
                                             xbf, gat_ai, gat_aj, sA_, sB_, npk, N);

    // ===== l_gat on the two line graphs (small; atomic path) =====
    auto lgat = [&](const float* xrel, const int* jjE, const int* iiE, const float* val, float* obuf) {
        hipMemsetAsync(lmi, 0, R*4, stream); hipMemsetAsync(lsi, 0, R*4, stream);
        hipMemsetAsync(lmj, 0, R*4, stream); hipMemsetAsync(lsj, 0, R*4, stream);
        hipMemsetAsync(lm2, 0, R*4, stream); hipMemsetAsync(ls2, 0, R*4, stream);
        hipMemsetAsync(obuf, 0, (size_t)R*RH*4, stream);
        k_segmax   <<<CDIV(LGE,256),256,0,stream>>>(val, iiE, lmi, LGE);
        k_segmax   <<<CDIV(LGE,256),256,0,stream>>>(val, jjE, lmj, LGE);
        k_segsumexp<<<CDIV(LGE,256),256,0,stream>>>(val, iiE, lmi, lsi, LGE);
        k_segsumexp<<<CDIV(LGE,256),256,0,stream>>>(val, jjE, lmj, lsj, LGE);
        k_lgat_vsum<<<CDIV(LGE,256),256,0,stream>>>(val, jjE, iiE, lmi, lsi, lmj, lsj, vsum, LGE);
        k_segmax   <<<CDIV(LGE,256),256,0,stream>>>(vsum, jjE, lm2, LGE);
        k_segsumexp<<<CDIV(LGE,256),256,0,stream>>>(vsum, jjE, lm2, ls2, LGE);
        k_edge_agg <<<(int)CDIV((long)LGE*64,256),256,0,stream>>>(vsum, lm2, ls2, jjE, iiE, jjE,
                                                                  xrel, RH, obuf, RH, LGE, RH);
        k_relu2d   <<<CDIV((long)R*RH,256),256,0,stream>>>(obuf, R, RH, RH);
    };
    lgat(remb1, jM, iM, mval, mrg);
    lgat(remb2, jT, iT, tval, tri);

    // ===== x_r = highway(mrg, tri, hrw, hrb) =====
    dim3 gridR(CDIV(RH,GBN), CDIV(R,GBM));
    k_gemm<<<gridR,256,0,stream>>>(mrg, RH, hrw, RH, xrg, RH, R, RH, RH);
    k_highway<<<CDIV((long)R*RH,256),256,0,stream>>>(mrg, RH, xrg, RH, tri, RH, hrb, xr, RH, R, RH, 0);

    // relscore[r] = rel_cat[r]·gat_ar
    k_relscore<<<CDIV((long)R*64,256),256,0,stream>>>(mrg, tri, gat_ar, rsc, R, RH);

    // ===== GAT -> out cols 300..599 + r2e score dots (fully fused) =====
    k_gat300<<<gatherGrid,256,0,stream>>>(xbf, sA_, sB_, rsc, jpA, relpA,
                                          rowptrA, cntA, out+300, OUTC,
                                          g2e_ah, g2e_at, sH_, sT_, N);

    // ===== gat_r_to_e over edge_index -> out cols 600..799 (h+t merged) =====
    k_rowdot2<<<CDIV((long)R*64,256),256,0,stream>>>(xr, RH, R, RH, g2e_ar, (const float*)nullptr,
                                                     srel, (float*)nullptr);
    k_gather_rel2<<<CDIV(2*N,4),256,0,stream>>>(xr, sH_, sT_, srel,
                                                relpH, rowptrH, cntH,
                                                relpT, rowptrT, cntT,
                                                out, OUTC, N);
}

// Round 12
// 1227.476 us; speedup vs baseline: 1.3700x; 1.1931x over previous
//
#include <hip/hip_runtime.h>

#define WAVE 64
#define CDIV(a,b) (((a)+(b)-1)/(b))

typedef float f32x16 __attribute__((ext_vector_type(16)));
typedef unsigned short u16x8 __attribute__((ext_vector_type(8)));

// ---------- bf16 helpers ----------
__device__ __forceinline__ unsigned short f2bf_rne(float f) {
    unsigned u = __float_as_uint(f);
    unsigned r = (u + 0x7FFFu + ((u >> 16) & 1u)) >> 16;
    return (unsigned short)r;
}
__device__ __forceinline__ float bf2f(unsigned short h) {
    return __uint_as_float(((unsigned)h) << 16);
}
__device__ __forceinline__ float2 bfp2f(ushort2 u) {
    float2 r; r.x = bf2f(u.x); r.y = bf2f(u.y); return r;
}
__device__ __forceinline__ float sigm(float x) { return 1.0f / (1.0f + expf(-x)); }

#define MFMA32(acc, a, b) \
    asm volatile("v_mfma_f32_32x32x16_bf16 %0, %1, %2, %0" : "+v"(acc) : "v"(a), "v"(b))

// ---------- monotonic float<->uint encoding for atomicMax on floats ----------
__device__ __forceinline__ unsigned f2mono(float f) {
    unsigned u = __float_as_uint(f);
    return (u & 0x80000000u) ? ~u : (u | 0x80000000u);
}
__device__ __forceinline__ float mono2f(unsigned u) {
    return (u & 0x80000000u) ? __uint_as_float(u & 0x7fffffffu) : __uint_as_float(~u);
}
__device__ __forceinline__ float leaky(float v) { return (v > 0.0f) ? v : 0.01f*v; }

// fragment-pack offset: matrix row r, col k -> packed short index.
__device__ __forceinline__ long fragoff(long r, int k, int npk) {
    return ((r >> 5) * (long)npk + (k >> 4)) * 512
         + (((k >> 3) & 1) << 8) + ((r & 31) << 3) + (k & 7);
}

// ---------- k_cvt_pack1: f32 -> fragment-packed single bf16 (rne) ----------
__global__ void k_cvt_pack1(const float* __restrict__ src, long ld, int rows, int K, int npk,
                            int roff, unsigned short* __restrict__ dst)
{
    int nc4 = npk << 2;
    long idx = (long)blockIdx.x*blockDim.x + threadIdx.x;
    if (idx >= (long)rows * nc4) return;
    long r = idx / nc4; int k = (int)(idx % nc4) << 2;
    float4 v = {0.0f, 0.0f, 0.0f, 0.0f};
    if (k + 4 <= K) v = *(const float4*)(src + r*ld + k);
    ushort4 h;
    h.x = f2bf_rne(v.x); h.y = f2bf_rne(v.y); h.z = f2bf_rne(v.z); h.w = f2bf_rne(v.w);
    *(ushort4*)(dst + fragoff(r + roff, k, npk)) = h;
}

// =========================================================================
// k_gemm_frag: C[M,620] (bf16) = A * B^T; A and B single bf16 (rne).
// NO LDS, NO barriers. XCD-ownership swizzle. 4 MFMA / 5 loads per k-step.
// =========================================================================
__global__ __launch_bounds__(256, 3)
void k_gemm_frag(const unsigned short* __restrict__ Ab,
                 const unsigned short* __restrict__ Bb,
                 unsigned short* __restrict__ C, long ldc, int M, int N, int nk, int nrb)
{
    const int lane = threadIdx.x & 63;
    const int wid  = threadIdx.x >> 6;
    const int lin  = blockIdx.x;
    const int xcd  = lin & 7;
    const int m    = lin >> 3;
    const int col0 = (m % 5) * 128;
    const int rb   = xcd + ((m / 5) << 3);
    if (rb >= nrb) return;
    const int row0 = rb * 128 + wid * 32;

    const long cs = (long)nk * 512;
    const unsigned short* pA = Ab + (long)(row0 >> 5) * cs + lane * 8;
    const unsigned short* pB = Bb + (long)(col0 >> 5) * cs + lane * 8;

    f32x16 acc[4];
    #pragma unroll
    for (int c = 0; c < 4; ++c) acc[c] = (f32x16)0.0f;

    u16x8 pa, pb0, pb1, pb2, pb3;
    u16x8 qa, qb0, qb1, qb2, qb3;

    #define LOADP(t_) { long o = (long)(t_)*512;                                   \
        pa  = *(const u16x8*)(pA + o);                                             \
        pb0 = *(const u16x8*)(pB + o);        pb1 = *(const u16x8*)(pB + cs + o);  \
        pb2 = *(const u16x8*)(pB + 2*cs + o); pb3 = *(const u16x8*)(pB + 3*cs + o); }
    #define LOADQ(t_) { long o = (long)(t_)*512;                                   \
        qa  = *(const u16x8*)(pA + o);                                             \
        qb0 = *(const u16x8*)(pB + o);        qb1 = *(const u16x8*)(pB + cs + o);  \
        qb2 = *(const u16x8*)(pB + 2*cs + o); qb3 = *(const u16x8*)(pB + 3*cs + o); }
    #define STEPP {                                                                 \
        MFMA32(acc[0], pa, pb0); MFMA32(acc[1], pa, pb1);                           \
        MFMA32(acc[2], pa, pb2); MFMA32(acc[3], pa, pb3); }
    #define STEPQ {                                                                 \
        MFMA32(acc[0], qa, qb0); MFMA32(acc[1], qa, qb1);                           \
        MFMA32(acc[2], qa, qb2); MFMA32(acc[3], qa, qb3); }

    LOADP(0);
    int t = 0;
    for (;;) {
        bool m1 = (t + 1 < nk);
        if (m1) LOADQ(t + 1);
        STEPP;
        if (!m1) break;
        bool m2 = (t + 2 < nk);
        if (m2) LOADP(t + 2);
        STEPQ;
        if (!m2) break;
        t += 2;
    }
    #undef LOADP
    #undef LOADQ
    #undef STEPP
    #undef STEPQ

    const int crow0 = row0 + 4*(lane >> 5);
    const int ccol0 = col0 + (lane & 31);
    #pragma unroll
    for (int c = 0; c < 4; ++c) {
        int col = ccol0 + c*32;
        if (col >= N) continue;
        #pragma unroll
        for (int reg = 0; reg < 16; ++reg) {
            int row = crow0 + (reg & 3) + 8*(reg >> 2);
            if (row < M) C[(long)row*ldc + col] = f2bf_rne(acc[c][reg]);
        }
    }
}

// ---------- small f32 GEMM (tiny R x RH highway gate) ----------
#define GBM 64
#define GBN 64
#define GBK 16
__global__ __launch_bounds__(256)
void k_gemm(const float* __restrict__ A, long lda,
            const float* __restrict__ B, long ldb,
            float* __restrict__ C, long ldc,
            int M, int N, int K)
{
    __shared__ float As[GBK][GBM + 4];
    __shared__ float Bs[GBK][GBN + 4];
    const int tid = threadIdx.x;
    const int tx = tid & 15, ty = tid >> 4;
    const int row0 = blockIdx.y * GBM, col0 = blockIdx.x * GBN;
    float acc[4][4] = {};
    for (int kt = 0; kt < K; kt += GBK) {
        #pragma unroll
        for (int p = 0; p < 4; ++p) {
            int mn = (tid >> 4) + p * 16;
            int k  = tid & 15;
            int gk = kt + k;
            int gr = row0 + mn;
            As[k][mn] = (gr < M && gk < K) ? A[(long)gr * lda + gk] : 0.0f;
            int gc = col0 + mn;
            Bs[k][mn] = (gc < N && gk < K) ? B[(long)gc * ldb + gk] : 0.0f;
        }
        __syncthreads();
        #pragma unroll
        for (int kk = 0; kk < GBK; ++kk) {
            float a0 = As[kk][ty*4+0], a1 = As[kk][ty*4+1];
            float a2 = As[kk][ty*4+2], a3 = As[kk][ty*4+3];
            float b0 = Bs[kk][tx*4+0], b1 = Bs[kk][tx*4+1];
            float b2 = Bs[kk][tx*4+2], b3 = Bs[kk][tx*4+3];
            acc[0][0] += a0*b0; acc[0][1] += a0*b1; acc[0][2] += a0*b2; acc[0][3] += a0*b3;
            acc[1][0] += a1*b0; acc[1][1] += a1*b1; acc[1][2] += a1*b2; acc[1][3] += a1*b3;
            acc[2][0] += a2*b0; acc[2][1] += a2*b1; acc[2][2] += a2*b2; acc[2][3] += a2*b3;
            acc[3][0] += a3*b0; acc[3][1] += a3*b1; acc[3][2] += a3*b2; acc[3][3] += a3*b3;
        }
        __syncthreads();
    }
    #pragma unroll
    for (int i2 = 0; i2 < 4; ++i2)
        #pragma unroll
        for (int j2 = 0; j2 < 4; ++j2) {
            int r = row0 + ty*4 + i2, c = col0 + tx*4 + j2;
            if (r < M && c < N) C[(long)r*ldc + c] = acc[i2][j2];
        }
}

// ================= merged CSR build over 3 graphs =================
__global__ void k_hist3(const int* __restrict__ iA, const int* __restrict__ hE,
                        const int* __restrict__ tE, int* __restrict__ cnt,
                        int EA, int E, int N) {
    int e = blockIdx.x*blockDim.x + threadIdx.x;
    int tot = EA + 2*E;
    if (e >= tot) return;
    if (e < EA)            atomicAdd(&cnt[iA[e]], 1);
    else if (e < EA + E)   atomicAdd(&cnt[N + hE[e - EA]], 1);
    else                   atomicAdd(&cnt[2*N + tE[e - EA - E]], 1);
}
__global__ void k_scan1(const int* __restrict__ in, int* __restrict__ out,
                        int* __restrict__ bsum, int n) {
    __shared__ int sh[512];
    int gid = blockIdx.x*512 + threadIdx.x;
    int v = (gid < n) ? in[gid] : 0;
    sh[threadIdx.x] = v; __syncthreads();
    for (int o = 1; o < 512; o <<= 1) {
        int t = (threadIdx.x >= o) ? sh[threadIdx.x - o] : 0;
        __syncthreads();
        sh[threadIdx.x] += t;
        __syncthreads();
    }
    if (gid < n) out[gid] = sh[threadIdx.x] - v;      // exclusive
    if (threadIdx.x == 511) bsum[blockIdx.x] = sh[511];
}
__global__ void k_scan2(int* __restrict__ bsum, int nb) {   // single block, nb <= 1024
    __shared__ int sh[1024];
    int v = (threadIdx.x < nb) ? bsum[threadIdx.x] : 0;
    sh[threadIdx.x] = v; __syncthreads();
    for (int o = 1; o < 1024; o <<= 1) {
        int t = (threadIdx.x >= o) ? sh[threadIdx.x - o] : 0;
        __syncthreads();
        sh[threadIdx.x] += t;
        __syncthreads();
    }
    if (threadIdx.x < nb) bsum[threadIdx.x] = sh[threadIdx.x] - v;  // exclusive
}
__global__ void k_scan3(int* __restrict__ out, const int* __restrict__ bsum, int n) {
    int gid = blockIdx.x*512 + threadIdx.x;
    if (gid < n) out[gid] += bsum[blockIdx.x];
}
__global__ void k_fill3(const int* __restrict__ iA, const int* __restrict__ hE,
                        const int* __restrict__ tE, const int* __restrict__ rowptr,
                        int* __restrict__ cursor, int* __restrict__ perm,
                        int EA, int E, int N) {
    int e = blockIdx.x*blockDim.x + threadIdx.x;
    int tot = EA + 2*E;
    if (e >= tot) return;
    int key, le;
    if (e < EA)          { le = e;          key = iA[le]; }
    else if (e < EA + E) { le = e - EA;     key = N + hE[le]; }
    else                 { le = e - EA - E; key = 2*N + tE[le]; }
    int p = rowptr[key] + atomicAdd(&cursor[key], 1);
    perm[p] = le;
}
__global__ void k_dinv_cnt(const int* __restrict__ cnt, float* __restrict__ dinv, int n) {
    int i = blockIdx.x*blockDim.x + threadIdx.x;
    if (i < n) { int c = cnt[i]; dinv[i] = (c > 0) ? rsqrtf((float)c) : 0.0f; }
}
__global__ void k_prep_gcn(const int* __restrict__ perm, const int* __restrict__ jA,
                           const int* __restrict__ iA, const float* __restrict__ dinv,
                           int* __restrict__ jp, float* __restrict__ nm, int E) {
    int p = blockIdx.x*blockDim.x + threadIdx.x;
    if (p >= E) return;
    int e = perm[p];
    int j = jA[e];
    jp[p] = j;
    nm[p] = dinv[iA[e]] * dinv[j];
}
// merged rel permute: region A (rel_all % R), regions H/T (rel, local ids)
__global__ void k_permute3(const int* __restrict__ rel_all, const int* __restrict__ rel,
                           const int* __restrict__ perm, int* __restrict__ relp,
                           int EA, int E, int R) {
    int p = blockIdx.x*blockDim.x + threadIdx.x;
    int tot = EA + 2*E;
    if (p >= tot) return;
    if (p < EA) relp[p] = rel_all[perm[p]] % R;
    else        relp[p] = rel[perm[p]];
}

// =========================================================================
// k_gather_hw: fused GCN gather (bf16 src) + relu + highway + extras.
// x1 comes from f32 (x1f) or bf16 row-major stride 304 (x1b).
// =========================================================================
__global__ void k_gather_hw(const unsigned short* __restrict__ xg, long ldx,
                            const unsigned short* __restrict__ gl,
                            const float* __restrict__ x1f,
                            const unsigned short* __restrict__ x1b, long ld1,
                            const float* __restrict__ bias,
                            const int* __restrict__ jp, const float* __restrict__ nm,
                            const int* __restrict__ rowptr, const int* __restrict__ cnt,
                            float* __restrict__ outp, long ldo,
                            unsigned short* __restrict__ pk,
                            unsigned short* __restrict__ xbf,
                            const float* __restrict__ ai, const float* __restrict__ aj,
                            float* __restrict__ sa, float* __restrict__ sb,
                            int npk, int n)
{
    int w = (blockIdx.x*blockDim.x + threadIdx.x) >> 6;
    int lane = threadIdx.x & 63;
    if (w >= n) return;
    int beg = rowptr[w], end = beg + cnt[w];
    const int i0 = lane, i1 = lane + 64, i2 = lane + 128;
    const bool t3 = (lane < 22);
    float2 a0 = {0,0}, a1 = {0,0}, a2 = {0,0};
    int e = beg;
    for (; e + 4 <= end; e += 4) {
        const ushort2* r0 = (const ushort2*)(xg + (long)jp[e]  *ldx);
        const ushort2* r1 = (const ushort2*)(xg + (long)jp[e+1]*ldx);
        const ushort2* r2 = (const ushort2*)(xg + (long)jp[e+2]*ldx);
        const ushort2* r3 = (const ushort2*)(xg + (long)jp[e+3]*ldx);
        float w0 = nm[e], w1 = nm[e+1], w2 = nm[e+2], w3 = nm[e+3];
        float2 v;
        v = bfp2f(r0[i0]); a0.x += w0*v.x; a0.y += w0*v.y;
        v = bfp2f(r1[i0]); a0.x += w1*v.x; a0.y += w1*v.y;
        v = bfp2f(r2[i0]); a0.x += w2*v.x; a0.y += w2*v.y;
        v = bfp2f(r3[i0]); a0.x += w3*v.x; a0.y += w3*v.y;
        v = bfp2f(r0[i1]); a1.x += w0*v.x; a1.y += w0*v.y;
        v = bfp2f(r1[i1]); a1.x += w1*v.x; a1.y += w1*v.y;
        v = bfp2f(r2[i1]); a1.x += w2*v.x; a1.y += w2*v.y;
        v = bfp2f(r3[i1]); a1.x += w3*v.x; a1.y += w3*v.y;
        if (t3) {
            v = bfp2f(r0[i2]); a2.x += w0*v.x; a2.y += w0*v.y;
            v = bfp2f(r1[i2]); a2.x += w1*v.x; a2.y += w1*v.y;
            v = bfp2f(r2[i2]); a2.x += w2*v.x; a2.y += w2*v.y;
            v = bfp2f(r3[i2]); a2.x += w3*v.x; a2.y += w3*v.y;
        }
    }
    for (; e < end; ++e) {
        const ushort2* r0 = (const ushort2*)(xg + (long)jp[e]*ldx);
        float w0 = nm[e];
        float2 v;
        v = bfp2f(r0[i0]); a0.x += w0*v.x; a0.y += w0*v.y;
        v = bfp2f(r0[i1]); a1.x += w0*v.x; a1.y += w0*v.y;
        if (t3) { v = bfp2f(r0[i2]); a2.x += w0*v.x; a2.y += w0*v.y; }
    }
    // highway: o = sig(gl+b)*relu(acc) + (1-sig)*x1
    const ushort2* glr = (const ushort2*)(gl + (long)w*ldx);
    const float2*  x1r = (const float2*)(x1f + (long)w*ld1);
    const ushort2* x1r2 = (const ushort2*)(x1b + (long)w*304);
    const float2*  br  = (const float2*)bias;
    float2 o0 = {0,0}, o1 = {0,0}, o2 = {0,0};
    {
        float2 gv = bfp2f(glr[i0]); float2 bv = br[i0];
        float2 xv = x1f ? x1r[i0] : bfp2f(x1r2[i0]);
        float g0 = sigm(gv.x + bv.x), g1 = sigm(gv.y + bv.y);
        o0.x = g0*fmaxf(a0.x,0.0f) + (1.0f-g0)*xv.x;
        o0.y = g1*fmaxf(a0.y,0.0f) + (1.0f-g1)*xv.y;
    }
    {
        float2 gv = bfp2f(glr[i1]); float2 bv = br[i1];
        float2 xv = x1f ? x1r[i1] : bfp2f(x1r2[i1]);
        float g0 = sigm(gv.x + bv.x), g1 = sigm(gv.y + bv.y);
        o1.x = g0*fmaxf(a1.x,0.0f) + (1.0f-g0)*xv.x;
        o1.y = g1*fmaxf(a1.y,0.0f) + (1.0f-g1)*xv.y;
    }
    if (t3) {
        float2 gv = bfp2f(glr[i2]); float2 bv = br[i2];
        float2 xv = x1f ? x1r[i2] : bfp2f(x1r2[i2]);
        float g0 = sigm(gv.x + bv.x), g1 = sigm(gv.y + bv.y);
        o2.x = g0*fmaxf(a2.x,0.0f) + (1.0f-g0)*xv.x;
        o2.y = g1*fmaxf(a2.y,0.0f) + (1.0f-g1)*xv.y;
    }
    if (outp) {
        float2* dst = (float2*)(outp + (long)w*ldo);
        dst[i0] = o0; dst[i1] = o1;
        if (t3) dst[i2] = o2;
    }
    if (pk) {   // single-bf16 fragment pack for the next GEMM's A
        auto pack2 = [&](int k, float2 o) {
            ushort2 hv; hv.x = f2bf_rne(o.x); hv.y = f2bf_rne(o.y);
            *(ushort2*)(pk + fragoff(w, k, npk)) = hv;
        };
        pack2(2*lane, o0);
        pack2(128 + 2*lane, o1);
        if (t3) pack2(256 + 2*lane, o2);
        else if (lane < 24) {
            ushort2 z = {0,0};
            *(ushort2*)(pk + fragoff(w, 256 + 2*lane, npk)) = z;
        }
    }
    if (xbf) {  // row-major bf16 copy (stride 304 shorts)
        ushort2* xw = (ushort2*)(xbf + (long)w*304);
        ushort2 t;
        t.x = f2bf_rne(o0.x); t.y = f2bf_rne(o0.y); xw[i0] = t;
        t.x = f2bf_rne(o1.x); t.y = f2bf_rne(o1.y); xw[i1] = t;
        if (t3) { t.x = f2bf_rne(o2.x); t.y = f2bf_rne(o2.y); xw[i2] = t; }
    }
    if (sa) {   // GAT score dots
        const float2* ai2 = (const float2*)ai;
        const float2* aj2 = (const float2*)aj;
        float2 A0 = ai2[i0], A1 = ai2[i1], J0 = aj2[i0], J1 = aj2[i1];
        float sva = o0.x*A0.x + o0.y*A0.y + o1.x*A1.x + o1.y*A1.y;
        float svb = o0.x*J0.x + o0.y*J0.y + o1.x*J1.x + o1.y*J1.y;
        if (t3) {
            float2 A2 = ai2[i2], J2 = aj2[i2];
            sva += o2.x*A2.x + o2.y*A2.y;
            svb += o2.x*J2.x + o2.y*J2.y;
        }
        #pragma unroll
        for (int o = 32; o > 0; o >>= 1) {
            sva += __shfl_down(sva, o);
            svb += __shfl_down(svb, o);
        }
        if (lane == 0) { sa[w] = sva; sb[w] = svb; }
    }
}

// =========================================================================
// k_gat300: fused edge score + segment softmax + weighted gather (bf16)
// + relu -> out cols 300..599, PLUS r2e score dots.
// =========================================================================
__global__ void k_gat300(const unsigned short* __restrict__ xbf,
                         const float* __restrict__ sA, const float* __restrict__ sB,
                         const float* __restrict__ rsc,
                         const int* __restrict__ jp, const int* __restrict__ relp,
                         const int* __restrict__ rowptr, const int* __restrict__ cnt,
                         float* __restrict__ out, long ldo,
                         const float* __restrict__ ah, const float* __restrict__ at,
                         float* __restrict__ sh, float* __restrict__ st,
                         int n)
{
    int w = (blockIdx.x*blockDim.x + threadIdx.x) >> 6;
    int lane = threadIdx.x & 63;
    if (w >= n) return;
    int beg = rowptr[w], c = cnt[w];
    const int i0 = lane, i1 = lane + 64, i2 = lane + 128;
    const bool t3 = (lane < 22);
    float2 a0 = {0,0}, a1 = {0,0}, a2 = {0,0};
    if (c > 0) {
        float base = sA[w];
        int   jc = 0;
        float sval = -3.4e38f;
        if (lane < c) {
            jc = jp[beg + lane];
            sval = leaky(base + sB[jc] + rsc[relp[beg + lane]]);
        }
        float mx = sval;
        for (int t = 64 + lane; t < c; t += 64)
            mx = fmaxf(mx, leaky(base + sB[jp[beg+t]] + rsc[relp[beg+t]]));
        #pragma unroll
        for (int o = 32; o > 0; o >>= 1) mx = fmaxf(mx, __shfl_xor(mx, o));
        float pexp = (lane < c) ? expf(sval - mx) : 0.0f;
        float ss = pexp;
        for (int t = 64 + lane; t < c; t += 64)
            ss += expf(leaky(base + sB[jp[beg+t]] + rsc[relp[beg+t]]) - mx);
        #pragma unroll
        for (int o = 32; o > 0; o >>= 1) ss += __shfl_xor(ss, o);
        float inv = 1.0f / (ss + 1e-16f);
        int q = 0;
        int cc = (c < 64) ? c : 64;
        for (; q + 4 <= cc; q += 4) {
            float al0 = __shfl(pexp, q)   * inv;
            float al1 = __shfl(pexp, q+1) * inv;
            float al2 = __shfl(pexp, q+2) * inv;
            float al3 = __shfl(pexp, q+3) * inv;
            long  j0 = __shfl(jc, q), j1 = __shfl(jc, q+1);
            long  j2 = __shfl(jc, q+2), j3 = __shfl(jc, q+3);
            const ushort2* r0 = (const ushort2*)(xbf + j0*304);
            const ushort2* r1 = (const ushort2*)(xbf + j1*304);
            const ushort2* r2 = (const ushort2*)(xbf + j2*304);
            const ushort2* r3 = (const ushort2*)(xbf + j3*304);
            float2 v;
            v = bfp2f(r0[i0]); a0.x += al0*v.x; a0.y += al0*v.y;
            v = bfp2f(r1[i0]); a0.x += al1*v.x; a0.y += al1*v.y;
            v = bfp2f(r2[i0]); a0.x += al2*v.x; a0.y += al2*v.y;
            v = bfp2f(r3[i0]); a0.x += al3*v.x; a0.y += al3*v.y;
            v = bfp2f(r0[i1]); a1.x += al0*v.x; a1.y += al0*v.y;
            v = bfp2f(r1[i1]); a1.x += al1*v.x; a1.y += al1*v.y;
            v = bfp2f(r2[i1]); a1.x += al2*v.x; a1.y += al2*v.y;
            v = bfp2f(r3[i1]); a1.x += al3*v.x; a1.y += al3*v.y;
            if (t3) {
                v = bfp2f(r0[i2]); a2.x += al0*v.x; a2.y += al0*v.y;
                v = bfp2f(r1[i2]); a2.x += al1*v.x; a2.y += al1*v.y;
                v = bfp2f(r2[i2]); a2.x += al2*v.x; a2.y += al2*v.y;
                v = bfp2f(r3[i2]); a2.x += al3*v.x; a2.y += al3*v.y;
            }
        }
        for (; q < c; ++q) {
            float al; long j0;
            if (q < 64) { al = __shfl(pexp, q) * inv; j0 = __shfl(jc, q); }
            else {
                j0 = jp[beg + q];
                al = expf(leaky(base + sB[(int)j0] + rsc[relp[beg+q]]) - mx) * inv;
            }
            const ushort2* r0 = (const ushort2*)(xbf + j0*304);
            float2 v;
            v = bfp2f(r0[i0]); a0.x += al*v.x; a0.y += al*v.y;
            v = bfp2f(r0[i1]); a1.x += al*v.x; a1.y += al*v.y;
            if (t3) { v = bfp2f(r0[i2]); a2.x += al*v.x; a2.y += al*v.y; }
        }
    }
    a0.x = fmaxf(a0.x, 0.0f); a0.y = fmaxf(a0.y, 0.0f);
    a1.x = fmaxf(a1.x, 0.0f); a1.y = fmaxf(a1.y, 0.0f);
    a2.x = fmaxf(a2.x, 0.0f); a2.y = fmaxf(a2.y, 0.0f);
    float2* dst = (float2*)(out + (long)w*ldo);
    dst[i0] = a0; dst[i1] = a1;
    if (t3) dst[i2] = a2;
    {
        const ushort2* xw = (const ushort2*)(xbf + (long)w*304);
        const float2* ahL = (const float2*)ah;
        const float2* atL = (const float2*)at;
        const float2* ahH = (const float2*)(ah + 300);
        const float2* atH = (const float2*)(at + 300);
        float2 x0 = bfp2f(xw[i0]), x1v = bfp2f(xw[i1]);
        float svh = x0.x*ahL[i0].x + x0.y*ahL[i0].y + x1v.x*ahL[i1].x + x1v.y*ahL[i1].y
                  + a0.x*ahH[i0].x + a0.y*ahH[i0].y + a1.x*ahH[i1].x + a1.y*ahH[i1].y;
        float svt = x0.x*atL[i0].x + x0.y*atL[i0].y + x1v.x*atL[i1].x + x1v.y*atL[i1].y
                  + a0.x*atH[i0].x + a0.y*atH[i0].y + a1.x*atH[i1].x + a1.y*atH[i1].y;
        if (t3) {
            float2 x2v = bfp2f(xw[i2]);
            svh += x2v.x*ahL[i2].x + x2v.y*ahL[i2].y + a2.x*ahH[i2].x + a2.y*ahH[i2].y;
            svt += x2v.x*atL[i2].x + x2v.y*atL[i2].y + a2.x*atH[i2].x + a2.y*atH[i2].y;
        }
        #pragma unroll
        for (int o = 32; o > 0; o >>= 1) {
            svh += __shfl_down(svh, o);
            svt += __shfl_down(svt, o);
        }
        if (lane == 0) { sh[w] = svh; st[w] = svt; }
    }
}

// r2e (h+t merged): fused score + softmax + gather (F=100)
__global__ void k_gather_rel2(const float* __restrict__ xr,
                              const float* __restrict__ sH, const float* __restrict__ sT,
                              const float* __restrict__ srel,
                              const int* __restrict__ relp,
                              const int* __restrict__ rowptrH, const int* __restrict__ cntH,
                              const int* __restrict__ rowptrT, const int* __restrict__ cntT,
                              float* __restrict__ out, long ldo, int n)
{
    int gw = (blockIdx.x*blockDim.x + threadIdx.x) >> 6;
    int lane = threadIdx.x & 63;
    if (gw >= 2*n) return;
    const bool isT = (gw >= n);
    const int w = isT ? gw - n : gw;
    const float* snode = isT ? sT : sH;
    const int* rowptr = isT ? rowptrT : rowptrH;
    const int* cnt    = isT ? cntT    : cntH;
    float* dst = out + (isT ? 700 : 600) + (long)w*ldo;
    int beg = rowptr[w], c = cnt[w];
    const bool t0 = (lane < 50);
    float2 a0 = {0,0};
    if (c > 0) {
        float base = snode[w];
        int   rc = 0;
        float sval = -3.4e38f;
        if (lane < c) {
            rc = relp[beg + lane];
            sval = leaky(base + srel[rc]);
        }
        float mx = sval;
        for (int t = 64 + lane; t < c; t += 64)
            mx = fmaxf(mx, leaky(base + srel[relp[beg+t]]));
        #pragma unroll
        for (int o = 32; o > 0; o >>= 1) mx = fmaxf(mx, __shfl_xor(mx, o));
        float pexp = (lane < c) ? expf(sval - mx) : 0.0f;
        float ss = pexp;
        for (int t = 64 + lane; t < c; t += 64)
            ss += expf(leaky(base + srel[relp[beg+t]]) - mx);
        #pragma unroll
        for (int o = 32; o > 0; o >>= 1) ss += __shfl_xor(ss, o);
        float inv = 1.0f / (ss + 1e-16f);
        int q = 0;
        int cc = (c < 64) ? c : 64;
        for (; q + 4 <= cc; q += 4) {
            float al0 = __shfl(pexp, q)   * inv;
            float al1 = __shfl(pexp, q+1) * inv;
            float al2 = __shfl(pexp, q+2) * inv;
            float al3 = __shfl(pexp, q+3) * inv;
            long r0i = __shfl(rc, q), r1i = __shfl(rc, q+1);
            long r2i = __shfl(rc, q+2), r3i = __shfl(rc, q+3);
            if (t0) {
                float2 v;
                v = ((const float2*)(xr + r0i*100))[lane]; a0.x += al0*v.x; a0.y += al0*v.y;
                v = ((const float2*)(xr + r1i*100))[lane]; a0.x += al1*v.x; a0.y += al1*v.y;
                v = ((const float2*)(xr + r2i*100))[lane]; a0.x += al2*v.x; a0.y += al2*v.y;
                v = ((const float2*)(xr + r3i*100))[lane]; a0.x += al3*v.x; a0.y += al3*v.y;
            }
        }
        for (; q < c; ++q) {
            float al; long r0i;
            if (q < 64) { al = __shfl(pexp, q) * inv; r0i = __shfl(rc, q); }
            else {
                r0i = relp[beg + q];
                al = expf(leaky(base + srel[(int)r0i]) - mx) * inv;
            }
            if (t0) {
                float2 v = ((const float2*)(xr + r0i*100))[lane];
                a0.x += al*v.x; a0.y += al*v.y;
            }
        }
    }
    if (t0) ((float2*)dst)[lane] = a0;
}

// ================= merged l_gat over both line graphs =================
__global__ void k_lgat_max(const float* __restrict__ mval, const float* __restrict__ tval,
                           const int* __restrict__ iM, const int* __restrict__ jM,
                           const int* __restrict__ iT, const int* __restrict__ jT,
                           unsigned* __restrict__ mi, unsigned* __restrict__ mj,
                           int LGE, int R)
{
    int e = blockIdx.x*blockDim.x + threadIdx.x;
    if (e >= 2*LGE) return;
    bool g1 = e >= LGE; int le = g1 ? e - LGE : e;
    float v = g1 ? tval[le] : mval[le];
    int i = (g1 ? iT[le] : iM[le]) + (g1 ? R : 0);
    int j = (g1 ? jT[le] : jM[le]) + (g1 ? R : 0);
    unsigned mv = f2mono(v);
    atomicMax(&mi[i], mv);
    atomicMax(&mj[j], mv);
}
__global__ void k_lgat_sum(const float* __restrict__ mval, const float* __restrict__ tval,
                           const int* __restrict__ iM, const int* __restrict__ jM,
                           const int* __restrict__ iT, const int* __restrict__ jT,
                           const unsigned* __restrict__ mi, const unsigned* __restrict__ mj,
                           float* __restrict__ si, float* __restrict__ sj,
                           int LGE, int R)
{
    int e = blockIdx.x*blockDim.x + threadIdx.x;
    if (e >= 2*LGE) return;
    bool g1 = e >= LGE; int le = g1 ? e - LGE : e;
    float v = g1 ? tval[le] : mval[le];
    int i = (g1 ? iT[le] : iM[le]) + (g1 ? R : 0);
    int j = (g1 ? jT[le] : jM[le]) + (g1 ? R : 0);
    atomicAdd(&si[i], expf(v - mono2f(mi[i])));
    atomicAdd(&sj[j], expf(v - mono2f(mj[j])));
}
__global__ void k_lgat_vsum2(const float* __restrict__ mval, const float* __restrict__ tval,
                             const int* __restrict__ iM, const int* __restrict__ jM,
                             const int* __restrict__ iT, const int* __restrict__ jT,
                             const unsigned* __restrict__ mi, const float* __restrict__ si,
                             const unsigned* __restrict__ mj, const float* __restrict__ sj,
                             float* __restrict__ vsum, int LGE, int R)
{
    int e = blockIdx.x*blockDim.x + threadIdx.x;
    if (e >= 2*LGE) return;
    bool g1 = e >= LGE; int le = g1 ? e - LGE : e;
    float v = g1 ? tval[le] : mval[le];
    int i = (g1 ? iT[le] : iM[le]) + (g1 ? R : 0);
    int j = (g1 ? jT[le] : jM[le]) + (g1 ? R : 0);
    float pi = expf(v - mono2f(mi[i])) / (si[i] + 1e-16f);
    float pj = expf(v - mono2f(mj[j])) / (sj[j] + 1e-16f);
    vsum[e] = pi + pj;
}
__global__ void k_lgat_max2(const float* __restrict__ vsum,
                            const int* __restrict__ jM, const int* __restrict__ jT,
                            unsigned* __restrict__ m2, int LGE, int R)
{
    int e = blockIdx.x*blockDim.x + threadIdx.x;
    if (e >= 2*LGE) return;
    bool g1 = e >= LGE; int le = g1 ? e - LGE : e;
    int j = (g1 ? jT[le] : jM[le]) + (g1 ? R : 0);
    atomicMax(&m2[j], f2mono(vsum[e]));
}
__global__ void k_lgat_sum2(const float* __restrict__ vsum,
                            const int* __restrict__ jM, const int* __restrict__ jT,
                            const unsigned* __restrict__ m2, float* __restrict__ s2,
                            int LGE, int R)
{
    int e = blockIdx.x*blockDim.x + threadIdx.x;
    if (e >= 2*LGE) return;
    bool g1 = e >= LGE; int le = g1 ? e - LGE : e;
    int j = (g1 ? jT[le] : jM[le]) + (g1 ? R : 0);
    atomicAdd(&s2[j], expf(vsum[e] - mono2f(m2[j])));
}
__global__ void k_lgat_agg(const float* __restrict__ vsum,
                           const unsigned* __restrict__ m2, const float* __restrict__ s2,
                           const int* __restrict__ iM, const int* __restrict__ jM,
                           const int* __restrict__ iT, const int* __restrict__ jT,
                           const float* __restrict__ remb1, const float* __restrict__ remb2,
                           float* __restrict__ obuf, int LGE, int R, int RH)
{
    int w = (blockIdx.x*blockDim.x + threadIdx.x) >> 6;
    int lane = threadIdx.x & 63;
    if (w >= 2*LGE) return;
    bool g1 = w >= LGE; int le = g1 ? w - LGE : w;
    int o = g1 ? R : 0;
    int i = (g1 ? iT[le] : iM[le]) + o;
    int j = (g1 ? jT[le] : jM[le]);
    float alpha = expf(vsum[w] - mono2f(m2[o + j])) / (s2[o + j] + 1e-16f);
    const float* x = g1 ? remb2 : remb1;
    const float4* src = (const float4*)(x + (long)j*RH);
    float* dst = obuf + (long)i*RH;
    if (lane < 25) {
        float4 v = src[lane];
        atomicAdd(&dst[lane*4+0], alpha*v.x);
        atomicAdd(&dst[lane*4+1], alpha*v.y);
        atomicAdd(&dst[lane*4+2], alpha*v.z);
        atomicAdd(&dst[lane*4+3], alpha*v.w);
    }
}
__global__ void k_relu2d(float* __restrict__ p, long rows, int cols, long ld) {
    long idx = (long)blockIdx.x*blockDim.x + threadIdx.x;
    if (idx >= rows*(long)cols) return;
    long r = idx / cols; int c = (int)(idx % cols);
    float v = p[r*ld+c];
    p[r*ld+c] = fmaxf(v, 0.0f);
}

// ---------- highway combine (small R x RH path) ----------
__global__ void k_highway(const float* __restrict__ x1, long ld1,
                          const float* __restrict__ gl, long ldg,
                          const float* __restrict__ x2, long ld2,
                          const float* __restrict__ bias,
                          float* __restrict__ out, long ldo,
                          long rows, int F, int relu_x2)
{
    long idx = (long)blockIdx.x*blockDim.x + threadIdx.x;
    if (idx >= rows * (long)F) return;
    long r = idx / F; int c = (int)(idx % F);
    float g = 1.0f / (1.0f + expf(-(gl[r*ldg+c] + bias[c])));
    float v2 = x2[r*ld2+c]; if (relu_x2) v2 = fmaxf(v2, 0.0f);
    float v1 = x1[r*ld1+c];
    out[r*ldo+c] = g*v2 + (1.0f-g)*v1;
}

// ---------- row dots (small path: srel) ----------
__global__ void k_rowdot2(const float* __restrict__ x, long ldx, int rows, int K,
                          const float* __restrict__ a, const float* __restrict__ b,
                          float* __restrict__ oa, float* __restrict__ ob)
{
    int w = (blockIdx.x*blockDim.x + threadIdx.x) >> 6;
    int lane = threadIdx.x & 63;
    if (w >= rows) return;
    const float* xr = x + (long)w*ldx;
    float sa = 0.0f, sb = 0.0f;
    for (int k = lane; k < K; k += WAVE) {
        float v = xr[k];
        sa += v * a[k];
        if (b) sb += v * b[k];
    }
    #pragma unroll
    for (int off = 32; off > 0; off >>= 1) {
        sa += __shfl_down(sa, off);
        if (b) sb += __shfl_down(sb, off);
    }
    if (lane == 0) { oa[w] = sa; if (ob) ob[w] = sb; }
}

// ---------- relscore[r] = merge[r]·ar[0:RH] + tri[r]·ar[RH:2RH] ----------
__global__ void k_relscore(const float* __restrict__ mg, const float* __restrict__ tr,
                           const float* __restrict__ ar, float* __restrict__ out, int R, int RH)
{
    int w = (blockIdx.x*blockDim.x + threadIdx.x) >> 6;
    int lane = threadIdx.x & 63;
    if (w >= R) return;
    float s = 0.0f;
    for (int k = lane; k < RH; k += WAVE)
        s += mg[(long)w*RH+k]*ar[k] + tr[(long)w*RH+k]*ar[RH+k];
    #pragma unroll
    for (int off = 32; off > 0; off >>= 1) s += __shfl_down(s, off);
    if (lane == 0) out[w] = s;
}

extern "C" void kernel_launch(void* const* d_in, const int* in_sizes, int n_in,
                              void* d_out, int out_size, void* d_ws, size_t ws_size,
                              hipStream_t stream)
{
    const float* x_e   = (const float*)d_in[0];
    const float* mval  = (const float*)d_in[1];
    const float* tval  = (const float*)d_in[2];
    const float* g1w   = (const float*)d_in[3];
    const float* h1w   = (const float*)d_in[4];
    const float* h1b   = (const float*)d_in[5];
    const float* g2w   = (const float*)d_in[6];
    const float* h2w   = (const float*)d_in[7];
    const float* h2b   = (const float*)d_in[8];
    const float* remb1 = (const float*)d_in[9];
    const float* remb2 = (const float*)d_in[10];
    const float* hrw   = (const float*)d_in[11];
    const float* hrb   = (const float*)d_in[12];
    const float* gat_ai= (const float*)d_in[13];
    const float* gat_aj= (const float*)d_in[14];
    const float* gat_ar= (const float*)d_in[15];
    const float* g2e_ah= (const float*)d_in[16];
    const float* g2e_at= (const float*)d_in[17];
    const float* g2e_ar= (const float*)d_in[18];
    const int* edge_index     = (const int*)d_in[19];
    const int* rel            = (const int*)d_in[20];
    const int* edge_index_all = (const int*)d_in[21];
    const int* rel_all        = (const int*)d_in[22];
    const int* lg_merge       = (const int*)d_in[23];
    const int* lg_tri         = (const int*)d_in[24];

    const int F    = 300;
    const int RH   = 100;
    const int Kp   = 304;
    const int npk  = Kp / 16;              // 19
    const int N    = in_sizes[0] / F;      // 100000
    const int E    = in_sizes[20];         // 400000
    const int EA   = in_sizes[22];         // 800000
    const int LGE  = in_sizes[1];          // 60000
    const int R    = in_sizes[9] / RH;     // 2000
    const long OUTC = 800;
    const int Mpad = CDIV(N, 128) * 128;
    const int NB   = 640;                  // W rows: g @0..299, h @320..619
    const long LDC = 640;

    const int* jA = edge_index_all;
    const int* iA = edge_index_all + EA;
    const int* hE = edge_index;
    const int* tE = edge_index + E;
    const int* jM = lg_merge;  const int* iM = lg_merge + LGE;
    const int* jT = lg_tri;    const int* iT = lg_tri  + LGE;

    float* ws = (float*)d_ws;
    size_t off = 0;
    auto alloc = [&](size_t n) { float* p = ws + off; off += (n + 3) & ~(size_t)3; return p; };
    unsigned short* Ascr = (unsigned short*)alloc((size_t)N*NB/2);    // GEMM out bf16 [N,640]
    unsigned short* Axb = (unsigned short*)alloc((size_t)Mpad*Kp/2);  // A packed bf16
    unsigned short* xbf = (unsigned short*)alloc((size_t)N*304/2);    // row-major bf16 x
    unsigned short* Wb  = (unsigned short*)alloc((size_t)2*NB*Kp/2);  // 2 packed weights
    unsigned short* W0 = Wb;
    unsigned short* W1 = Wb + (size_t)NB*Kp;
    float*    dinv = alloc(N);
    float*    sA_  = alloc(N);
    float*    sB_  = alloc(N);
    float*    sH_  = alloc(N);
    float*    sT_  = alloc(N);
    float*    xr   = alloc((size_t)R*RH);
    float*    xrg  = alloc((size_t)R*RH);
    // merged l_gat stats + output (single memset region)
    float*    lg   = alloc((size_t)12*R + (size_t)2*R*RH);
    unsigned* lmi  = (unsigned*)lg;          float* lsi = lg + 2*R;
    unsigned* lmj  = (unsigned*)(lg + 4*R);  float* lsj = lg + 6*R;
    unsigned* lm2  = (unsigned*)(lg + 8*R);  float* ls2 = lg + 10*R;
    float*    obuf = lg + 12*R;              // [2R][RH]: mrg then tri
    float*    mrg  = obuf;
    float*    tri  = obuf + (size_t)R*RH;
    float*    vsum = alloc((size_t)2*LGE);
    float*    rsc  = alloc(R);
    float*    srel = alloc(R);
    int*   bsum    = (int*)alloc(1024);
    // merged CSR region: cnt(3N) + cursor(3N) contiguous for single memset
    int*   cntAll  = (int*)alloc((size_t)6*N);
    int*   curAll  = cntAll + 3*N;
    int*   rowptrG = (int*)alloc((size_t)3*N);
    int*   permAll = (int*)alloc((size_t)EA + 2*E);
    int*   relpAll = (int*)alloc((size_t)EA + 2*E);
    int*   jpA     = (int*)alloc(EA);
    float* nmA     = alloc(EA);

    float* out = (float*)d_out;              // [N, 800]

    const int  nrb = CDIV(N, 128);
    const int  gemmBlocks = 8 * CDIV(nrb, 8) * 5;
    const int  gatherGrid = CDIV(N, 4);
    const int  cvtBigGrid = CDIV((long)N * (Kp/4), 256);
    const int  cvtWGrid   = CDIV(300 * (Kp/4), 256);
    const int  ETOT = EA + 2*E;
    const int  nb3 = CDIV(3*N, 512);         // 586 <= 1024

    // ===== converts (weights + x_e), pads zeroed =====
    hipMemsetAsync(Wb, 0, (size_t)2*NB*Kp*2, stream);
    hipMemsetAsync(Axb + (size_t)N*Kp, 0, (size_t)(Mpad-N)*Kp*2, stream);
    k_cvt_pack1<<<cvtWGrid,256,0,stream>>>(g1w, 300, 300, 300, npk, 0,   W0);
    k_cvt_pack1<<<cvtWGrid,256,0,stream>>>(h1w, 300, 300, 300, npk, 320, W0);
    k_cvt_pack1<<<cvtWGrid,256,0,stream>>>(g2w, 300, 300, 300, npk, 0,   W1);
    k_cvt_pack1<<<cvtWGrid,256,0,stream>>>(h2w, 300, 300, 300, npk, 320, W1);
    k_cvt_pack1<<<cvtBigGrid,256,0,stream>>>(x_e, 300, N, 300, npk, 0, Axb);

    // ===== merged CSR build (A, H, T) =====
    hipMemsetAsync(cntAll, 0, (size_t)6*N*4, stream);
    k_hist3<<<CDIV(ETOT,256),256,0,stream>>>(iA, hE, tE, cntAll, EA, E, N);
    k_scan1<<<nb3,512,0,stream>>>(cntAll, rowptrG, bsum, 3*N);
    k_scan2<<<1,1024,0,stream>>>(bsum, nb3);
    k_scan3<<<nb3,512,0,stream>>>(rowptrG, bsum, 3*N);
    k_fill3<<<CDIV(ETOT,256),256,0,stream>>>(iA, hE, tE, rowptrG, curAll, permAll, EA, E, N);
    k_dinv_cnt<<<CDIV(N,256),256,0,stream>>>(cntAll, dinv, N);
    k_prep_gcn<<<CDIV(EA,256),256,0,stream>>>(permAll, jA, iA, dinv, jpA, nmA, EA);
    k_permute3<<<CDIV(ETOT,256),256,0,stream>>>(rel_all, rel, permAll, relpAll, EA, E, R);

    // ===== GCN layer 1: GEMM (bf16) + gather/highway -> Axb pack + xbf =====
    k_gemm_frag<<<gemmBlocks,256,0,stream>>>(Axb, W0, Ascr, LDC, N, 620, npk, nrb);
    k_gather_hw<<<gatherGrid,256,0,stream>>>(Ascr, LDC, Ascr+320,
                                             x_e, (const unsigned short*)nullptr, 300, h1b,
                                             jpA, nmA, rowptrG, cntAll,
                                             (float*)nullptr, OUTC, Axb, xbf,
                                             (const float*)nullptr, (const float*)nullptr,
                                             (float*)nullptr, (float*)nullptr, npk, N);

    // ===== GCN layer 2: x1 from xbf (bf16), out write + xbf update + GAT dots =====
    k_gemm_frag<<<gemmBlocks,256,0,stream>>>(Axb, W1, Ascr, LDC, N, 620, npk, nrb);
    k_gather_hw<<<gatherGrid,256,0,stream>>>(Ascr, LDC, Ascr+320,
                                             (const float*)nullptr, xbf, 300, h2b,
                                             jpA, nmA, rowptrG, cntAll,
                                             out, OUTC, (unsigned short*)nullptr, xbf,
                                             gat_ai, gat_aj, sA_, sB_, npk, N);

    // ===== merged l_gat over both line graphs =====
    hipMemsetAsync(lg, 0, ((size_t)12*R + (size_t)2*R*RH)*4, stream);
    const int lgGrid = CDIV(2*LGE, 256);
    k_lgat_max  <<<lgGrid,256,0,stream>>>(mval, tval, iM, jM, iT, jT, lmi, lmj, LGE, R);
    k_lgat_sum  <<<lgGrid,256,0,stream>>>(mval, tval, iM, jM, iT, jT, lmi, lmj, lsi, lsj, LGE, R);
    k_lgat_vsum2<<<lgGrid,256,0,stream>>>(mval, tval, iM, jM, iT, jT, lmi, lsi, lmj, lsj,
                                          vsum, LGE, R);
    k_lgat_max2 <<<lgGrid,256,0,stream>>>(vsum, jM, jT, lm2, LGE, R);
    k_lgat_sum2 <<<lgGrid,256,0,stream>>>(vsum, jM, jT, lm2, ls2, LGE, R);
    k_lgat_agg  <<<CDIV(2*LGE*64,256),256,0,stream>>>(vsum, lm2, ls2, iM, jM, iT, jT,
                                                      remb1, remb2, obuf, LGE, R, RH);
    k_relu2d    <<<CDIV((long)2*R*RH,256),256,0,stream>>>(obuf, 2*R, RH, RH);

    // ===== x_r = highway(mrg, tri, hrw, hrb) =====
    dim3 gridR(CDIV(RH,GBN), CDIV(R,GBM));
    k_gemm<<<gridR,256,0,stream>>>(mrg, RH, hrw, RH, xrg, RH, R, RH, RH);
    k_highway<<<CDIV((long)R*RH,256),256,0,stream>>>(mrg, RH, xrg, RH, tri, RH, hrb, xr, RH, R, RH, 0);

    // relscore[r] = rel_cat[r]·gat_ar
    k_relscore<<<CDIV((long)R*64,256),256,0,stream>>>(mrg, tri, gat_ar, rsc, R, RH);

    // ===== GAT -> out cols 300..599 + r2e score dots =====
    k_gat300<<<gatherGrid,256,0,stream>>>(xbf, sA_, sB_, rsc, jpA, relpAll,
                                          rowptrG, cntAll, out+300, OUTC,
                                          g2e_ah, g2e_at, sH_, sT_, N);

    // ===== gat_r_to_e -> out cols 600..799 (h+t merged) =====
    k_rowdot2<<<CDIV((long)R*64,256),256,0,stream>>>(xr, RH, R, RH, g2e_ar, (const float*)nullptr,
                                                     srel, (float*)nullptr);
    k_gather_rel2<<<CDIV(2*N,4),256,0,stream>>>(xr, sH_, sT_, srel, relpAll,
                                                rowptrG + N, cntAll + N,
                                                rowptrG + 2*N, cntAll + 2*N,
                                                out, OUTC, N);
}

// Round 13
// 1223.319 us; speedup vs baseline: 1.3746x; 1.0034x over previous
//
#include <hip/hip_runtime.h>

#define WAVE 64
#define CDIV(a,b) (((a)+(b)-1)/(b))
#define XBS 320   // xbf row stride in shorts (640B, 64B-aligned rows)

typedef float f32x16 __attribute__((ext_vector_type(16)));
typedef unsigned short u16x8 __attribute__((ext_vector_type(8)));

// ---------- bf16 helpers ----------
__device__ __forceinline__ unsigned short f2bf_rne(float f) {
    unsigned u = __float_as_uint(f);
    unsigned r = (u + 0x7FFFu + ((u >> 16) & 1u)) >> 16;
    return (unsigned short)r;
}
__device__ __forceinline__ float bf2f(unsigned short h) {
    return __uint_as_float(((unsigned)h) << 16);
}
__device__ __forceinline__ float2 bfp2f(ushort2 u) {
    float2 r; r.x = bf2f(u.x); r.y = bf2f(u.y); return r;
}
__device__ __forceinline__ float sigm(float x) { return 1.0f / (1.0f + expf(-x)); }

#define MFMA32(acc, a, b) \
    asm volatile("v_mfma_f32_32x32x16_bf16 %0, %1, %2, %0" : "+v"(acc) : "v"(a), "v"(b))

// ---------- monotonic float<->uint encoding for atomicMax on floats ----------
__device__ __forceinline__ unsigned f2mono(float f) {
    unsigned u = __float_as_uint(f);
    return (u & 0x80000000u) ? ~u : (u | 0x80000000u);
}
__device__ __forceinline__ float mono2f(unsigned u) {
    return (u & 0x80000000u) ? __uint_as_float(u & 0x7fffffffu) : __uint_as_float(~u);
}
__device__ __forceinline__ float leaky(float v) { return (v > 0.0f) ? v : 0.01f*v; }

// fragment-pack offset: matrix row r, col k -> packed short index.
__device__ __forceinline__ long fragoff(long r, int k, int npk) {
    return ((r >> 5) * (long)npk + (k >> 4)) * 512
         + (((k >> 3) & 1) << 8) + ((r & 31) << 3) + (k & 7);
}

// ---------- k_cvt_pack1: f32 -> fragment-packed single bf16 (rne) ----------
__global__ void k_cvt_pack1(const float* __restrict__ src, long ld, int rows, int K, int npk,
                            int roff, unsigned short* __restrict__ dst)
{
    int nc4 = npk << 2;
    long idx = (long)blockIdx.x*blockDim.x + threadIdx.x;
    if (idx >= (long)rows * nc4) return;
    long r = idx / nc4; int k = (int)(idx % nc4) << 2;
    float4 v = {0.0f, 0.0f, 0.0f, 0.0f};
    if (k + 4 <= K) v = *(const float4*)(src + r*ld + k);
    ushort4 h;
    h.x = f2bf_rne(v.x); h.y = f2bf_rne(v.y); h.z = f2bf_rne(v.z); h.w = f2bf_rne(v.w);
    *(ushort4*)(dst + fragoff(r + roff, k, npk)) = h;
}

// merged weight convert: 4 matrices [300][300] -> W0(g@0,h@320), W1(g@0,h@320)
__global__ void k_cvt_w4(const float* __restrict__ g1w, const float* __restrict__ h1w,
                         const float* __restrict__ g2w, const float* __restrict__ h2w,
                         int npk, unsigned short* __restrict__ W0,
                         unsigned short* __restrict__ W1)
{
    const int nc4 = npk << 2;                 // 76
    const long per = (long)300 * nc4;
    long idx = (long)blockIdx.x*blockDim.x + threadIdx.x;
    if (idx >= 4*per) return;
    int which = (int)(idx / per);
    long lidx = idx % per;
    long r = lidx / nc4; int k = (int)(lidx % nc4) << 2;
    const float* src = (which == 0) ? g1w : (which == 1) ? h1w : (which == 2) ? g2w : h2w;
    unsigned short* dst = (which < 2) ? W0 : W1;
    int roff = (which & 1) ? 320 : 0;
    float4 v = {0.0f, 0.0f, 0.0f, 0.0f};
    if (k + 4 <= 300) v = *(const float4*)(src + r*300 + k);
    ushort4 h;
    h.x = f2bf_rne(v.x); h.y = f2bf_rne(v.y); h.z = f2bf_rne(v.z); h.w = f2bf_rne(v.w);
    *(ushort4*)(dst + fragoff(r + roff, k, npk)) = h;
}

// =========================================================================
// k_gemm_frag: C[M,620] (bf16) = A * B^T; A and B single bf16 (rne).
// NO LDS, NO barriers. XCD-ownership swizzle. 4 MFMA / 5 loads per k-step.
// =========================================================================
__global__ __launch_bounds__(256, 3)
void k_gemm_frag(const unsigned short* __restrict__ Ab,
                 const unsigned short* __restrict__ Bb,
                 unsigned short* __restrict__ C, long ldc, int M, int N, int nk, int nrb)
{
    const int lane = threadIdx.x & 63;
    const int wid  = threadIdx.x >> 6;
    const int lin  = blockIdx.x;
    const int xcd  = lin & 7;
    const int m    = lin >> 3;
    const int col0 = (m % 5) * 128;
    const int rb   = xcd + ((m / 5) << 3);
    if (rb >= nrb) return;
    const int row0 = rb * 128 + wid * 32;

    const long cs = (long)nk * 512;
    const unsigned short* pA = Ab + (long)(row0 >> 5) * cs + lane * 8;
    const unsigned short* pB = Bb + (long)(col0 >> 5) * cs + lane * 8;

    f32x16 acc[4];
    #pragma unroll
    for (int c = 0; c < 4; ++c) acc[c] = (f32x16)0.0f;

    u16x8 pa, pb0, pb1, pb2, pb3;
    u16x8 qa, qb0, qb1, qb2, qb3;

    #define LOADP(t_) { long o = (long)(t_)*512;                                   \
        pa  = *(const u16x8*)(pA + o);                                             \
        pb0 = *(const u16x8*)(pB + o);        pb1 = *(const u16x8*)(pB + cs + o);  \
        pb2 = *(const u16x8*)(pB + 2*cs + o); pb3 = *(const u16x8*)(pB + 3*cs + o); }
    #define LOADQ(t_) { long o = (long)(t_)*512;                                   \
        qa  = *(const u16x8*)(pA + o);                                             \
        qb0 = *(const u16x8*)(pB + o);        qb1 = *(const u16x8*)(pB + cs + o);  \
        qb2 = *(const u16x8*)(pB + 2*cs + o); qb3 = *(const u16x8*)(pB + 3*cs + o); }
    #define STEPP {                                                                 \
        MFMA32(acc[0], pa, pb0); MFMA32(acc[1], pa, pb1);                           \
        MFMA32(acc[2], pa, pb2); MFMA32(acc[3], pa, pb3); }
    #define STEPQ {                                                                 \
        MFMA32(acc[0], qa, qb0); MFMA32(acc[1], qa, qb1);                           \
        MFMA32(acc[2], qa, qb2); MFMA32(acc[3], qa, qb3); }

    LOADP(0);
    int t = 0;
    for (;;) {
        bool m1 = (t + 1 < nk);
        if (m1) LOADQ(t + 1);
        STEPP;
        if (!m1) break;
        bool m2 = (t + 2 < nk);
        if (m2) LOADP(t + 2);
        STEPQ;
        if (!m2) break;
        t += 2;
    }
    #undef LOADP
    #undef LOADQ
    #undef STEPP
    #undef STEPQ

    const int crow0 = row0 + 4*(lane >> 5);
    const int ccol0 = col0 + (lane & 31);
    #pragma unroll
    for (int c = 0; c < 4; ++c) {
        int col = ccol0 + c*32;
        if (col >= N) continue;
        #pragma unroll
        for (int reg = 0; reg < 16; ++reg) {
            int row = crow0 + (reg & 3) + 8*(reg >> 2);
            if (row < M) C[(long)row*ldc + col] = f2bf_rne(acc[c][reg]);
        }
    }
}

// ---------- small f32 GEMM (tiny R x RH highway gate) ----------
#define GBM 64
#define GBN 64
#define GBK 16
__global__ __launch_bounds__(256)
void k_gemm(const float* __restrict__ A, long lda,
            const float* __restrict__ B, long ldb,
            float* __restrict__ C, long ldc,
            int M, int N, int K)
{
    __shared__ float As[GBK][GBM + 4];
    __shared__ float Bs[GBK][GBN + 4];
    const int tid = threadIdx.x;
    const int tx = tid & 15, ty = tid >> 4;
    const int row0 = blockIdx.y * GBM, col0 = blockIdx.x * GBN;
    float acc[4][4] = {};
    for (int kt = 0; kt < K; kt += GBK) {
        #pragma unroll
        for (int p = 0; p < 4; ++p) {
            int mn = (tid >> 4) + p * 16;
            int k  = tid & 15;
            int gk = kt + k;
            int gr = row0 + mn;
            As[k][mn] = (gr < M && gk < K) ? A[(long)gr * lda + gk] : 0.0f;
            int gc = col0 + mn;
            Bs[k][mn] = (gc < N && gk < K) ? B[(long)gc * ldb + gk] : 0.0f;
        }
        __syncthreads();
        #pragma unroll
        for (int kk = 0; kk < GBK; ++kk) {
            float a0 = As[kk][ty*4+0], a1 = As[kk][ty*4+1];
            float a2 = As[kk][ty*4+2], a3 = As[kk][ty*4+3];
            float b0 = Bs[kk][tx*4+0], b1 = Bs[kk][tx*4+1];
            float b2 = Bs[kk][tx*4+2], b3 = Bs[kk][tx*4+3];
            acc[0][0] += a0*b0; acc[0][1] += a0*b1; acc[0][2] += a0*b2; acc[0][3] += a0*b3;
            acc[1][0] += a1*b0; acc[1][1] += a1*b1; acc[1][2] += a1*b2; acc[1][3] += a1*b3;
            acc[2][0] += a2*b0; acc[2][1] += a2*b1; acc[2][2] += a2*b2; acc[2][3] += a2*b3;
            acc[3][0] += a3*b0; acc[3][1] += a3*b1; acc[3][2] += a3*b2; acc[3][3] += a3*b3;
        }
        __syncthreads();
    }
    #pragma unroll
    for (int i2 = 0; i2 < 4; ++i2)
        #pragma unroll
        for (int j2 = 0; j2 < 4; ++j2) {
            int r = row0 + ty*4 + i2, c = col0 + tx*4 + j2;
            if (r < M && c < N) C[(long)r*ldc + c] = acc[i2][j2];
        }
}

// ================= merged CSR build over 3 graphs =================
__global__ void k_hist3(const int* __restrict__ iA, const int* __restrict__ hE,
                        const int* __restrict__ tE, int* __restrict__ cnt,
                        int EA, int E, int N) {
    int e = blockIdx.x*blockDim.x + threadIdx.x;
    int tot = EA + 2*E;
    if (e >= tot) return;
    if (e < EA)            atomicAdd(&cnt[iA[e]], 1);
    else if (e < EA + E)   atomicAdd(&cnt[N + hE[e - EA]], 1);
    else                   atomicAdd(&cnt[2*N + tE[e - EA - E]], 1);
}
__global__ void k_scan1(const int* __restrict__ in, int* __restrict__ out,
                        int* __restrict__ bsum, int n) {
    __shared__ int sh[512];
    int gid = blockIdx.x*512 + threadIdx.x;
    int v = (gid < n) ? in[gid] : 0;
    sh[threadIdx.x] = v; __syncthreads();
    for (int o = 1; o < 512; o <<= 1) {
        int t = (threadIdx.x >= o) ? sh[threadIdx.x - o] : 0;
        __syncthreads();
        sh[threadIdx.x] += t;
        __syncthreads();
    }
    if (gid < n) out[gid] = sh[threadIdx.x] - v;      // exclusive
    if (threadIdx.x == 511) bsum[blockIdx.x] = sh[511];
}
__global__ void k_scan2(int* __restrict__ bsum, int nb) {   // single block, nb <= 1024
    __shared__ int sh[1024];
    int v = (threadIdx.x < nb) ? bsum[threadIdx.x] : 0;
    sh[threadIdx.x] = v; __syncthreads();
    for (int o = 1; o < 1024; o <<= 1) {
        int t = (threadIdx.x >= o) ? sh[threadIdx.x - o] : 0;
        __syncthreads();
        sh[threadIdx.x] += t;
        __syncthreads();
    }
    if (threadIdx.x < nb) bsum[threadIdx.x] = sh[threadIdx.x] - v;  // exclusive
}
__global__ void k_scan3(int* __restrict__ out, const int* __restrict__ bsum, int n) {
    int gid = blockIdx.x*512 + threadIdx.x;
    if (gid < n) out[gid] += bsum[blockIdx.x];
}
__global__ void k_fill3(const int* __restrict__ iA, const int* __restrict__ hE,
                        const int* __restrict__ tE, const int* __restrict__ rowptr,
                        int* __restrict__ cursor, int* __restrict__ perm,
                        int EA, int E, int N) {
    int e = blockIdx.x*blockDim.x + threadIdx.x;
    int tot = EA + 2*E;
    if (e >= tot) return;
    int key, le;
    if (e < EA)          { le = e;          key = iA[le]; }
    else if (e < EA + E) { le = e - EA;     key = N + hE[le]; }
    else                 { le = e - EA - E; key = 2*N + tE[le]; }
    int p = rowptr[key] + atomicAdd(&cursor[key], 1);
    perm[p] = le;
}
__global__ void k_dinv_cnt(const int* __restrict__ cnt, float* __restrict__ dinv, int n) {
    int i = blockIdx.x*blockDim.x + threadIdx.x;
    if (i < n) { int c = cnt[i]; dinv[i] = (c > 0) ? rsqrtf((float)c) : 0.0f; }
}
__global__ void k_prep_gcn(const int* __restrict__ perm, const int* __restrict__ jA,
                           const int* __restrict__ iA, const float* __restrict__ dinv,
                           int* __restrict__ jp, float* __restrict__ nm, int E) {
    int p = blockIdx.x*blockDim.x + threadIdx.x;
    if (p >= E) return;
    int e = perm[p];
    int j = jA[e];
    jp[p] = j;
    nm[p] = dinv[iA[e]] * dinv[j];
}
__global__ void k_permute3(const int* __restrict__ rel_all, const int* __restrict__ rel,
                           const int* __restrict__ perm, int* __restrict__ relp,
                           int EA, int E, int R) {
    int p = blockIdx.x*blockDim.x + threadIdx.x;
    int tot = EA + 2*E;
    if (p >= tot) return;
    if (p < EA) relp[p] = rel_all[perm[p]] % R;
    else        relp[p] = rel[perm[p]];
}

// =========================================================================
// k_gather_hw: fused GCN gather (bf16 src, 8/4/1 edge unroll) + relu +
// highway + extras. x1 from f32 (x1f) or xbf bf16 stride XBS (x1b).
// =========================================================================
__global__ void k_gather_hw(const unsigned short* __restrict__ xg, long ldx,
                            const unsigned short* __restrict__ gl,
                            const float* __restrict__ x1f,
                            const unsigned short* __restrict__ x1b,
                            const float* __restrict__ bias,
                            const int* __restrict__ jp, const float* __restrict__ nm,
                            const int* __restrict__ rowptr, const int* __restrict__ cnt,
                            float* __restrict__ outp, long ldo,
                            unsigned short* __restrict__ pk,
                            unsigned short* __restrict__ xbf,
                            const float* __restrict__ ai, const float* __restrict__ aj,
                            float* __restrict__ sa, float* __restrict__ sb,
                            int npk, int n)
{
    int w = (blockIdx.x*blockDim.x + threadIdx.x) >> 6;
    int lane = threadIdx.x & 63;
    if (w >= n) return;
    int beg = rowptr[w], end = beg + cnt[w];
    const int i0 = lane, i1 = lane + 64, i2 = lane + 128;
    const bool t3 = (lane < 22);
    float2 a0 = {0,0}, a1 = {0,0}, a2 = {0,0};
    int e = beg;
    for (; e + 8 <= end; e += 8) {
        long jj[8]; float wt[8];
        #pragma unroll
        for (int u = 0; u < 8; ++u) { jj[u] = jp[e+u]; wt[u] = nm[e+u]; }
        #pragma unroll
        for (int u = 0; u < 8; ++u) {
            float2 v = bfp2f(((const ushort2*)(xg + jj[u]*ldx))[i0]);
            a0.x += wt[u]*v.x; a0.y += wt[u]*v.y;
        }
        #pragma unroll
        for (int u = 0; u < 8; ++u) {
            float2 v = bfp2f(((const ushort2*)(xg + jj[u]*ldx))[i1]);
            a1.x += wt[u]*v.x; a1.y += wt[u]*v.y;
        }
        if (t3) {
            #pragma unroll
            for (int u = 0; u < 8; ++u) {
                float2 v = bfp2f(((const ushort2*)(xg + jj[u]*ldx))[i2]);
                a2.x += wt[u]*v.x; a2.y += wt[u]*v.y;
            }
        }
    }
    for (; e + 4 <= end; e += 4) {
        long jj[4]; float wt[4];
        #pragma unroll
        for (int u = 0; u < 4; ++u) { jj[u] = jp[e+u]; wt[u] = nm[e+u]; }
        #pragma unroll
        for (int u = 0; u < 4; ++u) {
            float2 v = bfp2f(((const ushort2*)(xg + jj[u]*ldx))[i0]);
            a0.x += wt[u]*v.x; a0.y += wt[u]*v.y;
        }
        #pragma unroll
        for (int u = 0; u < 4; ++u) {
            float2 v = bfp2f(((const ushort2*)(xg + jj[u]*ldx))[i1]);
            a1.x += wt[u]*v.x; a1.y += wt[u]*v.y;
        }
        if (t3) {
            #pragma unroll
            for (int u = 0; u < 4; ++u) {
                float2 v = bfp2f(((const ushort2*)(xg + jj[u]*ldx))[i2]);
                a2.x += wt[u]*v.x; a2.y += wt[u]*v.y;
            }
        }
    }
    for (; e < end; ++e) {
        long j0 = jp[e]; float w0 = nm[e];
        float2 v;
        v = bfp2f(((const ushort2*)(xg + j0*ldx))[i0]); a0.x += w0*v.x; a0.y += w0*v.y;
        v = bfp2f(((const ushort2*)(xg + j0*ldx))[i1]); a1.x += w0*v.x; a1.y += w0*v.y;
        if (t3) { v = bfp2f(((const ushort2*)(xg + j0*ldx))[i2]); a2.x += w0*v.x; a2.y += w0*v.y; }
    }
    // highway: o = sig(gl+b)*relu(acc) + (1-sig)*x1
    const ushort2* glr = (const ushort2*)(gl + (long)w*ldx);
    const float2*  x1r = (const float2*)(x1f + (long)w*300);
    const ushort2* x1r2 = (const ushort2*)(x1b + (long)w*XBS);
    const float2*  br  = (const float2*)bias;
    float2 o0 = {0,0}, o1 = {0,0}, o2 = {0,0};
    {
        float2 gv = bfp2f(glr[i0]); float2 bv = br[i0];
        float2 xv = x1f ? x1r[i0] : bfp2f(x1r2[i0]);
        float g0 = sigm(gv.x + bv.x), g1 = sigm(gv.y + bv.y);
        o0.x = g0*fmaxf(a0.x,0.0f) + (1.0f-g0)*xv.x;
        o0.y = g1*fmaxf(a0.y,0.0f) + (1.0f-g1)*xv.y;
    }
    {
        float2 gv = bfp2f(glr[i1]); float2 bv = br[i1];
        float2 xv = x1f ? x1r[i1] : bfp2f(x1r2[i1]);
        float g0 = sigm(gv.x + bv.x), g1 = sigm(gv.y + bv.y);
        o1.x = g0*fmaxf(a1.x,0.0f) + (1.0f-g0)*xv.x;
        o1.y = g1*fmaxf(a1.y,0.0f) + (1.0f-g1)*xv.y;
    }
    if (t3) {
        float2 gv = bfp2f(glr[i2]); float2 bv = br[i2];
        float2 xv = x1f ? x1r[i2] : bfp2f(x1r2[i2]);
        float g0 = sigm(gv.x + bv.x), g1 = sigm(gv.y + bv.y);
        o2.x = g0*fmaxf(a2.x,0.0f) + (1.0f-g0)*xv.x;
        o2.y = g1*fmaxf(a2.y,0.0f) + (1.0f-g1)*xv.y;
    }
    if (outp) {
        float2* dst = (float2*)(outp + (long)w*ldo);
        dst[i0] = o0; dst[i1] = o1;
        if (t3) dst[i2] = o2;
    }
    if (pk) {
        auto pack2 = [&](int k, float2 o) {
            ushort2 hv; hv.x = f2bf_rne(o.x); hv.y = f2bf_rne(o.y);
            *(ushort2*)(pk + fragoff(w, k, npk)) = hv;
        };
        pack2(2*lane, o0);
        pack2(128 + 2*lane, o1);
        if (t3) pack2(256 + 2*lane, o2);
        else if (lane < 24) {
            ushort2 z = {0,0};
            *(ushort2*)(pk + fragoff(w, 256 + 2*lane, npk)) = z;
        }
    }
    if (xbf) {
        ushort2* xw = (ushort2*)(xbf + (long)w*XBS);
        ushort2 t;
        t.x = f2bf_rne(o0.x); t.y = f2bf_rne(o0.y); xw[i0] = t;
        t.x = f2bf_rne(o1.x); t.y = f2bf_rne(o1.y); xw[i1] = t;
        if (t3) { t.x = f2bf_rne(o2.x); t.y = f2bf_rne(o2.y); xw[i2] = t; }
    }
    if (sa) {
        const float2* ai2 = (const float2*)ai;
        const float2* aj2 = (const float2*)aj;
        float2 A0 = ai2[i0], A1 = ai2[i1], J0 = aj2[i0], J1 = aj2[i1];
        float sva = o0.x*A0.x + o0.y*A0.y + o1.x*A1.x + o1.y*A1.y;
        float svb = o0.x*J0.x + o0.y*J0.y + o1.x*J1.x + o1.y*J1.y;
        if (t3) {
            float2 A2 = ai2[i2], J2 = aj2[i2];
            sva += o2.x*A2.x + o2.y*A2.y;
            svb += o2.x*J2.x + o2.y*J2.y;
        }
        #pragma unroll
        for (int o = 32; o > 0; o >>= 1) {
            sva += __shfl_down(sva, o);
            svb += __shfl_down(svb, o);
        }
        if (lane == 0) { sa[w] = sva; sb[w] = svb; }
    }
}

// =========================================================================
// k_gat300: fused edge score + segment softmax + weighted gather (bf16,
// 8/4/1 unroll) + relu -> out cols 300..599, PLUS r2e score dots.
// =========================================================================
__global__ void k_gat300(const unsigned short* __restrict__ xbf,
                         const float* __restrict__ sA, const float* __restrict__ sB,
                         const float* __restrict__ rsc,
                         const int* __restrict__ jp, const int* __restrict__ relp,
                         const int* __restrict__ rowptr, const int* __restrict__ cnt,
                         float* __restrict__ out, long ldo,
                         const float* __restrict__ ah, const float* __restrict__ at,
                         float* __restrict__ sh, float* __restrict__ st,
                         int n)
{
    int w = (blockIdx.x*blockDim.x + threadIdx.x) >> 6;
    int lane = threadIdx.x & 63;
    if (w >= n) return;
    int beg = rowptr[w], c = cnt[w];
    const int i0 = lane, i1 = lane + 64, i2 = lane + 128;
    const bool t3 = (lane < 22);
    float2 a0 = {0,0}, a1 = {0,0}, a2 = {0,0};
    if (c > 0) {
        float base = sA[w];
        int   jc = 0;
        float sval = -3.4e38f;
        if (lane < c) {
            jc = jp[beg + lane];
            sval = leaky(base + sB[jc] + rsc[relp[beg + lane]]);
        }
        float mx = sval;
        for (int t = 64 + lane; t < c; t += 64)
            mx = fmaxf(mx, leaky(base + sB[jp[beg+t]] + rsc[relp[beg+t]]));
        #pragma unroll
        for (int o = 32; o > 0; o >>= 1) mx = fmaxf(mx, __shfl_xor(mx, o));
        float pexp = (lane < c) ? expf(sval - mx) : 0.0f;
        float ss = pexp;
        for (int t = 64 + lane; t < c; t += 64)
            ss += expf(leaky(base + sB[jp[beg+t]] + rsc[relp[beg+t]]) - mx);
        #pragma unroll
        for (int o = 32; o > 0; o >>= 1) ss += __shfl_xor(ss, o);
        float inv = 1.0f / (ss + 1e-16f);
        int q = 0;
        int cc = (c < 64) ? c : 64;
        for (; q + 8 <= cc; q += 8) {
            float al[8]; long jj[8];
            #pragma unroll
            for (int u = 0; u < 8; ++u) {
                al[u] = __shfl(pexp, q+u) * inv;
                jj[u] = __shfl(jc, q+u);
            }
            #pragma unroll
            for (int u = 0; u < 8; ++u) {
                float2 v = bfp2f(((const ushort2*)(xbf + jj[u]*XBS))[i0]);
                a0.x += al[u]*v.x; a0.y += al[u]*v.y;
            }
            #pragma unroll
            for (int u = 0; u < 8; ++u) {
                float2 v = bfp2f(((const ushort2*)(xbf + jj[u]*XBS))[i1]);
                a1.x += al[u]*v.x; a1.y += al[u]*v.y;
            }
            if (t3) {
                #pragma unroll
                for (int u = 0; u < 8; ++u) {
                    float2 v = bfp2f(((const ushort2*)(xbf + jj[u]*XBS))[i2]);
                    a2.x += al[u]*v.x; a2.y += al[u]*v.y;
                }
            }
        }
        for (; q + 4 <= cc; q += 4) {
            float al[4]; long jj[4];
            #pragma unroll
            for (int u = 0; u < 4; ++u) {
                al[u] = __shfl(pexp, q+u) * inv;
                jj[u] = __shfl(jc, q+u);
            }
            #pragma unroll
            for (int u = 0; u < 4; ++u) {
                float2 v = bfp2f(((const ushort2*)(xbf + jj[u]*XBS))[i0]);
                a0.x += al[u]*v.x; a0.y += al[u]*v.y;
            }
            #pragma unroll
            for (int u = 0; u < 4; ++u) {
                float2 v = bfp2f(((const ushort2*)(xbf + jj[u]*XBS))[i1]);
                a1.x += al[u]*v.x; a1.y += al[u]*v.y;
            }
            if (t3) {
                #pragma unroll
                for (int u = 0; u < 4; ++u) {
                    float2 v = bfp2f(((const ushort2*)(xbf + jj[u]*XBS))[i2]);
                    a2.x += al[u]*v.x; a2.y += al[u]*v.y;
                }
            }
        }
        for (; q < c; ++q) {
            float al; long j0;
            if (q < 64) { al = __shfl(pexp, q) * inv; j0 = __shfl(jc, q); }
            else {
                j0 = jp[beg + q];
                al = expf(leaky(base + sB[(int)j0] + rsc[relp[beg+q]]) - mx) * inv;
            }
            float2 v;
            v = bfp2f(((const ushort2*)(xbf + j0*XBS))[i0]); a0.x += al*v.x; a0.y += al*v.y;
            v = bfp2f(((const ushort2*)(xbf + j0*XBS))[i1]); a1.x += al*v.x; a1.y += al*v.y;
            if (t3) { v = bfp2f(((const ushort2*)(xbf + j0*XBS))[i2]); a2.x += al*v.x; a2.y += al*v.y; }
        }
    }
    a0.x = fmaxf(a0.x, 0.0f); a0.y = fmaxf(a0.y, 0.0f);
    a1.x = fmaxf(a1.x, 0.0f); a1.y = fmaxf(a1.y, 0.0f);
    a2.x = fmaxf(a2.x, 0.0f); a2.y = fmaxf(a2.y, 0.0f);
    float2* dst = (float2*)(out + (long)w*ldo);
    dst[i0] = a0; dst[i1] = a1;
    if (t3) dst[i2] = a2;
    {
        const ushort2* xw = (const ushort2*)(xbf + (long)w*XBS);
        const float2* ahL = (const float2*)ah;
        const float2* atL = (const float2*)at;
        const float2* ahH = (const float2*)(ah + 300);
        const float2* atH = (const float2*)(at + 300);
        float2 x0 = bfp2f(xw[i0]), x1v = bfp2f(xw[i1]);
        float svh = x0.x*ahL[i0].x + x0.y*ahL[i0].y + x1v.x*ahL[i1].x + x1v.y*ahL[i1].y
                  + a0.x*ahH[i0].x + a0.y*ahH[i0].y + a1.x*ahH[i1].x + a1.y*ahH[i1].y;
        float svt = x0.x*atL[i0].x + x0.y*atL[i0].y + x1v.x*atL[i1].x + x1v.y*atL[i1].y
                  + a0.x*atH[i0].x + a0.y*atH[i0].y + a1.x*atH[i1].x + a1.y*atH[i1].y;
        if (t3) {
            float2 x2v = bfp2f(xw[i2]);
            svh += x2v.x*ahL[i2].x + x2v.y*ahL[i2].y + a2.x*ahH[i2].x + a2.y*ahH[i2].y;
            svt += x2v.x*atL[i2].x + x2v.y*atL[i2].y + a2.x*atH[i2].x + a2.y*atH[i2].y;
        }
        #pragma unroll
        for (int o = 32; o > 0; o >>= 1) {
            svh += __shfl_down(svh, o);
            svt += __shfl_down(svt, o);
        }
        if (lane == 0) { sh[w] = svh; st[w] = svt; }
    }
}

// r2e (h+t merged): fused score + softmax + gather (F=100)
__global__ void k_gather_rel2(const float* __restrict__ xr,
                              const float* __restrict__ sH, const float* __restrict__ sT,
                              const float* __restrict__ srel,
                              const int* __restrict__ relp,
                              const int* __restrict__ rowptrH, const int* __restrict__ cntH,
                              const int* __restrict__ rowptrT, const int* __restrict__ cntT,
                              float* __restrict__ out, long ldo, int n)
{
    int gw = (blockIdx.x*blockDim.x + threadIdx.x) >> 6;
    int lane = threadIdx.x & 63;
    if (gw >= 2*n) return;
    const bool isT = (gw >= n);
    const int w = isT ? gw - n : gw;
    const float* snode = isT ? sT : sH;
    const int* rowptr = isT ? rowptrT : rowptrH;
    const int* cnt    = isT ? cntT    : cntH;
    float* dst = out + (isT ? 700 : 600) + (long)w*ldo;
    int beg = rowptr[w], c = cnt[w];
    const bool t0 = (lane < 50);
    float2 a0 = {0,0};
    if (c > 0) {
        float base = snode[w];
        int   rc = 0;
        float sval = -3.4e38f;
        if (lane < c) {
            rc = relp[beg + lane];
            sval = leaky(base + srel[rc]);
        }
        float mx = sval;
        for (int t = 64 + lane; t < c; t += 64)
            mx = fmaxf(mx, leaky(base + srel[relp[beg+t]]));
        #pragma unroll
        for (int o = 32; o > 0; o >>= 1) mx = fmaxf(mx, __shfl_xor(mx, o));
        float pexp = (lane < c) ? expf(sval - mx) : 0.0f;
        float ss = pexp;
        for (int t = 64 + lane; t < c; t += 64)
            ss += expf(leaky(base + srel[relp[beg+t]]) - mx);
        #pragma unroll
        for (int o = 32; o > 0; o >>= 1) ss += __shfl_xor(ss, o);
        float inv = 1.0f / (ss + 1e-16f);
        int q = 0;
        int cc = (c < 64) ? c : 64;
        for (; q + 4 <= cc; q += 4) {
            float al0 = __shfl(pexp, q)   * inv;
            float al1 = __shfl(pexp, q+1) * inv;
            float al2 = __shfl(pexp, q+2) * inv;
            float al3 = __shfl(pexp, q+3) * inv;
            long r0i = __shfl(rc, q), r1i = __shfl(rc, q+1);
            long r2i = __shfl(rc, q+2), r3i = __shfl(rc, q+3);
            if (t0) {
                float2 v;
                v = ((const float2*)(xr + r0i*100))[lane]; a0.x += al0*v.x; a0.y += al0*v.y;
                v = ((const float2*)(xr + r1i*100))[lane]; a0.x += al1*v.x; a0.y += al1*v.y;
                v = ((const float2*)(xr + r2i*100))[lane]; a0.x += al2*v.x; a0.y += al2*v.y;
                v = ((const float2*)(xr + r3i*100))[lane]; a0.x += al3*v.x; a0.y += al3*v.y;
            }
        }
        for (; q < c; ++q) {
            float al; long r0i;
            if (q < 64) { al = __shfl(pexp, q) * inv; r0i = __shfl(rc, q); }
            else {
                r0i = relp[beg + q];
                al = expf(leaky(base + srel[(int)r0i]) - mx) * inv;
            }
            if (t0) {
                float2 v = ((const float2*)(xr + r0i*100))[lane];
                a0.x += al*v.x; a0.y += al*v.y;
            }
        }
    }
    if (t0) ((float2*)dst)[lane] = a0;
}

// ================= merged l_gat over both line graphs =================
__global__ void k_lgat_max(const float* __restrict__ mval, const float* __restrict__ tval,
                           const int* __restrict__ iM, const int* __restrict__ jM,
                           const int* __restrict__ iT, const int* __restrict__ jT,
                           unsigned* __restrict__ mi, unsigned* __restrict__ mj,
                           int LGE, int R)
{
    int e = blockIdx.x*blockDim.x + threadIdx.x;
    if (e >= 2*LGE) return;
    bool g1 = e >= LGE; int le = g1 ? e - LGE : e;
    float v = g1 ? tval[le] : mval[le];
    int i = (g1 ? iT[le] : iM[le]) + (g1 ? R : 0);
    int j = (g1 ? jT[le] : jM[le]) + (g1 ? R : 0);
    unsigned mv = f2mono(v);
    atomicMax(&mi[i], mv);
    atomicMax(&mj[j], mv);
}
__global__ void k_lgat_sum(const float* __restrict__ mval, const float* __restrict__ tval,
                           const int* __restrict__ iM, const int* __restrict__ jM,
                           const int* __restrict__ iT, const int* __restrict__ jT,
                           const unsigned* __restrict__ mi, const unsigned* __restrict__ mj,
                           float* __restrict__ si, float* __restrict__ sj,
                           int LGE, int R)
{
    int e = blockIdx.x*blockDim.x + threadIdx.x;
    if (e >= 2*LGE) return;
    bool g1 = e >= LGE; int le = g1 ? e - LGE : e;
    float v = g1 ? tval[le] : mval[le];
    int i = (g1 ? iT[le] : iM[le]) + (g1 ? R : 0);
    int j = (g1 ? jT[le] : jM[le]) + (g1 ? R : 0);
    atomicAdd(&si[i], expf(v - mono2f(mi[i])));
    atomicAdd(&sj[j], expf(v - mono2f(mj[j])));
}
__global__ void k_lgat_vsum2(const float* __restrict__ mval, const float* __restrict__ tval,
                             const int* __restrict__ iM, const int* __restrict__ jM,
                             const int* __restrict__ iT, const int* __restrict__ jT,
                             const unsigned* __restrict__ mi, const float* __restrict__ si,
                             const unsigned* __restrict__ mj, const float* __restrict__ sj,
                             float* __restrict__ vsum, int LGE, int R)
{
    int e = blockIdx.x*blockDim.x + threadIdx.x;
    if (e >= 2*LGE) return;
    bool g1 = e >= LGE; int le = g1 ? e - LGE : e;
    float v = g1 ? tval[le] : mval[le];
    int i = (g1 ? iT[le] : iM[le]) + (g1 ? R : 0);
    int j = (g1 ? jT[le] : jM[le]) + (g1 ? R : 0);
    float pi = expf(v - mono2f(mi[i])) / (si[i] + 1e-16f);
    float pj = expf(v - mono2f(mj[j])) / (sj[j] + 1e-16f);
    vsum[e] = pi + pj;
}
__global__ void k_lgat_max2(const float* __restrict__ vsum,
                            const int* __restrict__ jM, const int* __restrict__ jT,
                            unsigned* __restrict__ m2, int LGE, int R)
{
    int e = blockIdx.x*blockDim.x + threadIdx.x;
    if (e >= 2*LGE) return;
    bool g1 = e >= LGE; int le = g1 ? e - LGE : e;
    int j = (g1 ? jT[le] : jM[le]) + (g1 ? R : 0);
    atomicMax(&m2[j], f2mono(vsum[e]));
}
__global__ void k_lgat_sum2(const float* __restrict__ vsum,
                            const int* __restrict__ jM, const int* __restrict__ jT,
                            const unsigned* __restrict__ m2, float* __restrict__ s2,
                            int LGE, int R)
{
    int e = blockIdx.x*blockDim.x + threadIdx.x;
    if (e >= 2*LGE) return;
    bool g1 = e >= LGE; int le = g1 ? e - LGE : e;
    int j = (g1 ? jT[le] : jM[le]) + (g1 ? R : 0);
    atomicAdd(&s2[j], expf(vsum[e] - mono2f(m2[j])));
}
__global__ void k_lgat_agg(const float* __restrict__ vsum,
                           const unsigned* __restrict__ m2, const float* __restrict__ s2,
                           const int* __restrict__ iM, const int* __restrict__ jM,
                           const int* __restrict__ iT, const int* __restrict__ jT,
                           const float* __restrict__ remb1, const float* __restrict__ remb2,
                           float* __restrict__ obuf, int LGE, int R, int RH)
{
    int w = (blockIdx.x*blockDim.x + threadIdx.x) >> 6;
    int lane = threadIdx.x & 63;
    if (w >= 2*LGE) return;
    bool g1 = w >= LGE; int le = g1 ? w - LGE : w;
    int o = g1 ? R : 0;
    int i = (g1 ? iT[le] : iM[le]) + o;
    int j = (g1 ? jT[le] : jM[le]);
    float alpha = expf(vsum[w] - mono2f(m2[o + j])) / (s2[o + j] + 1e-16f);
    const float* x = g1 ? remb2 : remb1;
    const float4* src = (const float4*)(x + (long)j*RH);
    float* dst = obuf + (long)i*RH;
    if (lane < 25) {
        float4 v = src[lane];
        atomicAdd(&dst[lane*4+0], alpha*v.x);
        atomicAdd(&dst[lane*4+1], alpha*v.y);
        atomicAdd(&dst[lane*4+2], alpha*v.z);
        atomicAdd(&dst[lane*4+3], alpha*v.w);
    }
}
__global__ void k_relu2d(float* __restrict__ p, long rows, int cols, long ld) {
    long idx = (long)blockIdx.x*blockDim.x + threadIdx.x;
    if (idx >= rows*(long)cols) return;
    long r = idx / cols; int c = (int)(idx % cols);
    float v = p[r*ld+c];
    p[r*ld+c] = fmaxf(v, 0.0f);
}

// ---------- highway combine (small R x RH path) ----------
__global__ void k_highway(const float* __restrict__ x1, long ld1,
                          const float* __restrict__ gl, long ldg,
                          const float* __restrict__ x2, long ld2,
                          const float* __restrict__ bias,
                          float* __restrict__ out, long ldo,
                          long rows, int F, int relu_x2)
{
    long idx = (long)blockIdx.x*blockDim.x + threadIdx.x;
    if (idx >= rows * (long)F) return;
    long r = idx / F; int c = (int)(idx % F);
    float g = 1.0f / (1.0f + expf(-(gl[r*ldg+c] + bias[c])));
    float v2 = x2[r*ld2+c]; if (relu_x2) v2 = fmaxf(v2, 0.0f);
    float v1 = x1[r*ld1+c];
    out[r*ldo+c] = g*v2 + (1.0f-g)*v1;
}

// ---------- row dots (small path: srel) ----------
__global__ void k_rowdot2(const float* __restrict__ x, long ldx, int rows, int K,
                          const float* __restrict__ a, const float* __restrict__ b,
                          float* __restrict__ oa, float* __restrict__ ob)
{
    int w = (blockIdx.x*blockDim.x + threadIdx.x) >> 6;
    int lane = threadIdx.x & 63;
    if (w >= rows) return;
    const float* xr = x + (long)w*ldx;
    float sa = 0.0f, sb = 0.0f;
    for (int k = lane; k < K; k += WAVE) {
        float v = xr[k];
        sa += v * a[k];
        if (b) sb += v * b[k];
    }
    #pragma unroll
    for (int off = 32; off > 0; off >>= 1) {
        sa += __shfl_down(sa, off);
        if (b) sb += __shfl_down(sb, off);
    }
    if (lane == 0) { oa[w] = sa; if (ob) ob[w] = sb; }
}

// ---------- relscore[r] = merge[r]·ar[0:RH] + tri[r]·ar[RH:2RH] ----------
__global__ void k_relscore(const float* __restrict__ mg, const float* __restrict__ tr,
                           const float* __restrict__ ar, float* __restrict__ out, int R, int RH)
{
    int w = (blockIdx.x*blockDim.x + threadIdx.x) >> 6;
    int lane = threadIdx.x & 63;
    if (w >= R) return;
    float s = 0.0f;
    for (int k = lane; k < RH; k += WAVE)
        s += mg[(long)w*RH+k]*ar[k] + tr[(long)w*RH+k]*ar[RH+k];
    #pragma unroll
    for (int off = 32; off > 0; off >>= 1) s += __shfl_down(s, off);
    if (lane == 0) out[w] = s;
}

extern "C" void kernel_launch(void* const* d_in, const int* in_sizes, int n_in,
                              void* d_out, int out_size, void* d_ws, size_t ws_size,
                              hipStream_t stream)
{
    const float* x_e   = (const float*)d_in[0];
    const float* mval  = (const float*)d_in[1];
    const float* tval  = (const float*)d_in[2];
    const float* g1w   = (const float*)d_in[3];
    const float* h1w   = (const float*)d_in[4];
    const float* h1b   = (const float*)d_in[5];
    const float* g2w   = (const float*)d_in[6];
    const float* h2w   = (const float*)d_in[7];
    const float* h2b   = (const float*)d_in[8];
    const float* remb1 = (const float*)d_in[9];
    const float* remb2 = (const float*)d_in[10];
    const float* hrw   = (const float*)d_in[11];
    const float* hrb   = (const float*)d_in[12];
    const float* gat_ai= (const float*)d_in[13];
    const float* gat_aj= (const float*)d_in[14];
    const float* gat_ar= (const float*)d_in[15];
    const float* g2e_ah= (const float*)d_in[16];
    const float* g2e_at= (const float*)d_in[17];
    const float* g2e_ar= (const float*)d_in[18];
    const int* edge_index     = (const int*)d_in[19];
    const int* rel            = (const int*)d_in[20];
    const int* edge_index_all = (const int*)d_in[21];
    const int* rel_all        = (const int*)d_in[22];
    const int* lg_merge       = (const int*)d_in[23];
    const int* lg_tri         = (const int*)d_in[24];

    const int F    = 300;
    const int RH   = 100;
    const int Kp   = 304;
    const int npk  = Kp / 16;              // 19
    const int N    = in_sizes[0] / F;      // 100000
    const int E    = in_sizes[20];         // 400000
    const int EA   = in_sizes[22];         // 800000
    const int LGE  = in_sizes[1];          // 60000
    const int R    = in_sizes[9] / RH;     // 2000
    const long OUTC = 800;
    const int Mpad = CDIV(N, 128) * 128;
    const int NB   = 640;                  // W rows: g @0..299, h @320..619
    const long LDC = 640;

    const int* jA = edge_index_all;
    const int* iA = edge_index_all + EA;
    const int* hE = edge_index;
    const int* tE = edge_index + E;
    const int* jM = lg_merge;  const int* iM = lg_merge + LGE;
    const int* jT = lg_tri;    const int* iT = lg_tri  + LGE;

    float* ws = (float*)d_ws;
    size_t off = 0;
    auto alloc = [&](size_t n) { float* p = ws + off; off += (n + 15) & ~(size_t)15; return p; };
    unsigned short* Ascr = (unsigned short*)alloc((size_t)N*NB/2);    // GEMM out bf16 [N,640]
    unsigned short* Axb = (unsigned short*)alloc((size_t)Mpad*Kp/2);  // A packed bf16
    unsigned short* xbf = (unsigned short*)alloc((size_t)N*XBS/2);    // row-major bf16 x (640B rows)
    unsigned short* Wb  = (unsigned short*)alloc((size_t)2*NB*Kp/2);  // 2 packed weights
    unsigned short* W0 = Wb;
    unsigned short* W1 = Wb + (size_t)NB*Kp;
    float*    dinv = alloc(N);
    float*    sA_  = alloc(N);
    float*    sB_  = alloc(N);
    float*    sH_  = alloc(N);
    float*    sT_  = alloc(N);
    float*    xr   = alloc((size_t)R*RH);
    float*    xrg  = alloc((size_t)R*RH);
    float*    lg   = alloc((size_t)12*R + (size_t)2*R*RH);
    unsigned* lmi  = (unsigned*)lg;          float* lsi = lg + 2*R;
    unsigned* lmj  = (unsigned*)(lg + 4*R);  float* lsj = lg + 6*R;
    unsigned* lm2  = (unsigned*)(lg + 8*R);  float* ls2 = lg + 10*R;
    float*    obuf = lg + 12*R;              // [2R][RH]: mrg then tri
    float*    mrg  = obuf;
    float*    tri  = obuf + (size_t)R*RH;
    float*    vsum = alloc((size_t)2*LGE);
    float*    rsc  = alloc(R);
    float*    srel = alloc(R);
    int*   bsum    = (int*)alloc(1024);
    int*   cntAll  = (int*)alloc((size_t)6*N);
    int*   curAll  = cntAll + 3*N;
    int*   rowptrG = (int*)alloc((size_t)3*N);
    int*   permAll = (int*)alloc((size_t)EA + 2*E);
    int*   relpAll = (int*)alloc((size_t)EA + 2*E);
    int*   jpA     = (int*)alloc(EA);
    float* nmA     = alloc(EA);

    float* out = (float*)d_out;              // [N, 800]

    const int  nrb = CDIV(N, 128);
    const int  gemmBlocks = 8 * CDIV(nrb, 8) * 5;
    const int  gatherGrid = CDIV(N, 4);
    const int  cvtBigGrid = CDIV((long)N * (Kp/4), 256);
    const int  cvtW4Grid  = CDIV((long)4 * 300 * (Kp/4), 256);
    const int  ETOT = EA + 2*E;
    const int  nb3 = CDIV(3*N, 512);

    // ===== converts (weights merged + x_e), pads zeroed =====
    hipMemsetAsync(Wb, 0, (size_t)2*NB*Kp*2, stream);
    hipMemsetAsync(Axb + (size_t)N*Kp, 0, (size_t)(Mpad-N)*Kp*2, stream);
    k_cvt_w4<<<cvtW4Grid,256,0,stream>>>(g1w, h1w, g2w, h2w, npk, W0, W1);
    k_cvt_pack1<<<cvtBigGrid,256,0,stream>>>(x_e, 300, N, 300, npk, 0, Axb);

    // ===== merged CSR build (A, H, T) =====
    hipMemsetAsync(cntAll, 0, (size_t)6*N*4, stream);
    k_hist3<<<CDIV(ETOT,256),256,0,stream>>>(iA, hE, tE, cntAll, EA, E, N);
    k_scan1<<<nb3,512,0,stream>>>(cntAll, rowptrG, bsum, 3*N);
    k_scan2<<<1,1024,0,stream>>>(bsum, nb3);
    k_scan3<<<nb3,512,0,stream>>>(rowptrG, bsum, 3*N);
    k_fill3<<<CDIV(ETOT,256),256,0,stream>>>(iA, hE, tE, rowptrG, curAll, permAll, EA, E, N);
    k_dinv_cnt<<<CDIV(N,256),256,0,stream>>>(cntAll, dinv, N);
    k_prep_gcn<<<CDIV(EA,256),256,0,stream>>>(permAll, jA, iA, dinv, jpA, nmA, EA);
    k_permute3<<<CDIV(ETOT,256),256,0,stream>>>(rel_all, rel, permAll, relpAll, EA, E, R);

    // ===== GCN layer 1: GEMM (bf16) + gather/highway -> Axb pack + xbf =====
    k_gemm_frag<<<gemmBlocks,256,0,stream>>>(Axb, W0, Ascr, LDC, N, 620, npk, nrb);
    k_gather_hw<<<gatherGrid,256,0,stream>>>(Ascr, LDC, Ascr+320,
                                             x_e, (const unsigned short*)nullptr, h1b,
                                             jpA, nmA, rowptrG, cntAll,
                                             (float*)nullptr, OUTC, Axb, xbf,
                                             (const float*)nullptr, (const float*)nullptr,
                                             (float*)nullptr, (float*)nullptr, npk, N);

    // ===== GCN layer 2: x1 from xbf (bf16), out write + xbf update + GAT dots =====
    k_gemm_frag<<<gemmBlocks,256,0,stream>>>(Axb, W1, Ascr, LDC, N, 620, npk, nrb);
    k_gather_hw<<<gatherGrid,256,0,stream>>>(Ascr, LDC, Ascr+320,
                                             (const float*)nullptr, xbf, h2b,
                                             jpA, nmA, rowptrG, cntAll,
                                             out, OUTC, (unsigned short*)nullptr, xbf,
                                             gat_ai, gat_aj, sA_, sB_, npk, N);

    // ===== merged l_gat over both line graphs =====
    hipMemsetAsync(lg, 0, ((size_t)12*R + (size_t)2*R*RH)*4, stream);
    const int lgGrid = CDIV(2*LGE, 256);
    k_lgat_max  <<<lgGrid,256,0,stream>>>(mval, tval, iM, jM, iT, jT, lmi, lmj, LGE, R);
    k_lgat_sum  <<<lgGrid,256,0,stream>>>(mval, tval, iM, jM, iT, jT, lmi, lmj, lsi, lsj, LGE, R);
    k_lgat_vsum2<<<lgGrid,256,0,stream>>>(mval, tval, iM, jM, iT, jT, lmi, lsi, lmj, lsj,
                                          vsum, LGE, R);
    k_lgat_max2 <<<lgGrid,256,0,stream>>>(vsum, jM, jT, lm2, LGE, R);
    k_lgat_sum2 <<<lgGrid,256,0,stream>>>(vsum, jM, jT, lm2, ls2, LGE, R);
    k_lgat_agg  <<<CDIV(2*LGE*64,256),256,0,stream>>>(vsum, lm2, ls2, iM, jM, iT, jT,
                                                      remb1, remb2, obuf, LGE, R, RH);
    k_relu2d    <<<CDIV((long)2*R*RH,256),256,0,stream>>>(obuf, 2*R, RH, RH);

    // ===== x_r = highway(mrg, tri, hrw, hrb) =====
    dim3 gridR(CDIV(RH,GBN), CDIV(R,GBM));
    k_gemm<<<gridR,256,0,stream>>>(mrg, RH, hrw, RH, xrg, RH, R, RH, RH);
    k_highway<<<CDIV((long)R*RH,256),256,0,stream>>>(mrg, RH, xrg, RH, tri, RH, hrb, xr, RH, R, RH, 0);

    // relscore[r] = rel_cat[r]·gat_ar
    k_relscore<<<CDIV((long)R*64,256),256,0,stream>>>(mrg, tri, gat_ar, rsc, R, RH);

    // ===== GAT -> out cols 300..599 + r2e score dots =====
    k_gat300<<<gatherGrid,256,0,stream>>>(xbf, sA_, sB_, rsc, jpA, relpAll,
                                          rowptrG, cntAll, out+300, OUTC,
                                          g2e_ah, g2e_at, sH_, sT_, N);

    // ===== gat_r_to_e -> out cols 600..799 (h+t merged) =====
    k_rowdot2<<<CDIV((long)R*64,256),256,0,stream>>>(xr, RH, R, RH, g2e_ar, (const float*)nullptr,
                                                     srel, (float*)nullptr);
    k_gather_rel2<<<CDIV(2*N,4),256,0,stream>>>(xr, sH_, sT_, srel, relpAll,
                                                rowptrG + N, cntAll + N,
                                                rowptrG + 2*N, cntAll + 2*N,
                                                out, OUTC, N);
}

// Round 14
// 1206.306 us; speedup vs baseline: 1.3940x; 1.0141x over previous
//
#include <hip/hip_runtime.h>

#define WAVE 64
#define CDIV(a,b) (((a)+(b)-1)/(b))
#define XBS 320   // xbf row stride in shorts (640B rows)

typedef float f32x16 __attribute__((ext_vector_type(16)));
typedef unsigned short u16x8 __attribute__((ext_vector_type(8)));

// ---------- bf16 helpers ----------
__device__ __forceinline__ unsigned short f2bf_rne(float f) {
    unsigned u = __float_as_uint(f);
    unsigned r = (u + 0x7FFFu + ((u >> 16) & 1u)) >> 16;
    return (unsigned short)r;
}
__device__ __forceinline__ float bf2f(unsigned short h) {
    return __uint_as_float(((unsigned)h) << 16);
}
__device__ __forceinline__ float2 bfp2f(ushort2 u) {
    float2 r; r.x = bf2f(u.x); r.y = bf2f(u.y); return r;
}
__device__ __forceinline__ float sigm(float x) { return 1.0f / (1.0f + expf(-x)); }

#define MFMA32(acc, a, b) \
    asm volatile("v_mfma_f32_32x32x16_bf16 %0, %1, %2, %0" : "+v"(acc) : "v"(a), "v"(b))

// ---------- monotonic float<->uint encoding for atomicMax on floats ----------
__device__ __forceinline__ unsigned f2mono(float f) {
    unsigned u = __float_as_uint(f);
    return (u & 0x80000000u) ? ~u : (u | 0x80000000u);
}
__device__ __forceinline__ float mono2f(unsigned u) {
    return (u & 0x80000000u) ? __uint_as_float(u & 0x7fffffffu) : __uint_as_float(~u);
}
__device__ __forceinline__ float leaky(float v) { return (v > 0.0f) ? v : 0.01f*v; }

// fragment-pack offset: matrix row r, col k -> packed short index.
__device__ __forceinline__ long fragoff(long r, int k, int npk) {
    return ((r >> 5) * (long)npk + (k >> 4)) * 512
         + (((k >> 3) & 1) << 8) + ((r & 31) << 3) + (k & 7);
}

// ---------- k_cvt_pack1: f32 -> fragment-packed single bf16 (rne) ----------
__global__ void k_cvt_pack1(const float* __restrict__ src, long ld, int rows, int K, int npk,
                            int roff, unsigned short* __restrict__ dst)
{
    int nc4 = npk << 2;
    long idx = (long)blockIdx.x*blockDim.x + threadIdx.x;
    if (idx >= (long)rows * nc4) return;
    long r = idx / nc4; int k = (int)(idx % nc4) << 2;
    float4 v = {0.0f, 0.0f, 0.0f, 0.0f};
    if (k + 4 <= K) v = *(const float4*)(src + r*ld + k);
    ushort4 h;
    h.x = f2bf_rne(v.x); h.y = f2bf_rne(v.y); h.z = f2bf_rne(v.z); h.w = f2bf_rne(v.w);
    *(ushort4*)(dst + fragoff(r + roff, k, npk)) = h;
}

// merged weight convert: 4 matrices [300][300] -> W0(g@0,h@320), W1(g@0,h@320)
__global__ void k_cvt_w4(const float* __restrict__ g1w, const float* __restrict__ h1w,
                         const float* __restrict__ g2w, const float* __restrict__ h2w,
                         int npk, unsigned short* __restrict__ W0,
                         unsigned short* __restrict__ W1)
{
    const int nc4 = npk << 2;                 // 76
    const long per = (long)300 * nc4;
    long idx = (long)blockIdx.x*blockDim.x + threadIdx.x;
    if (idx >= 4*per) return;
    int which = (int)(idx / per);
    long lidx = idx % per;
    long r = lidx / nc4; int k = (int)(lidx % nc4) << 2;
    const float* src = (which == 0) ? g1w : (which == 1) ? h1w : (which == 2) ? g2w : h2w;
    unsigned short* dst = (which < 2) ? W0 : W1;
    int roff = (which & 1) ? 320 : 0;
    float4 v = {0.0f, 0.0f, 0.0f, 0.0f};
    if (k + 4 <= 300) v = *(const float4*)(src + r*300 + k);
    ushort4 h;
    h.x = f2bf_rne(v.x); h.y = f2bf_rne(v.y); h.z = f2bf_rne(v.z); h.w = f2bf_rne(v.w);
    *(ushort4*)(dst + fragoff(r + roff, k, npk)) = h;
}

// =========================================================================
// k_gemm_frag: C[M,620] (bf16) = A * B^T; A and B single bf16 (rne).
// NO LDS, NO barriers. XCD-ownership swizzle. 4 MFMA / 5 loads per k-step.
// =========================================================================
__global__ __launch_bounds__(256, 3)
void k_gemm_frag(const unsigned short* __restrict__ Ab,
                 const unsigned short* __restrict__ Bb,
                 unsigned short* __restrict__ C, long ldc, int M, int N, int nk, int nrb)
{
    const int lane = threadIdx.x & 63;
    const int wid  = threadIdx.x >> 6;
    const int lin  = blockIdx.x;
    const int xcd  = lin & 7;
    const int m    = lin >> 3;
    const int col0 = (m % 5) * 128;
    const int rb   = xcd + ((m / 5) << 3);
    if (rb >= nrb) return;
    const int row0 = rb * 128 + wid * 32;

    const long cs = (long)nk * 512;
    const unsigned short* pA = Ab + (long)(row0 >> 5) * cs + lane * 8;
    const unsigned short* pB = Bb + (long)(col0 >> 5) * cs + lane * 8;

    f32x16 acc[4];
    #pragma unroll
    for (int c = 0; c < 4; ++c) acc[c] = (f32x16)0.0f;

    u16x8 pa, pb0, pb1, pb2, pb3;
    u16x8 qa, qb0, qb1, qb2, qb3;

    #define LOADP(t_) { long o = (long)(t_)*512;                                   \
        pa  = *(const u16x8*)(pA + o);                                             \
        pb0 = *(const u16x8*)(pB + o);        pb1 = *(const u16x8*)(pB + cs + o);  \
        pb2 = *(const u16x8*)(pB + 2*cs + o); pb3 = *(const u16x8*)(pB + 3*cs + o); }
    #define LOADQ(t_) { long o = (long)(t_)*512;                                   \
        qa  = *(const u16x8*)(pA + o);                                             \
        qb0 = *(const u16x8*)(pB + o);        qb1 = *(const u16x8*)(pB + cs + o);  \
        qb2 = *(const u16x8*)(pB + 2*cs + o); qb3 = *(const u16x8*)(pB + 3*cs + o); }
    #define STEPP {                                                                 \
        MFMA32(acc[0], pa, pb0); MFMA32(acc[1], pa, pb1);                           \
        MFMA32(acc[2], pa, pb2); MFMA32(acc[3], pa, pb3); }
    #define STEPQ {                                                                 \
        MFMA32(acc[0], qa, qb0); MFMA32(acc[1], qa, qb1);                           \
        MFMA32(acc[2], qa, qb2); MFMA32(acc[3], qa, qb3); }

    LOADP(0);
    int t = 0;
    for (;;) {
        bool m1 = (t + 1 < nk);
        if (m1) LOADQ(t + 1);
        STEPP;
        if (!m1) break;
        bool m2 = (t + 2 < nk);
        if (m2) LOADP(t + 2);
        STEPQ;
        if (!m2) break;
        t += 2;
    }
    #undef LOADP
    #undef LOADQ
    #undef STEPP
    #undef STEPQ

    const int crow0 = row0 + 4*(lane >> 5);
    const int ccol0 = col0 + (lane & 31);
    #pragma unroll
    for (int c = 0; c < 4; ++c) {
        int col = ccol0 + c*32;
        if (col >= N) continue;
        #pragma unroll
        for (int reg = 0; reg < 16; ++reg) {
            int row = crow0 + (reg & 3) + 8*(reg >> 2);
            if (row < M) C[(long)row*ldc + col] = f2bf_rne(acc[c][reg]);
        }
    }
}

// ---------- small f32 GEMM (tiny R x RH highway gate) ----------
#define GBM 64
#define GBN 64
#define GBK 16
__global__ __launch_bounds__(256)
void k_gemm(const float* __restrict__ A, long lda,
            const float* __restrict__ B, long ldb,
            float* __restrict__ C, long ldc,
            int M, int N, int K)
{
    __shared__ float As[GBK][GBM + 4];
    __shared__ float Bs[GBK][GBN + 4];
    const int tid = threadIdx.x;
    const int tx = tid & 15, ty = tid >> 4;
    const int row0 = blockIdx.y * GBM, col0 = blockIdx.x * GBN;
    float acc[4][4] = {};
    for (int kt = 0; kt < K; kt += GBK) {
        #pragma unroll
        for (int p = 0; p < 4; ++p) {
            int mn = (tid >> 4) + p * 16;
            int k  = tid & 15;
            int gk = kt + k;
            int gr = row0 + mn;
            As[k][mn] = (gr < M && gk < K) ? A[(long)gr * lda + gk] : 0.0f;
            int gc = col0 + mn;
            Bs[k][mn] = (gc < N && gk < K) ? B[(long)gc * ldb + gk] : 0.0f;
        }
        __syncthreads();
        #pragma unroll
        for (int kk = 0; kk < GBK; ++kk) {
            float a0 = As[kk][ty*4+0], a1 = As[kk][ty*4+1];
            float a2 = As[kk][ty*4+2], a3 = As[kk][ty*4+3];
            float b0 = Bs[kk][tx*4+0], b1 = Bs[kk][tx*4+1];
            float b2 = Bs[kk][tx*4+2], b3 = Bs[kk][tx*4+3];
            acc[0][0] += a0*b0; acc[0][1] += a0*b1; acc[0][2] += a0*b2; acc[0][3] += a0*b3;
            acc[1][0] += a1*b0; acc[1][1] += a1*b1; acc[1][2] += a1*b2; acc[1][3] += a1*b3;
            acc[2][0] += a2*b0; acc[2][1] += a2*b1; acc[2][2] += a2*b2; acc[2][3] += a2*b3;
            acc[3][0] += a3*b0; acc[3][1] += a3*b1; acc[3][2] += a3*b2; acc[3][3] += a3*b3;
        }
        __syncthreads();
    }
    #pragma unroll
    for (int i2 = 0; i2 < 4; ++i2)
        #pragma unroll
        for (int j2 = 0; j2 < 4; ++j2) {
            int r = row0 + ty*4 + i2, c = col0 + tx*4 + j2;
            if (r < M && c < N) C[(long)r*ldc + c] = acc[i2][j2];
        }
}

// ================= merged CSR build over 3 graphs =================
__global__ void k_hist3(const int* __restrict__ iA, const int* __restrict__ hE,
                        const int* __restrict__ tE, int* __restrict__ cnt,
                        int EA, int E, int N) {
    int e = blockIdx.x*blockDim.x + threadIdx.x;
    int tot = EA + 2*E;
    if (e >= tot) return;
    if (e < EA)            atomicAdd(&cnt[iA[e]], 1);
    else if (e < EA + E)   atomicAdd(&cnt[N + hE[e - EA]], 1);
    else                   atomicAdd(&cnt[2*N + tE[e - EA - E]], 1);
}
__global__ void k_scan1(const int* __restrict__ in, int* __restrict__ out,
                        int* __restrict__ bsum, int n) {
    __shared__ int sh[512];
    int gid = blockIdx.x*512 + threadIdx.x;
    int v = (gid < n) ? in[gid] : 0;
    sh[threadIdx.x] = v; __syncthreads();
    for (int o = 1; o < 512; o <<= 1) {
        int t = (threadIdx.x >= o) ? sh[threadIdx.x - o] : 0;
        __syncthreads();
        sh[threadIdx.x] += t;
        __syncthreads();
    }
    if (gid < n) out[gid] = sh[threadIdx.x] - v;      // exclusive
    if (threadIdx.x == 511) bsum[blockIdx.x] = sh[511];
}
__global__ void k_scan2(int* __restrict__ bsum, int nb) {   // single block, nb <= 1024
    __shared__ int sh[1024];
    int v = (threadIdx.x < nb) ? bsum[threadIdx.x] : 0;
    sh[threadIdx.x] = v; __syncthreads();
    for (int o = 1; o < 1024; o <<= 1) {
        int t = (threadIdx.x >= o) ? sh[threadIdx.x - o] : 0;
        __syncthreads();
        sh[threadIdx.x] += t;
        __syncthreads();
    }
    if (threadIdx.x < nb) bsum[threadIdx.x] = sh[threadIdx.x] - v;  // exclusive
}
__global__ void k_scan3(int* __restrict__ out, const int* __restrict__ bsum, int n) {
    int gid = blockIdx.x*512 + threadIdx.x;
    if (gid < n) out[gid] += bsum[blockIdx.x];
}
// fused fill: place edge at CSR slot AND write jp/nm (graph A) + relp directly.
__global__ void k_fill3f(const int* __restrict__ iA, const int* __restrict__ jA,
                         const int* __restrict__ hE, const int* __restrict__ tE,
                         const int* __restrict__ rel_all, const int* __restrict__ rel,
                         const int* __restrict__ rowptr, const int* __restrict__ cnt,
                         int* __restrict__ cursor,
                         int* __restrict__ jp, float* __restrict__ nm,
                         int* __restrict__ relp,
                         int EA, int E, int N, int R) {
    int e = blockIdx.x*blockDim.x + threadIdx.x;
    int tot = EA + 2*E;
    if (e >= tot) return;
    if (e < EA) {
        int le = e;
        int i = iA[le];
        int p = rowptr[i] + atomicAdd(&cursor[i], 1);
        int j = jA[le];
        jp[p] = j;
        float di = rsqrtf((float)cnt[i]);                 // cnt[i] >= 1 (edge exists)
        int cj = cnt[j];
        float dj = (cj > 0) ? rsqrtf((float)cj) : 0.0f;
        nm[p] = di * dj;
        relp[p] = rel_all[le] % R;
    } else if (e < EA + E) {
        int le = e - EA;
        int key = N + hE[le];
        int p = rowptr[key] + atomicAdd(&cursor[key], 1);
        relp[p] = rel[le];
    } else {
        int le = e - EA - E;
        int key = 2*N + tE[le];
        int p = rowptr[key] + atomicAdd(&cursor[key], 1);
        relp[p] = rel[le];
    }
}

// =========================================================================
// k_gather_hw: fused GCN gather (bf16 src, 8/4/1 edge unroll) + relu +
// highway + extras. x1 from f32 (x1f) or xbf bf16 stride XBS (x1b).
// =========================================================================
__global__ void k_gather_hw(const unsigned short* __restrict__ xg, long ldx,
                            const unsigned short* __restrict__ gl,
                            const float* __restrict__ x1f,
                            const unsigned short* __restrict__ x1b,
                            const float* __restrict__ bias,
                            const int* __restrict__ jp, const float* __restrict__ nm,
                            const int* __restrict__ rowptr, const int* __restrict__ cnt,
                            float* __restrict__ outp, long ldo,
                            unsigned short* __restrict__ pk,
                            unsigned short* __restrict__ xbf,
                            const float* __restrict__ ai, const float* __restrict__ aj,
                            float* __restrict__ sa, float* __restrict__ sb,
                            int npk, int n)
{
    int w = (blockIdx.x*blockDim.x + threadIdx.x) >> 6;
    int lane = threadIdx.x & 63;
    if (w >= n) return;
    int beg = rowptr[w], end = beg + cnt[w];
    const int i0 = lane, i1 = lane + 64, i2 = lane + 128;
    const bool t3 = (lane < 22);
    float2 a0 = {0,0}, a1 = {0,0}, a2 = {0,0};
    int e = beg;
    for (; e + 8 <= end; e += 8) {
        long jj[8]; float wt[8];
        #pragma unroll
        for (int u = 0; u < 8; ++u) { jj[u] = jp[e+u]; wt[u] = nm[e+u]; }
        #pragma unroll
        for (int u = 0; u < 8; ++u) {
            float2 v = bfp2f(((const ushort2*)(xg + jj[u]*ldx))[i0]);
            a0.x += wt[u]*v.x; a0.y += wt[u]*v.y;
        }
        #pragma unroll
        for (int u = 0; u < 8; ++u) {
            float2 v = bfp2f(((const ushort2*)(xg + jj[u]*ldx))[i1]);
            a1.x += wt[u]*v.x; a1.y += wt[u]*v.y;
        }
        if (t3) {
            #pragma unroll
            for (int u = 0; u < 8; ++u) {
                float2 v = bfp2f(((const ushort2*)(xg + jj[u]*ldx))[i2]);
                a2.x += wt[u]*v.x; a2.y += wt[u]*v.y;
            }
        }
    }
    for (; e + 4 <= end; e += 4) {
        long jj[4]; float wt[4];
        #pragma unroll
        for (int u = 0; u < 4; ++u) { jj[u] = jp[e+u]; wt[u] = nm[e+u]; }
        #pragma unroll
        for (int u = 0; u < 4; ++u) {
            float2 v = bfp2f(((const ushort2*)(xg + jj[u]*ldx))[i0]);
            a0.x += wt[u]*v.x; a0.y += wt[u]*v.y;
        }
        #pragma unroll
        for (int u = 0; u < 4; ++u) {
            float2 v = bfp2f(((const ushort2*)(xg + jj[u]*ldx))[i1]);
            a1.x += wt[u]*v.x; a1.y += wt[u]*v.y;
        }
        if (t3) {
            #pragma unroll
            for (int u = 0; u < 4; ++u) {
                float2 v = bfp2f(((const ushort2*)(xg + jj[u]*ldx))[i2]);
                a2.x += wt[u]*v.x; a2.y += wt[u]*v.y;
            }
        }
    }
    for (; e < end; ++e) {
        long j0 = jp[e]; float w0 = nm[e];
        float2 v;
        v = bfp2f(((const ushort2*)(xg + j0*ldx))[i0]); a0.x += w0*v.x; a0.y += w0*v.y;
        v = bfp2f(((const ushort2*)(xg + j0*ldx))[i1]); a1.x += w0*v.x; a1.y += w0*v.y;
        if (t3) { v = bfp2f(((const ushort2*)(xg + j0*ldx))[i2]); a2.x += w0*v.x; a2.y += w0*v.y; }
    }
    // highway: o = sig(gl+b)*relu(acc) + (1-sig)*x1
    const ushort2* glr = (const ushort2*)(gl + (long)w*ldx);
    const float2*  x1r = (const float2*)(x1f + (long)w*300);
    const ushort2* x1r2 = (const ushort2*)(x1b + (long)w*XBS);
    const float2*  br  = (const float2*)bias;
    float2 o0 = {0,0}, o1 = {0,0}, o2 = {0,0};
    {
        float2 gv = bfp2f(glr[i0]); float2 bv = br[i0];
        float2 xv = x1f ? x1r[i0] : bfp2f(x1r2[i0]);
        float g0 = sigm(gv.x + bv.x), g1 = sigm(gv.y + bv.y);
        o0.x = g0*fmaxf(a0.x,0.0f) + (1.0f-g0)*xv.x;
        o0.y = g1*fmaxf(a0.y,0.0f) + (1.0f-g1)*xv.y;
    }
    {
        float2 gv = bfp2f(glr[i1]); float2 bv = br[i1];
        float2 xv = x1f ? x1r[i1] : bfp2f(x1r2[i1]);
        float g0 = sigm(gv.x + bv.x), g1 = sigm(gv.y + bv.y);
        o1.x = g0*fmaxf(a1.x,0.0f) + (1.0f-g0)*xv.x;
        o1.y = g1*fmaxf(a1.y,0.0f) + (1.0f-g1)*xv.y;
    }
    if (t3) {
        float2 gv = bfp2f(glr[i2]); float2 bv = br[i2];
        float2 xv = x1f ? x1r[i2] : bfp2f(x1r2[i2]);
        float g0 = sigm(gv.x + bv.x), g1 = sigm(gv.y + bv.y);
        o2.x = g0*fmaxf(a2.x,0.0f) + (1.0f-g0)*xv.x;
        o2.y = g1*fmaxf(a2.y,0.0f) + (1.0f-g1)*xv.y;
    }
    if (outp) {
        float2* dst = (float2*)(outp + (long)w*ldo);
        dst[i0] = o0; dst[i1] = o1;
        if (t3) dst[i2] = o2;
    }
    if (pk) {
        auto pack2 = [&](int k, float2 o) {
            ushort2 hv; hv.x = f2bf_rne(o.x); hv.y = f2bf_rne(o.y);
            *(ushort2*)(pk + fragoff(w, k, npk)) = hv;
        };
        pack2(2*lane, o0);
        pack2(128 + 2*lane, o1);
        if (t3) pack2(256 + 2*lane, o2);
        else if (lane < 24) {
            ushort2 z = {0,0};
            *(ushort2*)(pk + fragoff(w, 256 + 2*lane, npk)) = z;
        }
    }
    if (xbf) {
        ushort2* xw = (ushort2*)(xbf + (long)w*XBS);
        ushort2 t;
        t.x = f2bf_rne(o0.x); t.y = f2bf_rne(o0.y); xw[i0] = t;
        t.x = f2bf_rne(o1.x); t.y = f2bf_rne(o1.y); xw[i1] = t;
        if (t3) { t.x = f2bf_rne(o2.x); t.y = f2bf_rne(o2.y); xw[i2] = t; }
    }
    if (sa) {
        const float2* ai2 = (const float2*)ai;
        const float2* aj2 = (const float2*)aj;
        float2 A0 = ai2[i0], A1 = ai2[i1], J0 = aj2[i0], J1 = aj2[i1];
        float sva = o0.x*A0.x + o0.y*A0.y + o1.x*A1.x + o1.y*A1.y;
        float svb = o0.x*J0.x + o0.y*J0.y + o1.x*J1.x + o1.y*J1.y;
        if (t3) {
            float2 A2 = ai2[i2], J2 = aj2[i2];
            sva += o2.x*A2.x + o2.y*A2.y;
            svb += o2.x*J2.x + o2.y*J2.y;
        }
        #pragma unroll
        for (int o = 32; o > 0; o >>= 1) {
            sva += __shfl_down(sva, o);
            svb += __shfl_down(svb, o);
        }
        if (lane == 0) { sa[w] = sva; sb[w] = svb; }
    }
}

// =========================================================================
// k_gat300: fused edge score + segment softmax + weighted gather (bf16,
// 8/4/1 unroll) + relu -> out cols 300..599, PLUS r2e score dots.
// =========================================================================
__global__ void k_gat300(const unsigned short* __restrict__ xbf,
                         const float* __restrict__ sA, const float* __restrict__ sB,
                         const float* __restrict__ rsc,
                         const int* __restrict__ jp, const int* __restrict__ relp,
                         const int* __restrict__ rowptr, const int* __restrict__ cnt,
                         float* __restrict__ out, long ldo,
                         const float* __restrict__ ah, const float* __restrict__ at,
                         float* __restrict__ sh, float* __restrict__ st,
                         int n)
{
    int w = (blockIdx.x*blockDim.x + threadIdx.x) >> 6;
    int lane = threadIdx.x & 63;
    if (w >= n) return;
    int beg = rowptr[w], c = cnt[w];
    const int i0 = lane, i1 = lane + 64, i2 = lane + 128;
    const bool t3 = (lane < 22);
    float2 a0 = {0,0}, a1 = {0,0}, a2 = {0,0};
    if (c > 0) {
        float base = sA[w];
        int   jc = 0;
        float sval = -3.4e38f;
        if (lane < c) {
            jc = jp[beg + lane];
            sval = leaky(base + sB[jc] + rsc[relp[beg + lane]]);
        }
        float mx = sval;
        for (int t = 64 + lane; t < c; t += 64)
            mx = fmaxf(mx, leaky(base + sB[jp[beg+t]] + rsc[relp[beg+t]]));
        #pragma unroll
        for (int o = 32; o > 0; o >>= 1) mx = fmaxf(mx, __shfl_xor(mx, o));
        float pexp = (lane < c) ? expf(sval - mx) : 0.0f;
        float ss = pexp;
        for (int t = 64 + lane; t < c; t += 64)
            ss += expf(leaky(base + sB[jp[beg+t]] + rsc[relp[beg+t]]) - mx);
        #pragma unroll
        for (int o = 32; o > 0; o >>= 1) ss += __shfl_xor(ss, o);
        float inv = 1.0f / (ss + 1e-16f);
        int q = 0;
        int cc = (c < 64) ? c : 64;
        for (; q + 8 <= cc; q += 8) {
            float al[8]; long jj[8];
            #pragma unroll
            for (int u = 0; u < 8; ++u) {
                al[u] = __shfl(pexp, q+u) * inv;
                jj[u] = __shfl(jc, q+u);
            }
            #pragma unroll
            for (int u = 0; u < 8; ++u) {
                float2 v = bfp2f(((const ushort2*)(xbf + jj[u]*XBS))[i0]);
                a0.x += al[u]*v.x; a0.y += al[u]*v.y;
            }
            #pragma unroll
            for (int u = 0; u < 8; ++u) {
                float2 v = bfp2f(((const ushort2*)(xbf + jj[u]*XBS))[i1]);
                a1.x += al[u]*v.x; a1.y += al[u]*v.y;
            }
            if (t3) {
                #pragma unroll
                for (int u = 0; u < 8; ++u) {
                    float2 v = bfp2f(((const ushort2*)(xbf + jj[u]*XBS))[i2]);
                    a2.x += al[u]*v.x; a2.y += al[u]*v.y;
                }
            }
        }
        for (; q + 4 <= cc; q += 4) {
            float al[4]; long jj[4];
            #pragma unroll
            for (int u = 0; u < 4; ++u) {
                al[u] = __shfl(pexp, q+u) * inv;
                jj[u] = __shfl(jc, q+u);
            }
            #pragma unroll
            for (int u = 0; u < 4; ++u) {
                float2 v = bfp2f(((const ushort2*)(xbf + jj[u]*XBS))[i0]);
                a0.x += al[u]*v.x; a0.y += al[u]*v.y;
            }
            #pragma unroll
            for (int u = 0; u < 4; ++u) {
                float2 v = bfp2f(((const ushort2*)(xbf + jj[u]*XBS))[i1]);
                a1.x += al[u]*v.x; a1.y += al[u]*v.y;
            }
            if (t3) {
                #pragma unroll
                for (int u = 0; u < 4; ++u) {
                    float2 v = bfp2f(((const ushort2*)(xbf + jj[u]*XBS))[i2]);
                    a2.x += al[u]*v.x; a2.y += al[u]*v.y;
                }
            }
        }
        for (; q < c; ++q) {
            float al; long j0;
            if (q < 64) { al = __shfl(pexp, q) * inv; j0 = __shfl(jc, q); }
            else {
                j0 = jp[beg + q];
                al = expf(leaky(base + sB[(int)j0] + rsc[relp[beg+q]]) - mx) * inv;
            }
            float2 v;
            v = bfp2f(((const ushort2*)(xbf + j0*XBS))[i0]); a0.x += al*v.x; a0.y += al*v.y;
            v = bfp2f(((const ushort2*)(xbf + j0*XBS))[i1]); a1.x += al*v.x; a1.y += al*v.y;
            if (t3) { v = bfp2f(((const ushort2*)(xbf + j0*XBS))[i2]); a2.x += al*v.x; a2.y += al*v.y; }
        }
    }
    a0.x = fmaxf(a0.x, 0.0f); a0.y = fmaxf(a0.y, 0.0f);
    a1.x = fmaxf(a1.x, 0.0f); a1.y = fmaxf(a1.y, 0.0f);
    a2.x = fmaxf(a2.x, 0.0f); a2.y = fmaxf(a2.y, 0.0f);
    float2* dst = (float2*)(out + (long)w*ldo);
    dst[i0] = a0; dst[i1] = a1;
    if (t3) dst[i2] = a2;
    {
        const ushort2* xw = (const ushort2*)(xbf + (long)w*XBS);
        const float2* ahL = (const float2*)ah;
        const float2* atL = (const float2*)at;
        const float2* ahH = (const float2*)(ah + 300);
        const float2* atH = (const float2*)(at + 300);
        float2 x0 = bfp2f(xw[i0]), x1v = bfp2f(xw[i1]);
        float svh = x0.x*ahL[i0].x + x0.y*ahL[i0].y + x1v.x*ahL[i1].x + x1v.y*ahL[i1].y
                  + a0.x*ahH[i0].x + a0.y*ahH[i0].y + a1.x*ahH[i1].x + a1.y*ahH[i1].y;
        float svt = x0.x*atL[i0].x + x0.y*atL[i0].y + x1v.x*atL[i1].x + x1v.y*atL[i1].y
                  + a0.x*atH[i0].x + a0.y*atH[i0].y + a1.x*atH[i1].x + a1.y*atH[i1].y;
        if (t3) {
            float2 x2v = bfp2f(xw[i2]);
            svh += x2v.x*ahL[i2].x + x2v.y*ahL[i2].y + a2.x*ahH[i2].x + a2.y*ahH[i2].y;
            svt += x2v.x*atL[i2].x + x2v.y*atL[i2].y + a2.x*atH[i2].x + a2.y*atH[i2].y;
        }
        #pragma unroll
        for (int o = 32; o > 0; o >>= 1) {
            svh += __shfl_down(svh, o);
            svt += __shfl_down(svt, o);
        }
        if (lane == 0) { sh[w] = svh; st[w] = svt; }
    }
}

// r2e (h+t merged): fused score + softmax + gather of xrb (bf16 [R][128])
__global__ void k_gather_rel2(const unsigned short* __restrict__ xrb,
                              const float* __restrict__ sH, const float* __restrict__ sT,
                              const float* __restrict__ srel,
                              const int* __restrict__ relp,
                              const int* __restrict__ rowptrH, const int* __restrict__ cntH,
                              const int* __restrict__ rowptrT, const int* __restrict__ cntT,
                              float* __restrict__ out, long ldo, int n)
{
    int gw = (blockIdx.x*blockDim.x + threadIdx.x) >> 6;
    int lane = threadIdx.x & 63;
    if (gw >= 2*n) return;
    const bool isT = (gw >= n);
    const int w = isT ? gw - n : gw;
    const float* snode = isT ? sT : sH;
    const int* rowptr = isT ? rowptrT : rowptrH;
    const int* cnt    = isT ? cntT    : cntH;
    float* dst = out + (isT ? 700 : 600) + (long)w*ldo;
    int beg = rowptr[w], c = cnt[w];
    const bool t0 = (lane < 50);
    float2 a0 = {0,0};
    if (c > 0) {
        float base = snode[w];
        int   rc = 0;
        float sval = -3.4e38f;
        if (lane < c) {
            rc = relp[beg + lane];
            sval = leaky(base + srel[rc]);
        }
        float mx = sval;
        for (int t = 64 + lane; t < c; t += 64)
            mx = fmaxf(mx, leaky(base + srel[relp[beg+t]]));
        #pragma unroll
        for (int o = 32; o > 0; o >>= 1) mx = fmaxf(mx, __shfl_xor(mx, o));
        float pexp = (lane < c) ? expf(sval - mx) : 0.0f;
        float ss = pexp;
        for (int t = 64 + lane; t < c; t += 64)
            ss += expf(leaky(base + srel[relp[beg+t]]) - mx);
        #pragma unroll
        for (int o = 32; o > 0; o >>= 1) ss += __shfl_xor(ss, o);
        float inv = 1.0f / (ss + 1e-16f);
        int q = 0;
        int cc = (c < 64) ? c : 64;
        for (; q + 4 <= cc; q += 4) {
            float al0 = __shfl(pexp, q)   * inv;
            float al1 = __shfl(pexp, q+1) * inv;
            float al2 = __shfl(pexp, q+2) * inv;
            float al3 = __shfl(pexp, q+3) * inv;
            long r0i = __shfl(rc, q), r1i = __shfl(rc, q+1);
            long r2i = __shfl(rc, q+2), r3i = __shfl(rc, q+3);
            if (t0) {
                float2 v;
                v = bfp2f(((const ushort2*)(xrb + r0i*128))[lane]); a0.x += al0*v.x; a0.y += al0*v.y;
                v = bfp2f(((const ushort2*)(xrb + r1i*128))[lane]); a0.x += al1*v.x; a0.y += al1*v.y;
                v = bfp2f(((const ushort2*)(xrb + r2i*128))[lane]); a0.x += al2*v.x; a0.y += al2*v.y;
                v = bfp2f(((const ushort2*)(xrb + r3i*128))[lane]); a0.x += al3*v.x; a0.y += al3*v.y;
            }
        }
        for (; q < c; ++q) {
            float al; long r0i;
            if (q < 64) { al = __shfl(pexp, q) * inv; r0i = __shfl(rc, q); }
            else {
                r0i = relp[beg + q];
                al = expf(leaky(base + srel[(int)r0i]) - mx) * inv;
            }
            if (t0) {
                float2 v = bfp2f(((const ushort2*)(xrb + r0i*128))[lane]);
                a0.x += al*v.x; a0.y += al*v.y;
            }
        }
    }
    if (t0) ((float2*)dst)[lane] = a0;
}

// ================= merged l_gat over both line graphs =================
__global__ void k_lgat_max(const float* __restrict__ mval, const float* __restrict__ tval,
                           const int* __restrict__ iM, const int* __restrict__ jM,
                           const int* __restrict__ iT, const int* __restrict__ jT,
                           unsigned* __restrict__ mi, unsigned* __restrict__ mj,
                           int LGE, int R)
{
    int e = blockIdx.x*blockDim.x + threadIdx.x;
    if (e >= 2*LGE) return;
    bool g1 = e >= LGE; int le = g1 ? e - LGE : e;
    float v = g1 ? tval[le] : mval[le];
    int i = (g1 ? iT[le] : iM[le]) + (g1 ? R : 0);
    int j = (g1 ? jT[le] : jM[le]) + (g1 ? R : 0);
    unsigned mv = f2mono(v);
    atomicMax(&mi[i], mv);
    atomicMax(&mj[j], mv);
}
__global__ void k_lgat_sum(const float* __restrict__ mval, const float* __restrict__ tval,
                           const int* __restrict__ iM, const int* __restrict__ jM,
                           const int* __restrict__ iT, const int* __restrict__ jT,
                           const unsigned* __restrict__ mi, const unsigned* __restrict__ mj,
                           float* __restrict__ si, float* __restrict__ sj,
                           int LGE, int R)
{
    int e = blockIdx.x*blockDim.x + threadIdx.x;
    if (e >= 2*LGE) return;
    bool g1 = e >= LGE; int le = g1 ? e - LGE : e;
    float v = g1 ? tval[le] : mval[le];
    int i = (g1 ? iT[le] : iM[le]) + (g1 ? R : 0);
    int j = (g1 ? jT[le] : jM[le]) + (g1 ? R : 0);
    atomicAdd(&si[i], expf(v - mono2f(mi[i])));
    atomicAdd(&sj[j], expf(v - mono2f(mj[j])));
}
__global__ void k_lgat_vsum2(const float* __restrict__ mval, const float* __restrict__ tval,
                             const int* __restrict__ iM, const int* __restrict__ jM,
                             const int* __restrict__ iT, const int* __restrict__ jT,
                             const unsigned* __restrict__ mi, const float* __restrict__ si,
                             const unsigned* __restrict__ mj, const float* __restrict__ sj,
                             float* __restrict__ vsum, int LGE, int R)
{
    int e = blockIdx.x*blockDim.x + threadIdx.x;
    if (e >= 2*LGE) return;
    bool g1 = e >= LGE; int le = g1 ? e - LGE : e;
    float v = g1 ? tval[le] : mval[le];
    int i = (g1 ? iT[le] : iM[le]) + (g1 ? R : 0);
    int j = (g1 ? jT[le] : jM[le]) + (g1 ? R : 0);
    float pi = expf(v - mono2f(mi[i])) / (si[i] + 1e-16f);
    float pj = expf(v - mono2f(mj[j])) / (sj[j] + 1e-16f);
    vsum[e] = pi + pj;
}
__global__ void k_lgat_max2(const float* __restrict__ vsum,
                            const int* __restrict__ jM, const int* __restrict__ jT,
                            unsigned* __restrict__ m2, int LGE, int R)
{
    int e = blockIdx.x*blockDim.x + threadIdx.x;
    if (e >= 2*LGE) return;
    bool g1 = e >= LGE; int le = g1 ? e - LGE : e;
    int j = (g1 ? jT[le] : jM[le]) + (g1 ? R : 0);
    atomicMax(&m2[j], f2mono(vsum[e]));
}
__global__ void k_lgat_sum2(const float* __restrict__ vsum,
                            const int* __restrict__ jM, const int* __restrict__ jT,
                            const unsigned* __restrict__ m2, float* __restrict__ s2,
                            int LGE, int R)
{
    int e = blockIdx.x*blockDim.x + threadIdx.x;
    if (e >= 2*LGE) return;
    bool g1 = e >= LGE; int le = g1 ? e - LGE : e;
    int j = (g1 ? jT[le] : jM[le]) + (g1 ? R : 0);
    atomicAdd(&s2[j], expf(vsum[e] - mono2f(m2[j])));
}
__global__ void k_lgat_agg(const float* __restrict__ vsum,
                           const unsigned* __restrict__ m2, const float* __restrict__ s2,
                           const int* __restrict__ iM, const int* __restrict__ jM,
                           const int* __restrict__ iT, const int* __restrict__ jT,
                           const float* __restrict__ remb1, const float* __restrict__ remb2,
                           float* __restrict__ obuf, int LGE, int R, int RH)
{
    int w = (blockIdx.x*blockDim.x + threadIdx.x) >> 6;
    int lane = threadIdx.x & 63;
    if (w >= 2*LGE) return;
    bool g1 = w >= LGE; int le = g1 ? w - LGE : w;
    int o = g1 ? R : 0;
    int i = (g1 ? iT[le] : iM[le]) + o;
    int j = (g1 ? jT[le] : jM[le]);
    float alpha = expf(vsum[w] - mono2f(m2[o + j])) / (s2[o + j] + 1e-16f);
    const float* x = g1 ? remb2 : remb1;
    const float4* src = (const float4*)(x + (long)j*RH);
    float* dst = obuf + (long)i*RH;
    if (lane < 25) {
        float4 v = src[lane];
        atomicAdd(&dst[lane*4+0], alpha*v.x);
        atomicAdd(&dst[lane*4+1], alpha*v.y);
        atomicAdd(&dst[lane*4+2], alpha*v.z);
        atomicAdd(&dst[lane*4+3], alpha*v.w);
    }
}
__global__ void k_relu2d(float* __restrict__ p, long rows, int cols, long ld) {
    long idx = (long)blockIdx.x*blockDim.x + threadIdx.x;
    if (idx >= rows*(long)cols) return;
    long r = idx / cols; int c = (int)(idx % cols);
    float v = p[r*ld+c];
    p[r*ld+c] = fmaxf(v, 0.0f);
}

// ---------- highway combine (small R x RH path) ----------
__global__ void k_highway(const float* __restrict__ x1, long ld1,
                          const float* __restrict__ gl, long ldg,
                          const float* __restrict__ x2, long ld2,
                          const float* __restrict__ bias,
                          float* __restrict__ out, long ldo,
                          long rows, int F, int relu_x2)
{
    long idx = (long)blockIdx.x*blockDim.x + threadIdx.x;
    if (idx >= rows * (long)F) return;
    long r = idx / F; int c = (int)(idx % F);
    float g = 1.0f / (1.0f + expf(-(gl[r*ldg+c] + bias[c])));
    float v2 = x2[r*ld2+c]; if (relu_x2) v2 = fmaxf(v2, 0.0f);
    float v1 = x1[r*ld1+c];
    out[r*ldo+c] = g*v2 + (1.0f-g)*v1;
}

// merged: waves 0..R-1: rsc[r] = mrg[r]·ar[0:RH] + tri[r]·ar[RH:2RH]
//         waves R..2R-1: srel[r] = xr[r]·g2e_ar; also emit xrb (bf16, [R][128])
__global__ void k_rs2(const float* __restrict__ mg, const float* __restrict__ tr,
                      const float* __restrict__ ar,
                      const float* __restrict__ xr, const float* __restrict__ g2e_ar,
                      float* __restrict__ rsc, float* __restrict__ srel,
                      unsigned short* __restrict__ xrb, int R, int RH)
{
    int gw = (blockIdx.x*blockDim.x + threadIdx.x) >> 6;
    int lane = threadIdx.x & 63;
    if (gw >= 2*R) return;
    float s = 0.0f;
    if (gw < R) {
        for (int k = lane; k < RH; k += WAVE)
            s += mg[(long)gw*RH+k]*ar[k] + tr[(long)gw*RH+k]*ar[RH+k];
        #pragma unroll
        for (int off = 32; off > 0; off >>= 1) s += __shfl_down(s, off);
        if (lane == 0) rsc[gw] = s;
    } else {
        int r = gw - R;
        #pragma unroll
        for (int t = 0; t < 2; ++t) {
            int k = lane + t*64;
            if (k < RH) {
                float v = xr[(long)r*RH + k];
                s += v * g2e_ar[k];
                xrb[(long)r*128 + k] = f2bf_rne(v);
            }
        }
        #pragma unroll
        for (int off = 32; off > 0; off >>= 1) s += __shfl_down(s, off);
        if (lane == 0) srel[r] = s;
    }
}

extern "C" void kernel_launch(void* const* d_in, const int* in_sizes, int n_in,
                              void* d_out, int out_size, void* d_ws, size_t ws_size,
                              hipStream_t stream)
{
    const float* x_e   = (const float*)d_in[0];
    const float* mval  = (const float*)d_in[1];
    const float* tval  = (const float*)d_in[2];
    const float* g1w   = (const float*)d_in[3];
    const float* h1w   = (const float*)d_in[4];
    const float* h1b   = (const float*)d_in[5];
    const float* g2w   = (const float*)d_in[6];
    const float* h2w   = (const float*)d_in[7];
    const float* h2b   = (const float*)d_in[8];
    const float* remb1 = (const float*)d_in[9];
    const float* remb2 = (const float*)d_in[10];
    const float* hrw   = (const float*)d_in[11];
    const float* hrb   = (const float*)d_in[12];
    const float* gat_ai= (const float*)d_in[13];
    const float* gat_aj= (const float*)d_in[14];
    const float* gat_ar= (const float*)d_in[15];
    const float* g2e_ah= (const float*)d_in[16];
    const float* g2e_at= (const float*)d_in[17];
    const float* g2e_ar= (const float*)d_in[18];
    const int* edge_index     = (const int*)d_in[19];
    const int* rel            = (const int*)d_in[20];
    const int* edge_index_all = (const int*)d_in[21];
    const int* rel_all        = (const int*)d_in[22];
    const int* lg_merge       = (const int*)d_in[23];
    const int* lg_tri         = (const int*)d_in[24];

    const int F    = 300;
    const int RH   = 100;
    const int Kp   = 304;
    const int npk  = Kp / 16;              // 19
    const int N    = in_sizes[0] / F;      // 100000
    const int E    = in_sizes[20];         // 400000
    const int EA   = in_sizes[22];         // 800000
    const int LGE  = in_sizes[1];          // 60000
    const int R    = in_sizes[9] / RH;     // 2000
    const long OUTC = 800;
    const int Mpad = CDIV(N, 128) * 128;
    const int NB   = 640;                  // W rows: g @0..299, h @320..619
    const long LDC = 640;

    const int* jA = edge_index_all;
    const int* iA = edge_index_all + EA;
    const int* hE = edge_index;
    const int* tE = edge_index + E;
    const int* jM = lg_merge;  const int* iM = lg_merge + LGE;
    const int* jT = lg_tri;    const int* iT = lg_tri  + LGE;

    float* ws = (float*)d_ws;
    size_t off = 0;
    auto alloc = [&](size_t n) { float* p = ws + off; off += (n + 15) & ~(size_t)15; return p; };
    unsigned short* Ascr = (unsigned short*)alloc((size_t)N*NB/2);    // GEMM out bf16 [N,640]
    unsigned short* Axb = (unsigned short*)alloc((size_t)Mpad*Kp/2);  // A packed bf16
    unsigned short* xbf = (unsigned short*)alloc((size_t)N*XBS/2);    // row-major bf16 x
    unsigned short* Wb  = (unsigned short*)alloc((size_t)2*NB*Kp/2);  // 2 packed weights
    unsigned short* W0 = Wb;
    unsigned short* W1 = Wb + (size_t)NB*Kp;
    unsigned short* xrb = (unsigned short*)alloc((size_t)R*128/2);    // bf16 xr [R][128]
    float*    sA_  = alloc(N);
    float*    sB_  = alloc(N);
    float*    sH_  = alloc(N);
    float*    sT_  = alloc(N);
    float*    xr   = alloc((size_t)R*RH);
    float*    xrg  = alloc((size_t)R*RH);
    float*    lg   = alloc((size_t)12*R + (size_t)2*R*RH);
    unsigned* lmi  = (unsigned*)lg;          float* lsi = lg + 2*R;
    unsigned* lmj  = (unsigned*)(lg + 4*R);  float* lsj = lg + 6*R;
    unsigned* lm2  = (unsigned*)(lg + 8*R);  float* ls2 = lg + 10*R;
    float*    obuf = lg + 12*R;              // [2R][RH]: mrg then tri
    float*    mrg  = obuf;
    float*    tri  = obuf + (size_t)R*RH;
    float*    vsum = alloc((size_t)2*LGE);
    float*    rsc  = alloc(R);
    float*    srel = alloc(R);
    int*   bsum    = (int*)alloc(1024);
    int*   cntAll  = (int*)alloc((size_t)6*N);
    int*   curAll  = cntAll + 3*N;
    int*   rowptrG = (int*)alloc((size_t)3*N);
    int*   relpAll = (int*)alloc((size_t)EA + 2*E);
    int*   jpA     = (int*)alloc(EA);
    float* nmA     = alloc(EA);

    float* out = (float*)d_out;              // [N, 800]

    const int  nrb = CDIV(N, 128);
    const int  gemmBlocks = 8 * CDIV(nrb, 8) * 5;
    const int  gatherGrid = CDIV(N, 4);
    const int  cvtBigGrid = CDIV((long)N * (Kp/4), 256);
    const int  cvtW4Grid  = CDIV((long)4 * 300 * (Kp/4), 256);
    const int  ETOT = EA + 2*E;
    const int  nb3 = CDIV(3*N, 512);

    // ===== converts (weights merged + x_e), pads zeroed =====
    hipMemsetAsync(Wb, 0, (size_t)2*NB*Kp*2, stream);
    hipMemsetAsync(Axb + (size_t)N*Kp, 0, (size_t)(Mpad-N)*Kp*2, stream);
    k_cvt_w4<<<cvtW4Grid,256,0,stream>>>(g1w, h1w, g2w, h2w, npk, W0, W1);
    k_cvt_pack1<<<cvtBigGrid,256,0,stream>>>(x_e, 300, N, 300, npk, 0, Axb);

    // ===== merged CSR build (A, H, T) with fused edge-data placement =====
    hipMemsetAsync(cntAll, 0, (size_t)6*N*4, stream);
    k_hist3<<<CDIV(ETOT,256),256,0,stream>>>(iA, hE, tE, cntAll, EA, E, N);
    k_scan1<<<nb3,512,0,stream>>>(cntAll, rowptrG, bsum, 3*N);
    k_scan2<<<1,1024,0,stream>>>(bsum, nb3);
    k_scan3<<<nb3,512,0,stream>>>(rowptrG, bsum, 3*N);
    k_fill3f<<<CDIV(ETOT,256),256,0,stream>>>(iA, jA, hE, tE, rel_all, rel,
                                              rowptrG, cntAll, curAll,
                                              jpA, nmA, relpAll, EA, E, N, R);

    // ===== GCN layer 1: GEMM (bf16) + gather/highway -> Axb pack + xbf =====
    k_gemm_frag<<<gemmBlocks,256,0,stream>>>(Axb, W0, Ascr, LDC, N, 620, npk, nrb);
    k_gather_hw<<<gatherGrid,256,0,stream>>>(Ascr, LDC, Ascr+320,
                                             x_e, (const unsigned short*)nullptr, h1b,
                                             jpA, nmA, rowptrG, cntAll,
                                             (float*)nullptr, OUTC, Axb, xbf,
                                             (const float*)nullptr, (const float*)nullptr,
                                             (float*)nullptr, (float*)nullptr, npk, N);

    // ===== GCN layer 2: x1 from xbf (bf16), out write + xbf update + GAT dots =====
    k_gemm_frag<<<gemmBlocks,256,0,stream>>>(Axb, W1, Ascr, LDC, N, 620, npk, nrb);
    k_gather_hw<<<gatherGrid,256,0,stream>>>(Ascr, LDC, Ascr+320,
                                             (const float*)nullptr, xbf, h2b,
                                             jpA, nmA, rowptrG, cntAll,
                                             out, OUTC, (unsigned short*)nullptr, xbf,
                                             gat_ai, gat_aj, sA_, sB_, npk, N);

    // ===== merged l_gat over both line graphs =====
    hipMemsetAsync(lg, 0, ((size_t)12*R + (size_t)2*R*RH)*4, stream);
    const int lgGrid = CDIV(2*LGE, 256);
    k_lgat_max  <<<lgGrid,256,0,stream>>>(mval, tval, iM, jM, iT, jT, lmi, lmj, LGE, R);
    k_lgat_sum  <<<lgGrid,256,0,stream>>>(mval, tval, iM, jM, iT, jT, lmi, lmj, lsi, lsj, LGE, R);
    k_lgat_vsum2<<<lgGrid,256,0,stream>>>(mval, tval, iM, jM, iT, jT, lmi, lsi, lmj, lsj,
                                          vsum, LGE, R);
    k_lgat_max2 <<<lgGrid,256,0,stream>>>(vsum, jM, jT, lm2, LGE, R);
    k_lgat_sum2 <<<lgGrid,256,0,stream>>>(vsum, jM, jT, lm2, ls2, LGE, R);
    k_lgat_agg  <<<CDIV(2*LGE*64,256),256,0,stream>>>(vsum, lm2, ls2, iM, jM, iT, jT,
                                                      remb1, remb2, obuf, LGE, R, RH);
    k_relu2d    <<<CDIV((long)2*R*RH,256),256,0,stream>>>(obuf, 2*R, RH, RH);

    // ===== x_r = highway(mrg, tri, hrw, hrb) =====
    dim3 gridR(CDIV(RH,GBN), CDIV(R,GBM));
    k_gemm<<<gridR,256,0,stream>>>(mrg, RH, hrw, RH, xrg, RH, R, RH, RH);
    k_highway<<<CDIV((long)R*RH,256),256,0,stream>>>(mrg, RH, xrg, RH, tri, RH, hrb, xr, RH, R, RH, 0);

    // merged relscore + srel (+ xrb emit)
    k_rs2<<<CDIV((long)2*R*64,256),256,0,stream>>>(mrg, tri, gat_ar, xr, g2e_ar,
                                                   rsc, srel, xrb, R, RH);

    // ===== GAT -> out cols 300..599 + r2e score dots =====
    k_gat300<<<gatherGrid,256,0,stream>>>(xbf, sA_, sB_, rsc, jpA, relpAll,
                                          rowptrG, cntAll, out+300, OUTC,
                                          g2e_ah, g2e_at, sH_, sT_, N);

    // ===== gat_r_to_e -> out cols 600..799 (h+t merged, bf16 xrb) =====
    k_gather_rel2<<<CDIV(2*N,4),256,0,stream>>>(xrb, sH_, sT_, srel, relpAll,
                                                rowptrG + N, cntAll + N,
                                                rowptrG + 2*N, cntAll + 2*N,
                                                out, OUTC, N);
}

// Round 15
// 1063.336 us; speedup vs baseline: 1.5815x; 1.1345x over previous
//
#include <hip/hip_runtime.h>

#define WAVE 64
#define CDIV(a,b) (((a)+(b)-1)/(b))
#define XBS 320   // xbf row stride in shorts (640B rows)

typedef float f32x16 __attribute__((ext_vector_type(16)));
typedef unsigned short u16x8 __attribute__((ext_vector_type(8)));

// ---------- bf16 helpers ----------
__device__ __forceinline__ unsigned short f2bf_rne(float f) {
    unsigned u = __float_as_uint(f);
    unsigned r = (u + 0x7FFFu + ((u >> 16) & 1u)) >> 16;
    return (unsigned short)r;
}
__device__ __forceinline__ float bf2f(unsigned short h) {
    return __uint_as_float(((unsigned)h) << 16);
}
__device__ __forceinline__ float2 bfp2f(ushort2 u) {
    float2 r; r.x = bf2f(u.x); r.y = bf2f(u.y); return r;
}
__device__ __forceinline__ float sigm(float x) { return 1.0f / (1.0f + expf(-x)); }

#define MFMA32(acc, a, b) \
    asm volatile("v_mfma_f32_32x32x16_bf16 %0, %1, %2, %0" : "+v"(acc) : "v"(a), "v"(b))

// ---------- monotonic float<->uint encoding for atomicMax on floats ----------
__device__ __forceinline__ unsigned f2mono(float f) {
    unsigned u = __float_as_uint(f);
    return (u & 0x80000000u) ? ~u : (u | 0x80000000u);
}
__device__ __forceinline__ float mono2f(unsigned u) {
    return (u & 0x80000000u) ? __uint_as_float(u & 0x7fffffffu) : __uint_as_float(~u);
}
__device__ __forceinline__ float leaky(float v) { return (v > 0.0f) ? v : 0.01f*v; }

// fragment-pack offset: matrix row r, col k -> packed short index.
__device__ __forceinline__ long fragoff(long r, int k, int npk) {
    return ((r >> 5) * (long)npk + (k >> 4)) * 512
         + (((k >> 3) & 1) << 8) + ((r & 31) << 3) + (k & 7);
}

// ---------- k_cvt_pack1: f32 -> fragment-packed single bf16 (rne) ----------
__global__ void k_cvt_pack1(const float* __restrict__ src, long ld, int rows, int K, int npk,
                            int roff, unsigned short* __restrict__ dst)
{
    int nc4 = npk << 2;
    long idx = (long)blockIdx.x*blockDim.x + threadIdx.x;
    if (idx >= (long)rows * nc4) return;
    long r = idx / nc4; int k = (int)(idx % nc4) << 2;
    float4 v = {0.0f, 0.0f, 0.0f, 0.0f};
    if (k + 4 <= K) v = *(const float4*)(src + r*ld + k);
    ushort4 h;
    h.x = f2bf_rne(v.x); h.y = f2bf_rne(v.y); h.z = f2bf_rne(v.z); h.w = f2bf_rne(v.w);
    *(ushort4*)(dst + fragoff(r + roff, k, npk)) = h;
}

// merged weight convert: 4 matrices [300][300] -> W0(g@0,h@320), W1(g@0,h@320)
__global__ void k_cvt_w4(const float* __restrict__ g1w, const float* __restrict__ h1w,
                         const float* __restrict__ g2w, const float* __restrict__ h2w,
                         int npk, unsigned short* __restrict__ W0,
                         unsigned short* __restrict__ W1)
{
    const int nc4 = npk << 2;                 // 76
    const long per = (long)300 * nc4;
    long idx = (long)blockIdx.x*blockDim.x + threadIdx.x;
    if (idx >= 4*per) return;
    int which = (int)(idx / per);
    long lidx = idx % per;
    long r = lidx / nc4; int k = (int)(lidx % nc4) << 2;
    const float* src = (which == 0) ? g1w : (which == 1) ? h1w : (which == 2) ? g2w : h2w;
    unsigned short* dst = (which < 2) ? W0 : W1;
    int roff = (which & 1) ? 320 : 0;
    float4 v = {0.0f, 0.0f, 0.0f, 0.0f};
    if (k + 4 <= 300) v = *(const float4*)(src + r*300 + k);
    ushort4 h;
    h.x = f2bf_rne(v.x); h.y = f2bf_rne(v.y); h.z = f2bf_rne(v.z); h.w = f2bf_rne(v.w);
    *(ushort4*)(dst + fragoff(r + roff, k, npk)) = h;
}

// =========================================================================
// k_gemm_frag: C[M,620] (bf16) = A * B^T; A and B single bf16 (rne).
// NO LDS, NO barriers. XCD-ownership swizzle. 4 MFMA / 5 loads per k-step.
// =========================================================================
__global__ __launch_bounds__(256, 3)
void k_gemm_frag(const unsigned short* __restrict__ Ab,
                 const unsigned short* __restrict__ Bb,
                 unsigned short* __restrict__ C, long ldc, int M, int N, int nk, int nrb)
{
    const int lane = threadIdx.x & 63;
    const int wid  = threadIdx.x >> 6;
    const int lin  = blockIdx.x;
    const int xcd  = lin & 7;
    const int m    = lin >> 3;
    const int col0 = (m % 5) * 128;
    const int rb   = xcd + ((m / 5) << 3);
    if (rb >= nrb) return;
    const int row0 = rb * 128 + wid * 32;

    const long cs = (long)nk * 512;
    const unsigned short* pA = Ab + (long)(row0 >> 5) * cs + lane * 8;
    const unsigned short* pB = Bb + (long)(col0 >> 5) * cs + lane * 8;

    f32x16 acc[4];
    #pragma unroll
    for (int c = 0; c < 4; ++c) acc[c] = (f32x16)0.0f;

    u16x8 pa, pb0, pb1, pb2, pb3;
    u16x8 qa, qb0, qb1, qb2, qb3;

    #define LOADP(t_) { long o = (long)(t_)*512;                                   \
        pa  = *(const u16x8*)(pA + o);                                             \
        pb0 = *(const u16x8*)(pB + o);        pb1 = *(const u16x8*)(pB + cs + o);  \
        pb2 = *(const u16x8*)(pB + 2*cs + o); pb3 = *(const u16x8*)(pB + 3*cs + o); }
    #define LOADQ(t_) { long o = (long)(t_)*512;                                   \
        qa  = *(const u16x8*)(pA + o);                                             \
        qb0 = *(const u16x8*)(pB + o);        qb1 = *(const u16x8*)(pB + cs + o);  \
        qb2 = *(const u16x8*)(pB + 2*cs + o); qb3 = *(const u16x8*)(pB + 3*cs + o); }
    #define STEPP {                                                                 \
        MFMA32(acc[0], pa, pb0); MFMA32(acc[1], pa, pb1);                           \
        MFMA32(acc[2], pa, pb2); MFMA32(acc[3], pa, pb3); }
    #define STEPQ {                                                                 \
        MFMA32(acc[0], qa, qb0); MFMA32(acc[1], qa, qb1);                           \
        MFMA32(acc[2], qa, qb2); MFMA32(acc[3], qa, qb3); }

    LOADP(0);
    int t = 0;
    for (;;) {
        bool m1 = (t + 1 < nk);
        if (m1) LOADQ(t + 1);
        STEPP;
        if (!m1) break;
        bool m2 = (t + 2 < nk);
        if (m2) LOADP(t + 2);
        STEPQ;
        if (!m2) break;
        t += 2;
    }
    #undef LOADP
    #undef LOADQ
    #undef STEPP
    #undef STEPQ

    const int crow0 = row0 + 4*(lane >> 5);
    const int ccol0 = col0 + (lane & 31);
    #pragma unroll
    for (int c = 0; c < 4; ++c) {
        int col = ccol0 + c*32;
        if (col >= N) continue;
        #pragma unroll
        for (int reg = 0; reg < 16; ++reg) {
            int row = crow0 + (reg & 3) + 8*(reg >> 2);
            if (row < M) C[(long)row*ldc + col] = f2bf_rne(acc[c][reg]);
        }
    }
}

// ---------- small f32 GEMM (tiny R x RH highway gate) ----------
#define GBM 64
#define GBN 64
#define GBK 16
__global__ __launch_bounds__(256)
void k_gemm(const float* __restrict__ A, long lda,
            const float* __restrict__ B, long ldb,
            float* __restrict__ C, long ldc,
            int M, int N, int K)
{
    __shared__ float As[GBK][GBM + 4];
    __shared__ float Bs[GBK][GBN + 4];
    const int tid = threadIdx.x;
    const int tx = tid & 15, ty = tid >> 4;
    const int row0 = blockIdx.y * GBM, col0 = blockIdx.x * GBN;
    float acc[4][4] = {};
    for (int kt = 0; kt < K; kt += GBK) {
        #pragma unroll
        for (int p = 0; p < 4; ++p) {
            int mn = (tid >> 4) + p * 16;
            int k  = tid & 15;
            int gk = kt + k;
            int gr = row0 + mn;
            As[k][mn] = (gr < M && gk < K) ? A[(long)gr * lda + gk] : 0.0f;
            int gc = col0 + mn;
            Bs[k][mn] = (gc < N && gk < K) ? B[(long)gc * ldb + gk] : 0.0f;
        }
        __syncthreads();
        #pragma unroll
        for (int kk = 0; kk < GBK; ++kk) {
            float a0 = As[kk][ty*4+0], a1 = As[kk][ty*4+1];
            float a2 = As[kk][ty*4+2], a3 = As[kk][ty*4+3];
            float b0 = Bs[kk][tx*4+0], b1 = Bs[kk][tx*4+1];
            float b2 = Bs[kk][tx*4+2], b3 = Bs[kk][tx*4+3];
            acc[0][0] += a0*b0; acc[0][1] += a0*b1; acc[0][2] += a0*b2; acc[0][3] += a0*b3;
            acc[1][0] += a1*b0; acc[1][1] += a1*b1; acc[1][2] += a1*b2; acc[1][3] += a1*b3;
            acc[2][0] += a2*b0; acc[2][1] += a2*b1; acc[2][2] += a2*b2; acc[2][3] += a2*b3;
            acc[3][0] += a3*b0; acc[3][1] += a3*b1; acc[3][2] += a3*b2; acc[3][3] += a3*b3;
        }
        __syncthreads();
    }
    #pragma unroll
    for (int i2 = 0; i2 < 4; ++i2)
        #pragma unroll
        for (int j2 = 0; j2 < 4; ++j2) {
            int r = row0 + ty*4 + i2, c = col0 + tx*4 + j2;
            if (r < M && c < N) C[(long)r*ldc + c] = acc[i2][j2];
        }
}

// ================= merged CSR build over 5 graphs =================
// rows: [0,N) A-dest, [N,2N) H, [2N,3N) T, [3N,3N+R) LG-merge-i, [3N+R,3N+2R) LG-tri-i
__global__ void k_hist5(const int* __restrict__ iA, const int* __restrict__ hE,
                        const int* __restrict__ tE, const int* __restrict__ iM,
                        const int* __restrict__ iT, int* __restrict__ cnt,
                        int EA, int E, int LGE, int N, int R) {
    int e = blockIdx.x*blockDim.x + threadIdx.x;
    int tot = EA + 2*E + 2*LGE;
    if (e >= tot) return;
    if (e < EA)                  atomicAdd(&cnt[iA[e]], 1);
    else if (e < EA + E)         atomicAdd(&cnt[N + hE[e - EA]], 1);
    else if (e < EA + 2*E)       atomicAdd(&cnt[2*N + tE[e - EA - E]], 1);
    else if (e < EA + 2*E + LGE) atomicAdd(&cnt[3*N + iM[e - EA - 2*E]], 1);
    else                         atomicAdd(&cnt[3*N + R + iT[e - EA - 2*E - LGE]], 1);
}
__global__ void k_scan1(const int* __restrict__ in, int* __restrict__ out,
                        int* __restrict__ bsum, int n) {
    __shared__ int sh[512];
    int gid = blockIdx.x*512 + threadIdx.x;
    int v = (gid < n) ? in[gid] : 0;
    sh[threadIdx.x] = v; __syncthreads();
    for (int o = 1; o < 512; o <<= 1) {
        int t = (threadIdx.x >= o) ? sh[threadIdx.x - o] : 0;
        __syncthreads();
        sh[threadIdx.x] += t;
        __syncthreads();
    }
    if (gid < n) out[gid] = sh[threadIdx.x] - v;      // exclusive
    if (threadIdx.x == 511) bsum[blockIdx.x] = sh[511];
}
__global__ void k_scan2(int* __restrict__ bsum, int nb) {   // single block, nb <= 1024
    __shared__ int sh[1024];
    int v = (threadIdx.x < nb) ? bsum[threadIdx.x] : 0;
    sh[threadIdx.x] = v; __syncthreads();
    for (int o = 1; o < 1024; o <<= 1) {
        int t = (threadIdx.x >= o) ? sh[threadIdx.x - o] : 0;
        __syncthreads();
        sh[threadIdx.x] += t;
        __syncthreads();
    }
    if (threadIdx.x < nb) bsum[threadIdx.x] = sh[threadIdx.x] - v;  // exclusive
}
__global__ void k_scan3(int* __restrict__ out, const int* __restrict__ bsum, int n) {
    int gid = blockIdx.x*512 + threadIdx.x;
    if (gid < n) out[gid] += bsum[blockIdx.x];
}
// fused fill: place edge at CSR slot AND write jp/nm (A) + relp (A/H/T)
// + lgjp/slotOf (LG regions; slots relative to lgbase).
__global__ void k_fill5f(const int* __restrict__ iA, const int* __restrict__ jA,
                         const int* __restrict__ hE, const int* __restrict__ tE,
                         const int* __restrict__ iM, const int* __restrict__ jM,
                         const int* __restrict__ iT, const int* __restrict__ jT,
                         const int* __restrict__ rel_all, const int* __restrict__ rel,
                         const int* __restrict__ rowptr, const int* __restrict__ cnt,
                         int* __restrict__ cursor,
                         int* __restrict__ jp, float* __restrict__ nm,
                         int* __restrict__ relp,
                         int* __restrict__ lgjp, int* __restrict__ slotOf,
                         int EA, int E, int LGE, int N, int R, int lgbase) {
    int e = blockIdx.x*blockDim.x + threadIdx.x;
    int tot = EA + 2*E + 2*LGE;
    if (e >= tot) return;
    if (e < EA) {
        int le = e;
        int i = iA[le];
        int p = rowptr[i] + atomicAdd(&cursor[i], 1);
        int j = jA[le];
        jp[p] = j;
        float di = rsqrtf((float)cnt[i]);
        int cj = cnt[j];
        float dj = (cj > 0) ? rsqrtf((float)cj) : 0.0f;
        nm[p] = di * dj;
        relp[p] = rel_all[le] % R;
    } else if (e < EA + E) {
        int le = e - EA;
        int key = N + hE[le];
        int p = rowptr[key] + atomicAdd(&cursor[key], 1);
        relp[p] = rel[le];
    } else if (e < EA + 2*E) {
        int le = e - EA - E;
        int key = 2*N + tE[le];
        int p = rowptr[key] + atomicAdd(&cursor[key], 1);
        relp[p] = rel[le];
    } else if (e < EA + 2*E + LGE) {
        int le = e - EA - 2*E;
        int key = 3*N + iM[le];
        int p = rowptr[key] + atomicAdd(&cursor[key], 1) - lgbase;
        lgjp[p] = jM[le];
        slotOf[le] = p;
    } else {
        int le = e - EA - 2*E - LGE;
        int key = 3*N + R + iT[le];
        int p = rowptr[key] + atomicAdd(&cursor[key], 1) - lgbase;
        lgjp[p] = jT[le] + R;
        slotOf[LGE + le] = p;
    }
}

// =========================================================================
// k_gather_hw: fused GCN gather (bf16 src, 8/4/1 edge unroll) + relu +
// highway + extras. x1 from f32 (x1f) or xbf bf16 stride XBS (x1b).
// =========================================================================
__global__ void k_gather_hw(const unsigned short* __restrict__ xg, long ldx,
                            const unsigned short* __restrict__ gl,
                            const float* __restrict__ x1f,
                            const unsigned short* __restrict__ x1b,
                            const float* __restrict__ bias,
                            const int* __restrict__ jp, const float* __restrict__ nm,
                            const int* __restrict__ rowptr, const int* __restrict__ cnt,
                            float* __restrict__ outp, long ldo,
                            unsigned short* __restrict__ pk,
                            unsigned short* __restrict__ xbf,
                            const float* __restrict__ ai, const float* __restrict__ aj,
                            float* __restrict__ sa, float* __restrict__ sb,
                            int npk, int n)
{
    int w = (blockIdx.x*blockDim.x + threadIdx.x) >> 6;
    int lane = threadIdx.x & 63;
    if (w >= n) return;
    int beg = rowptr[w], end = beg + cnt[w];
    const int i0 = lane, i1 = lane + 64, i2 = lane + 128;
    const bool t3 = (lane < 22);
    float2 a0 = {0,0}, a1 = {0,0}, a2 = {0,0};
    int e = beg;
    for (; e + 8 <= end; e += 8) {
        long jj[8]; float wt[8];
        #pragma unroll
        for (int u = 0; u < 8; ++u) { jj[u] = jp[e+u]; wt[u] = nm[e+u]; }
        #pragma unroll
        for (int u = 0; u < 8; ++u) {
            float2 v = bfp2f(((const ushort2*)(xg + jj[u]*ldx))[i0]);
            a0.x += wt[u]*v.x; a0.y += wt[u]*v.y;
        }
        #pragma unroll
        for (int u = 0; u < 8; ++u) {
            float2 v = bfp2f(((const ushort2*)(xg + jj[u]*ldx))[i1]);
            a1.x += wt[u]*v.x; a1.y += wt[u]*v.y;
        }
        if (t3) {
            #pragma unroll
            for (int u = 0; u < 8; ++u) {
                float2 v = bfp2f(((const ushort2*)(xg + jj[u]*ldx))[i2]);
                a2.x += wt[u]*v.x; a2.y += wt[u]*v.y;
            }
        }
    }
    for (; e + 4 <= end; e += 4) {
        long jj[4]; float wt[4];
        #pragma unroll
        for (int u = 0; u < 4; ++u) { jj[u] = jp[e+u]; wt[u] = nm[e+u]; }
        #pragma unroll
        for (int u = 0; u < 4; ++u) {
            float2 v = bfp2f(((const ushort2*)(xg + jj[u]*ldx))[i0]);
            a0.x += wt[u]*v.x; a0.y += wt[u]*v.y;
        }
        #pragma unroll
        for (int u = 0; u < 4; ++u) {
            float2 v = bfp2f(((const ushort2*)(xg + jj[u]*ldx))[i1]);
            a1.x += wt[u]*v.x; a1.y += wt[u]*v.y;
        }
        if (t3) {
            #pragma unroll
            for (int u = 0; u < 4; ++u) {
                float2 v = bfp2f(((const ushort2*)(xg + jj[u]*ldx))[i2]);
                a2.x += wt[u]*v.x; a2.y += wt[u]*v.y;
            }
        }
    }
    for (; e < end; ++e) {
        long j0 = jp[e]; float w0 = nm[e];
        float2 v;
        v = bfp2f(((const ushort2*)(xg + j0*ldx))[i0]); a0.x += w0*v.x; a0.y += w0*v.y;
        v = bfp2f(((const ushort2*)(xg + j0*ldx))[i1]); a1.x += w0*v.x; a1.y += w0*v.y;
        if (t3) { v = bfp2f(((const ushort2*)(xg + j0*ldx))[i2]); a2.x += w0*v.x; a2.y += w0*v.y; }
    }
    // highway: o = sig(gl+b)*relu(acc) + (1-sig)*x1
    const ushort2* glr = (const ushort2*)(gl + (long)w*ldx);
    const float2*  x1r = (const float2*)(x1f + (long)w*300);
    const ushort2* x1r2 = (const ushort2*)(x1b + (long)w*XBS);
    const float2*  br  = (const float2*)bias;
    float2 o0 = {0,0}, o1 = {0,0}, o2 = {0,0};
    {
        float2 gv = bfp2f(glr[i0]); float2 bv = br[i0];
        float2 xv = x1f ? x1r[i0] : bfp2f(x1r2[i0]);
        float g0 = sigm(gv.x + bv.x), g1 = sigm(gv.y + bv.y);
        o0.x = g0*fmaxf(a0.x,0.0f) + (1.0f-g0)*xv.x;
        o0.y = g1*fmaxf(a0.y,0.0f) + (1.0f-g1)*xv.y;
    }
    {
        float2 gv = bfp2f(glr[i1]); float2 bv = br[i1];
        float2 xv = x1f ? x1r[i1] : bfp2f(x1r2[i1]);
        float g0 = sigm(gv.x + bv.x), g1 = sigm(gv.y + bv.y);
        o1.x = g0*fmaxf(a1.x,0.0f) + (1.0f-g0)*xv.x;
        o1.y = g1*fmaxf(a1.y,0.0f) + (1.0f-g1)*xv.y;
    }
    if (t3) {
        float2 gv = bfp2f(glr[i2]); float2 bv = br[i2];
        float2 xv = x1f ? x1r[i2] : bfp2f(x1r2[i2]);
        float g0 = sigm(gv.x + bv.x), g1 = sigm(gv.y + bv.y);
        o2.x = g0*fmaxf(a2.x,0.0f) + (1.0f-g0)*xv.x;
        o2.y = g1*fmaxf(a2.y,0.0f) + (1.0f-g1)*xv.y;
    }
    if (outp) {
        float2* dst = (float2*)(outp + (long)w*ldo);
        dst[i0] = o0; dst[i1] = o1;
        if (t3) dst[i2] = o2;
    }
    if (pk) {
        auto pack2 = [&](int k, float2 o) {
            ushort2 hv; hv.x = f2bf_rne(o.x); hv.y = f2bf_rne(o.y);
            *(ushort2*)(pk + fragoff(w, k, npk)) = hv;
        };
        pack2(2*lane, o0);
        pack2(128 + 2*lane, o1);
        if (t3) pack2(256 + 2*lane, o2);
        else if (lane < 24) {
            ushort2 z = {0,0};
            *(ushort2*)(pk + fragoff(w, 256 + 2*lane, npk)) = z;
        }
    }
    if (xbf) {
        ushort2* xw = (ushort2*)(xbf + (long)w*XBS);
        ushort2 t;
        t.x = f2bf_rne(o0.x); t.y = f2bf_rne(o0.y); xw[i0] = t;
        t.x = f2bf_rne(o1.x); t.y = f2bf_rne(o1.y); xw[i1] = t;
        if (t3) { t.x = f2bf_rne(o2.x); t.y = f2bf_rne(o2.y); xw[i2] = t; }
    }
    if (sa) {
        const float2* ai2 = (const float2*)ai;
        const float2* aj2 = (const float2*)aj;
        float2 A0 = ai2[i0], A1 = ai2[i1], J0 = aj2[i0], J1 = aj2[i1];
        float sva = o0.x*A0.x + o0.y*A0.y + o1.x*A1.x + o1.y*A1.y;
        float svb = o0.x*J0.x + o0.y*J0.y + o1.x*J1.x + o1.y*J1.y;
        if (t3) {
            float2 A2 = ai2[i2], J2 = aj2[i2];
            sva += o2.x*A2.x + o2.y*A2.y;
            svb += o2.x*J2.x + o2.y*J2.y;
        }
        #pragma unroll
        for (int o = 32; o > 0; o >>= 1) {
            sva += __shfl_down(sva, o);
            svb += __shfl_down(svb, o);
        }
        if (lane == 0) { sa[w] = sva; sb[w] = svb; }
    }
}

// =========================================================================
// k_gat300: fused edge score + segment softmax + weighted gather (bf16,
// 8/4/1 unroll) + relu -> out cols 300..599, PLUS r2e score dots.
// =========================================================================
__global__ void k_gat300(const unsigned short* __restrict__ xbf,
                         const float* __restrict__ sA, const float* __restrict__ sB,
                         const float* __restrict__ rsc,
                         const int* __restrict__ jp, const int* __restrict__ relp,
                         const int* __restrict__ rowptr, const int* __restrict__ cnt,
                         float* __restrict__ out, long ldo,
                         const float* __restrict__ ah, const float* __restrict__ at,
                         float* __restrict__ sh, float* __restrict__ st,
                         int n)
{
    int w = (blockIdx.x*blockDim.x + threadIdx.x) >> 6;
    int lane = threadIdx.x & 63;
    if (w >= n) return;
    int beg = rowptr[w], c = cnt[w];
    const int i0 = lane, i1 = lane + 64, i2 = lane + 128;
    const bool t3 = (lane < 22);
    float2 a0 = {0,0}, a1 = {0,0}, a2 = {0,0};
    if (c > 0) {
        float base = sA[w];
        int   jc = 0;
        float sval = -3.4e38f;
        if (lane < c) {
            jc = jp[beg + lane];
            sval = leaky(base + sB[jc] + rsc[relp[beg + lane]]);
        }
        float mx = sval;
        for (int t = 64 + lane; t < c; t += 64)
            mx = fmaxf(mx, leaky(base + sB[jp[beg+t]] + rsc[relp[beg+t]]));
        #pragma unroll
        for (int o = 32; o > 0; o >>= 1) mx = fmaxf(mx, __shfl_xor(mx, o));
        float pexp = (lane < c) ? expf(sval - mx) : 0.0f;
        float ss = pexp;
        for (int t = 64 + lane; t < c; t += 64)
            ss += expf(leaky(base + sB[jp[beg+t]] + rsc[relp[beg+t]]) - mx);
        #pragma unroll
        for (int o = 32; o > 0; o >>= 1) ss += __shfl_xor(ss, o);
        float inv = 1.0f / (ss + 1e-16f);
        int q = 0;
        int cc = (c < 64) ? c : 64;
        for (; q + 8 <= cc; q += 8) {
            float al[8]; long jj[8];
            #pragma unroll
            for (int u = 0; u < 8; ++u) {
                al[u] = __shfl(pexp, q+u) * inv;
                jj[u] = __shfl(jc, q+u);
            }
            #pragma unroll
            for (int u = 0; u < 8; ++u) {
                float2 v = bfp2f(((const ushort2*)(xbf + jj[u]*XBS))[i0]);
                a0.x += al[u]*v.x; a0.y += al[u]*v.y;
            }
            #pragma unroll
            for (int u = 0; u < 8; ++u) {
                float2 v = bfp2f(((const ushort2*)(xbf + jj[u]*XBS))[i1]);
                a1.x += al[u]*v.x; a1.y += al[u]*v.y;
            }
            if (t3) {
                #pragma unroll
                for (int u = 0; u < 8; ++u) {
                    float2 v = bfp2f(((const ushort2*)(xbf + jj[u]*XBS))[i2]);
                    a2.x += al[u]*v.x; a2.y += al[u]*v.y;
                }
            }
        }
        for (; q + 4 <= cc; q += 4) {
            float al[4]; long jj[4];
            #pragma unroll
            for (int u = 0; u < 4; ++u) {
                al[u] = __shfl(pexp, q+u) * inv;
                jj[u] = __shfl(jc, q+u);
            }
            #pragma unroll
            for (int u = 0; u < 4; ++u) {
                float2 v = bfp2f(((const ushort2*)(xbf + jj[u]*XBS))[i0]);
                a0.x += al[u]*v.x; a0.y += al[u]*v.y;
            }
            #pragma unroll
            for (int u = 0; u < 4; ++u) {
                float2 v = bfp2f(((const ushort2*)(xbf + jj[u]*XBS))[i1]);
                a1.x += al[u]*v.x; a1.y += al[u]*v.y;
            }
            if (t3) {
                #pragma unroll
                for (int u = 0; u < 4; ++u) {
                    float2 v = bfp2f(((const ushort2*)(xbf + jj[u]*XBS))[i2]);
                    a2.x += al[u]*v.x; a2.y += al[u]*v.y;
                }
            }
        }
        for (; q < c; ++q) {
            float al; long j0;
            if (q < 64) { al = __shfl(pexp, q) * inv; j0 = __shfl(jc, q); }
            else {
                j0 = jp[beg + q];
                al = expf(leaky(base + sB[(int)j0] + rsc[relp[beg+q]]) - mx) * inv;
            }
            float2 v;
            v = bfp2f(((const ushort2*)(xbf + j0*XBS))[i0]); a0.x += al*v.x; a0.y += al*v.y;
            v = bfp2f(((const ushort2*)(xbf + j0*XBS))[i1]); a1.x += al*v.x; a1.y += al*v.y;
            if (t3) { v = bfp2f(((const ushort2*)(xbf + j0*XBS))[i2]); a2.x += al*v.x; a2.y += al*v.y; }
        }
    }
    a0.x = fmaxf(a0.x, 0.0f); a0.y = fmaxf(a0.y, 0.0f);
    a1.x = fmaxf(a1.x, 0.0f); a1.y = fmaxf(a1.y, 0.0f);
    a2.x = fmaxf(a2.x, 0.0f); a2.y = fmaxf(a2.y, 0.0f);
    float2* dst = (float2*)(out + (long)w*ldo);
    dst[i0] = a0; dst[i1] = a1;
    if (t3) dst[i2] = a2;
    {
        const ushort2* xw = (const ushort2*)(xbf + (long)w*XBS);
        const float2* ahL = (const float2*)ah;
        const float2* atL = (const float2*)at;
        const float2* ahH = (const float2*)(ah + 300);
        const float2* atH = (const float2*)(at + 300);
        float2 x0 = bfp2f(xw[i0]), x1v = bfp2f(xw[i1]);
        float svh = x0.x*ahL[i0].x + x0.y*ahL[i0].y + x1v.x*ahL[i1].x + x1v.y*ahL[i1].y
                  + a0.x*ahH[i0].x + a0.y*ahH[i0].y + a1.x*ahH[i1].x + a1.y*ahH[i1].y;
        float svt = x0.x*atL[i0].x + x0.y*atL[i0].y + x1v.x*atL[i1].x + x1v.y*atL[i1].y
                  + a0.x*atH[i0].x + a0.y*atH[i0].y + a1.x*atH[i1].x + a1.y*atH[i1].y;
        if (t3) {
            float2 x2v = bfp2f(xw[i2]);
            svh += x2v.x*ahL[i2].x + x2v.y*ahL[i2].y + a2.x*ahH[i2].x + a2.y*ahH[i2].y;
            svt += x2v.x*atL[i2].x + x2v.y*atL[i2].y + a2.x*atH[i2].x + a2.y*atH[i2].y;
        }
        #pragma unroll
        for (int o = 32; o > 0; o >>= 1) {
            svh += __shfl_down(svh, o);
            svt += __shfl_down(svt, o);
        }
        if (lane == 0) { sh[w] = svh; st[w] = svt; }
    }
}

// r2e (h+t merged): fused score + softmax + gather of xrb (bf16 [R][128])
__global__ void k_gather_rel2(const unsigned short* __restrict__ xrb,
                              const float* __restrict__ sH, const float* __restrict__ sT,
                              const float* __restrict__ srel,
                              const int* __restrict__ relp,
                              const int* __restrict__ rowptrH, const int* __restrict__ cntH,
                              const int* __restrict__ rowptrT, const int* __restrict__ cntT,
                              float* __restrict__ out, long ldo, int n)
{
    int gw = (blockIdx.x*blockDim.x + threadIdx.x) >> 6;
    int lane = threadIdx.x & 63;
    if (gw >= 2*n) return;
    const bool isT = (gw >= n);
    const int w = isT ? gw - n : gw;
    const float* snode = isT ? sT : sH;
    const int* rowptr = isT ? rowptrT : rowptrH;
    const int* cnt    = isT ? cntT    : cntH;
    float* dst = out + (isT ? 700 : 600) + (long)w*ldo;
    int beg = rowptr[w], c = cnt[w];
    const bool t0 = (lane < 50);
    float2 a0 = {0,0};
    if (c > 0) {
        float base = snode[w];
        int   rc = 0;
        float sval = -3.4e38f;
        if (lane < c) {
            rc = relp[beg + lane];
            sval = leaky(base + srel[rc]);
        }
        float mx = sval;
        for (int t = 64 + lane; t < c; t += 64)
            mx = fmaxf(mx, leaky(base + srel[relp[beg+t]]));
        #pragma unroll
        for (int o = 32; o > 0; o >>= 1) mx = fmaxf(mx, __shfl_xor(mx, o));
        float pexp = (lane < c) ? expf(sval - mx) : 0.0f;
        float ss = pexp;
        for (int t = 64 + lane; t < c; t += 64)
            ss += expf(leaky(base + srel[relp[beg+t]]) - mx);
        #pragma unroll
        for (int o = 32; o > 0; o >>= 1) ss += __shfl_xor(ss, o);
        float inv = 1.0f / (ss + 1e-16f);
        int q = 0;
        int cc = (c < 64) ? c : 64;
        for (; q + 4 <= cc; q += 4) {
            float al0 = __shfl(pexp, q)   * inv;
            float al1 = __shfl(pexp, q+1) * inv;
            float al2 = __shfl(pexp, q+2) * inv;
            float al3 = __shfl(pexp, q+3) * inv;
            long r0i = __shfl(rc, q), r1i = __shfl(rc, q+1);
            long r2i = __shfl(rc, q+2), r3i = __shfl(rc, q+3);
            if (t0) {
                float2 v;
                v = bfp2f(((const ushort2*)(xrb + r0i*128))[lane]); a0.x += al0*v.x; a0.y += al0*v.y;
                v = bfp2f(((const ushort2*)(xrb + r1i*128))[lane]); a0.x += al1*v.x; a0.y += al1*v.y;
                v = bfp2f(((const ushort2*)(xrb + r2i*128))[lane]); a0.x += al2*v.x; a0.y += al2*v.y;
                v = bfp2f(((const ushort2*)(xrb + r3i*128))[lane]); a0.x += al3*v.x; a0.y += al3*v.y;
            }
        }
        for (; q < c; ++q) {
            float al; long r0i;
            if (q < 64) { al = __shfl(pexp, q) * inv; r0i = __shfl(rc, q); }
            else {
                r0i = relp[beg + q];
                al = expf(leaky(base + srel[(int)r0i]) - mx) * inv;
            }
            if (t0) {
                float2 v = bfp2f(((const ushort2*)(xrb + r0i*128))[lane]);
                a0.x += al*v.x; a0.y += al*v.y;
            }
        }
    }
    if (t0) ((float2*)dst)[lane] = a0;
}

// ================= merged l_gat over both line graphs =================
__global__ void k_lgat_max(const float* __restrict__ mval, const float* __restrict__ tval,
                           const int* __restrict__ iM, const int* __restrict__ jM,
                           const int* __restrict__ iT, const int* __restrict__ jT,
                           unsigned* __restrict__ mi, unsigned* __restrict__ mj,
                           int LGE, int R)
{
    int e = blockIdx.x*blockDim.x + threadIdx.x;
    if (e >= 2*LGE) return;
    bool g1 = e >= LGE; int le = g1 ? e - LGE : e;
    float v = g1 ? tval[le] : mval[le];
    int i = (g1 ? iT[le] : iM[le]) + (g1 ? R : 0);
    int j = (g1 ? jT[le] : jM[le]) + (g1 ? R : 0);
    unsigned mv = f2mono(v);
    atomicMax(&mi[i], mv);
    atomicMax(&mj[j], mv);
}
__global__ void k_lgat_sum(const float* __restrict__ mval, const float* __restrict__ tval,
                           const int* __restrict__ iM, const int* __restrict__ jM,
                           const int* __restrict__ iT, const int* __restrict__ jT,
                           const unsigned* __restrict__ mi, const unsigned* __restrict__ mj,
                           float* __restrict__ si, float* __restrict__ sj,
                           int LGE, int R)
{
    int e = blockIdx.x*blockDim.x + threadIdx.x;
    if (e >= 2*LGE) return;
    bool g1 = e >= LGE; int le = g1 ? e - LGE : e;
    float v = g1 ? tval[le] : mval[le];
    int i = (g1 ? iT[le] : iM[le]) + (g1 ? R : 0);
    int j = (g1 ? jT[le] : jM[le]) + (g1 ? R : 0);
    atomicAdd(&si[i], expf(v - mono2f(mi[i])));
    atomicAdd(&sj[j], expf(v - mono2f(mj[j])));
}
// vsum written in CSR-slot order via slotOf
__global__ void k_lgat_vsum2(const float* __restrict__ mval, const float* __restrict__ tval,
                             const int* __restrict__ iM, const int* __restrict__ jM,
                             const int* __restrict__ iT, const int* __restrict__ jT,
                             const unsigned* __restrict__ mi, const float* __restrict__ si,
                             const unsigned* __restrict__ mj, const float* __restrict__ sj,
                             const int* __restrict__ slotOf,
                             float* __restrict__ vsumC, int LGE, int R)
{
    int e = blockIdx.x*blockDim.x + threadIdx.x;
    if (e >= 2*LGE) return;
    bool g1 = e >= LGE; int le = g1 ? e - LGE : e;
    float v = g1 ? tval[le] : mval[le];
    int i = (g1 ? iT[le] : iM[le]) + (g1 ? R : 0);
    int j = (g1 ? jT[le] : jM[le]) + (g1 ? R : 0);
    float pi = expf(v - mono2f(mi[i])) / (si[i] + 1e-16f);
    float pj = expf(v - mono2f(mj[j])) / (sj[j] + 1e-16f);
    vsumC[slotOf[e]] = pi + pj;
}
// stats for second softmax, iterated in CSR order (lgjp has graph offset)
__global__ void k_lgat_max2C(const float* __restrict__ vsumC, const int* __restrict__ lgjp,
                             unsigned* __restrict__ m2, int tot)
{
    int p = blockIdx.x*blockDim.x + threadIdx.x;
    if (p >= tot) return;
    atomicMax(&m2[lgjp[p]], f2mono(vsumC[p]));
}
__global__ void k_lgat_sum2C(const float* __restrict__ vsumC, const int* __restrict__ lgjp,
                             const unsigned* __restrict__ m2, float* __restrict__ s2, int tot)
{
    int p = blockIdx.x*blockDim.x + threadIdx.x;
    if (p >= tot) return;
    int j = lgjp[p];
    atomicAdd(&s2[j], expf(vsumC[p] - mono2f(m2[j])));
}
// GATHER aggregation: wave per output row gw in [0,2R); relu fused.
__global__ void k_lgat_gather(const float* __restrict__ vsumC, const int* __restrict__ lgjp,
                              const unsigned* __restrict__ m2, const float* __restrict__ s2,
                              const int* __restrict__ rowptr, const int* __restrict__ cnt,
                              const float* __restrict__ remb1, const float* __restrict__ remb2,
                              float* __restrict__ obuf, int lgbase, int R, int RH)
{
    int gw = (blockIdx.x*blockDim.x + threadIdx.x) >> 6;
    int lane = threadIdx.x & 63;
    if (gw >= 2*R) return;
    int beg = rowptr[gw] - lgbase, end = beg + cnt[gw];
    float4 acc = {0,0,0,0};
    const bool act = (lane < 25);
    for (int p = beg; p < end; ++p) {
        int j = lgjp[p];
        float alpha = expf(vsumC[p] - mono2f(m2[j])) / (s2[j] + 1e-16f);
        if (act) {
            const float* x = (j < R) ? (remb1 + (long)j*RH) : (remb2 + (long)(j - R)*RH);
            float4 v = ((const float4*)x)[lane];
            acc.x += alpha*v.x; acc.y += alpha*v.y;
            acc.z += alpha*v.z; acc.w += alpha*v.w;
        }
    }
    if (act) {
        acc.x = fmaxf(acc.x, 0.0f); acc.y = fmaxf(acc.y, 0.0f);
        acc.z = fmaxf(acc.z, 0.0f); acc.w = fmaxf(acc.w, 0.0f);
        ((float4*)(obuf + (long)gw*RH))[lane] = acc;
    }
}

// ---------- highway combine (small R x RH path) ----------
__global__ void k_highway(const float* __restrict__ x1, long ld1,
                          const float* __restrict__ gl, long ldg,
                          const float* __restrict__ x2, long ld2,
                          const float* __restrict__ bias,
                          float* __restrict__ out, long ldo,
                          long rows, int F, int relu_x2)
{
    long idx = (long)blockIdx.x*blockDim.x + threadIdx.x;
    if (idx >= rows * (long)F) return;
    long r = idx / F; int c = (int)(idx % F);
    float g = 1.0f / (1.0f + expf(-(gl[r*ldg+c] + bias[c])));
    float v2 = x2[r*ld2+c]; if (relu_x2) v2 = fmaxf(v2, 0.0f);
    float v1 = x1[r*ld1+c];
    out[r*ldo+c] = g*v2 + (1.0f-g)*v1;
}

// merged: waves 0..R-1: rsc[r]; waves R..2R-1: srel[r] + xrb emit
__global__ void k_rs2(const float* __restrict__ mg, const float* __restrict__ tr,
                      const float* __restrict__ ar,
                      const float* __restrict__ xr, const float* __restrict__ g2e_ar,
                      float* __restrict__ rsc, float* __restrict__ srel,
                      unsigned short* __restrict__ xrb, int R, int RH)
{
    int gw = (blockIdx.x*blockDim.x + threadIdx.x) >> 6;
    int lane = threadIdx.x & 63;
    if (gw >= 2*R) return;
    float s = 0.0f;
    if (gw < R) {
        for (int k = lane; k < RH; k += WAVE)
            s += mg[(long)gw*RH+k]*ar[k] + tr[(long)gw*RH+k]*ar[RH+k];
        #pragma unroll
        for (int off = 32; off > 0; off >>= 1) s += __shfl_down(s, off);
        if (lane == 0) rsc[gw] = s;
    } else {
        int r = gw - R;
        #pragma unroll
        for (int t = 0; t < 2; ++t) {
            int k = lane + t*64;
            if (k < RH) {
                float v = xr[(long)r*RH + k];
                s += v * g2e_ar[k];
                xrb[(long)r*128 + k] = f2bf_rne(v);
            }
        }
        #pragma unroll
        for (int off = 32; off > 0; off >>= 1) s += __shfl_down(s, off);
        if (lane == 0) srel[r] = s;
    }
}

extern "C" void kernel_launch(void* const* d_in, const int* in_sizes, int n_in,
                              void* d_out, int out_size, void* d_ws, size_t ws_size,
                              hipStream_t stream)
{
    const float* x_e   = (const float*)d_in[0];
    const float* mval  = (const float*)d_in[1];
    const float* tval  = (const float*)d_in[2];
    const float* g1w   = (const float*)d_in[3];
    const float* h1w   = (const float*)d_in[4];
    const float* h1b   = (const float*)d_in[5];
    const float* g2w   = (const float*)d_in[6];
    const float* h2w   = (const float*)d_in[7];
    const float* h2b   = (const float*)d_in[8];
    const float* remb1 = (const float*)d_in[9];
    const float* remb2 = (const float*)d_in[10];
    const float* hrw   = (const float*)d_in[11];
    const float* hrb   = (const float*)d_in[12];
    const float* gat_ai= (const float*)d_in[13];
    const float* gat_aj= (const float*)d_in[14];
    const float* gat_ar= (const float*)d_in[15];
    const float* g2e_ah= (const float*)d_in[16];
    const float* g2e_at= (const float*)d_in[17];
    const float* g2e_ar= (const float*)d_in[18];
    const int* edge_index     = (const int*)d_in[19];
    const int* rel            = (const int*)d_in[20];
    const int* edge_index_all = (const int*)d_in[21];
    const int* rel_all        = (const int*)d_in[22];
    const int* lg_merge       = (const int*)d_in[23];
    const int* lg_tri         = (const int*)d_in[24];

    const int F    = 300;
    const int RH   = 100;
    const int Kp   = 304;
    const int npk  = Kp / 16;              // 19
    const int N    = in_sizes[0] / F;      // 100000
    const int E    = in_sizes[20];         // 400000
    const int EA   = in_sizes[22];         // 800000
    const int LGE  = in_sizes[1];          // 60000
    const int R    = in_sizes[9] / RH;     // 2000
    const long OUTC = 800;
    const int Mpad = CDIV(N, 128) * 128;
    const int NB   = 640;
    const long LDC = 640;

    const int* jA = edge_index_all;
    const int* iA = edge_index_all + EA;
    const int* hE = edge_index;
    const int* tE = edge_index + E;
    const int* jM = lg_merge;  const int* iM = lg_merge + LGE;
    const int* jT = lg_tri;    const int* iT = lg_tri  + LGE;

    float* ws = (float*)d_ws;
    size_t off = 0;
    auto alloc = [&](size_t n) { float* p = ws + off; off += (n + 15) & ~(size_t)15; return p; };
    unsigned short* Ascr = (unsigned short*)alloc((size_t)N*NB/2);
    unsigned short* Axb = (unsigned short*)alloc((size_t)Mpad*Kp/2);
    unsigned short* xbf = (unsigned short*)alloc((size_t)N*XBS/2);
    unsigned short* Wb  = (unsigned short*)alloc((size_t)2*NB*Kp/2);
    unsigned short* W0 = Wb;
    unsigned short* W1 = Wb + (size_t)NB*Kp;
    unsigned short* xrb = (unsigned short*)alloc((size_t)R*128/2);
    float*    sA_  = alloc(N);
    float*    sB_  = alloc(N);
    float*    sH_  = alloc(N);
    float*    sT_  = alloc(N);
    float*    xr   = alloc((size_t)R*RH);
    float*    xrg  = alloc((size_t)R*RH);
    float*    lg   = alloc((size_t)12*R + (size_t)2*R*RH);
    unsigned* lmi  = (unsigned*)lg;          float* lsi = lg + 2*R;
    unsigned* lmj  = (unsigned*)(lg + 4*R);  float* lsj = lg + 6*R;
    unsigned* lm2  = (unsigned*)(lg + 8*R);  float* ls2 = lg + 10*R;
    float*    obuf = lg + 12*R;              // [2R][RH]: mrg then tri
    float*    mrg  = obuf;
    float*    tri  = obuf + (size_t)R*RH;
    float*    vsumC = alloc((size_t)2*LGE);
    float*    rsc  = alloc(R);
    float*    srel = alloc(R);
    int*   bsum    = (int*)alloc(1024);
    const int NR   = 3*N + 2*R;
    int*   cntAll  = (int*)alloc((size_t)2*NR);
    int*   curAll  = cntAll + NR;
    int*   rowptrG = (int*)alloc((size_t)NR);
    int*   relpAll = (int*)alloc((size_t)EA + 2*E);
    int*   jpA     = (int*)alloc(EA);
    float* nmA     = alloc(EA);
    int*   lgjp    = (int*)alloc((size_t)2*LGE);
    int*   slotOf  = (int*)alloc((size_t)2*LGE);

    float* out = (float*)d_out;              // [N, 800]

    const int  nrb = CDIV(N, 128);
    const int  gemmBlocks = 8 * CDIV(nrb, 8) * 5;
    const int  gatherGrid = CDIV(N, 4);
    const int  cvtBigGrid = CDIV((long)N * (Kp/4), 256);
    const int  cvtW4Grid  = CDIV((long)4 * 300 * (Kp/4), 256);
    const int  ETOT = EA + 2*E + 2*LGE;
    const int  lgbase = EA + 2*E;
    const int  nbNR = CDIV(NR, 512);

    // ===== converts (weights merged + x_e), pads zeroed =====
    hipMemsetAsync(Wb, 0, (size_t)2*NB*Kp*2, stream);
    hipMemsetAsync(Axb + (size_t)N*Kp, 0, (size_t)(Mpad-N)*Kp*2, stream);
    k_cvt_w4<<<cvtW4Grid,256,0,stream>>>(g1w, h1w, g2w, h2w, npk, W0, W1);
    k_cvt_pack1<<<cvtBigGrid,256,0,stream>>>(x_e, 300, N, 300, npk, 0, Axb);

    // ===== merged CSR build (A, H, T, LG-M, LG-T) with fused placement =====
    hipMemsetAsync(cntAll, 0, (size_t)2*NR*4, stream);
    k_hist5<<<CDIV(ETOT,256),256,0,stream>>>(iA, hE, tE, iM, iT, cntAll, EA, E, LGE, N, R);
    k_scan1<<<nbNR,512,0,stream>>>(cntAll, rowptrG, bsum, NR);
    k_scan2<<<1,1024,0,stream>>>(bsum, nbNR);
    k_scan3<<<nbNR,512,0,stream>>>(rowptrG, bsum, NR);
    k_fill5f<<<CDIV(ETOT,256),256,0,stream>>>(iA, jA, hE, tE, iM, jM, iT, jT, rel_all, rel,
                                              rowptrG, cntAll, curAll,
                                              jpA, nmA, relpAll, lgjp, slotOf,
                                              EA, E, LGE, N, R, lgbase);

    // ===== GCN layer 1 =====
    k_gemm_frag<<<gemmBlocks,256,0,stream>>>(Axb, W0, Ascr, LDC, N, 620, npk, nrb);
    k_gather_hw<<<gatherGrid,256,0,stream>>>(Ascr, LDC, Ascr+320,
                                             x_e, (const unsigned short*)nullptr, h1b,
                                             jpA, nmA, rowptrG, cntAll,
                                             (float*)nullptr, OUTC, Axb, xbf,
                                             (const float*)nullptr, (const float*)nullptr,
                                             (float*)nullptr, (float*)nullptr, npk, N);

    // ===== GCN layer 2 =====
    k_gemm_frag<<<gemmBlocks,256,0,stream>>>(Axb, W1, Ascr, LDC, N, 620, npk, nrb);
    k_gather_hw<<<gatherGrid,256,0,stream>>>(Ascr, LDC, Ascr+320,
                                             (const float*)nullptr, xbf, h2b,
                                             jpA, nmA, rowptrG, cntAll,
                                             out, OUTC, (unsigned short*)nullptr, xbf,
                                             gat_ai, gat_aj, sA_, sB_, npk, N);

    // ===== merged l_gat (stats atomics + CSR gather aggregation) =====
    hipMemsetAsync(lg, 0, (size_t)12*R*4, stream);
    const int lgGrid = CDIV(2*LGE, 256);
    k_lgat_max  <<<lgGrid,256,0,stream>>>(mval, tval, iM, jM, iT, jT, lmi, lmj, LGE, R);
    k_lgat_sum  <<<lgGrid,256,0,stream>>>(mval, tval, iM, jM, iT, jT, lmi, lmj, lsi, lsj, LGE, R);
    k_lgat_vsum2<<<lgGrid,256,0,stream>>>(mval, tval, iM, jM, iT, jT, lmi, lsi, lmj, lsj,
                                          slotOf, vsumC, LGE, R);
    k_lgat_max2C<<<lgGrid,256,0,stream>>>(vsumC, lgjp, lm2, 2*LGE);
    k_lgat_sum2C<<<lgGrid,256,0,stream>>>(vsumC, lgjp, lm2, ls2, 2*LGE);
    k_lgat_gather<<<CDIV(2*R*64,256),256,0,stream>>>(vsumC, lgjp, lm2, ls2,
                                                     rowptrG + 3*N, cntAll + 3*N,
                                                     remb1, remb2, obuf, lgbase, R, RH);

    // ===== x_r = highway(mrg, tri, hrw, hrb) =====
    dim3 gridR(CDIV(RH,GBN), CDIV(R,GBM));
    k_gemm<<<gridR,256,0,stream>>>(mrg, RH, hrw, RH, xrg, RH, R, RH, RH);
    k_highway<<<CDIV((long)R*RH,256),256,0,stream>>>(mrg, RH, xrg, RH, tri, RH, hrb, xr, RH, R, RH, 0);

    // merged relscore + srel (+ xrb emit)
    k_rs2<<<CDIV((long)2*R*64,256),256,0,stream>>>(mrg, tri, gat_ar, xr, g2e_ar,
                                                   rsc, srel, xrb, R, RH);

    // ===== GAT -> out cols 300..599 + r2e score dots =====
    k_gat300<<<gatherGrid,256,0,stream>>>(xbf, sA_, sB_, rsc, jpA, relpAll,
                                          rowptrG, cntAll, out+300, OUTC,
                                          g2e_ah, g2e_at, sH_, sT_, N);

    // ===== gat_r_to_e -> out cols 600..799 (h+t merged, bf16 xrb) =====
    k_gather_rel2<<<CDIV(2*N,4),256,0,stream>>>(xrb, sH_, sT_, srel, relpAll,
                                                rowptrG + N, cntAll + N,
                                                rowptrG + 2*N, cntAll + 2*N,
                                                out, OUTC, N);
}

// Round 17
// 1037.474 us; speedup vs baseline: 1.6209x; 1.0249x over previous
//
#include <hip/hip_runtime.h>

#define WAVE 64
#define CDIV(a,b) (((a)+(b)-1)/(b))
#define XBS 320   // xbf row stride in shorts (640B rows)

typedef float f32x16 __attribute__((ext_vector_type(16)));
typedef unsigned short u16x8 __attribute__((ext_vector_type(8)));

// ---------- bf16 helpers ----------
__device__ __forceinline__ unsigned short f2bf_rne(float f) {
    unsigned u = __float_as_uint(f);
    unsigned r = (u + 0x7FFFu + ((u >> 16) & 1u)) >> 16;
    return (unsigned short)r;
}
__device__ __forceinline__ float bf2f(unsigned short h) {
    return __uint_as_float(((unsigned)h) << 16);
}
__device__ __forceinline__ float2 bfp2f(ushort2 u) {
    float2 r; r.x = bf2f(u.x); r.y = bf2f(u.y); return r;
}
__device__ __forceinline__ float sigm(float x) { return 1.0f / (1.0f + expf(-x)); }

#define MFMA32(acc, a, b) \
    asm volatile("v_mfma_f32_32x32x16_bf16 %0, %1, %2, %0" : "+v"(acc) : "v"(a), "v"(b))

// ---------- monotonic float<->uint encoding for atomicMax on floats ----------
__device__ __forceinline__ unsigned f2mono(float f) {
    unsigned u = __float_as_uint(f);
    return (u & 0x80000000u) ? ~u : (u | 0x80000000u);
}
__device__ __forceinline__ float mono2f(unsigned u) {
    return (u & 0x80000000u) ? __uint_as_float(u & 0x7fffffffu) : __uint_as_float(~u);
}
__device__ __forceinline__ float leaky(float v) { return (v > 0.0f) ? v : 0.01f*v; }

// fragment-pack offset: matrix row r, col k -> packed short index.
__device__ __forceinline__ long fragoff(long r, int k, int npk) {
    return ((r >> 5) * (long)npk + (k >> 4)) * 512
         + (((k >> 3) & 1) << 8) + ((r & 31) << 3) + (k & 7);
}

// ---------- k_cvt_pack1: f32 -> fragment-packed single bf16 (rne) ----------
__global__ void k_cvt_pack1(const float* __restrict__ src, long ld, int rows, int K, int npk,
                            int roff, unsigned short* __restrict__ dst)
{
    int nc4 = npk << 2;
    long idx = (long)blockIdx.x*blockDim.x + threadIdx.x;
    if (idx >= (long)rows * nc4) return;
    long r = idx / nc4; int k = (int)(idx % nc4) << 2;
    float4 v = {0.0f, 0.0f, 0.0f, 0.0f};
    if (k + 4 <= K) v = *(const float4*)(src + r*ld + k);
    ushort4 h;
    h.x = f2bf_rne(v.x); h.y = f2bf_rne(v.y); h.z = f2bf_rne(v.z); h.w = f2bf_rne(v.w);
    *(ushort4*)(dst + fragoff(r + roff, k, npk)) = h;
}

// merged weight convert: 4 matrices [300][300] -> W0(g@0,h@320), W1(g@0,h@320)
__global__ void k_cvt_w4(const float* __restrict__ g1w, const float* __restrict__ h1w,
                         const float* __restrict__ g2w, const float* __restrict__ h2w,
                         int npk, unsigned short* __restrict__ W0,
                         unsigned short* __restrict__ W1)
{
    const int nc4 = npk << 2;                 // 76
    const long per = (long)300 * nc4;
    long idx = (long)blockIdx.x*blockDim.x + threadIdx.x;
    if (idx >= 4*per) return;
    int which = (int)(idx / per);
    long lidx = idx % per;
    long r = lidx / nc4; int k = (int)(lidx % nc4) << 2;
    const float* src = (which == 0) ? g1w : (which == 1) ? h1w : (which == 2) ? g2w : h2w;
    unsigned short* dst = (which < 2) ? W0 : W1;
    int roff = (which & 1) ? 320 : 0;
    float4 v = {0.0f, 0.0f, 0.0f, 0.0f};
    if (k + 4 <= 300) v = *(const float4*)(src + r*300 + k);
    ushort4 h;
    h.x = f2bf_rne(v.x); h.y = f2bf_rne(v.y); h.z = f2bf_rne(v.z); h.w = f2bf_rne(v.w);
    *(ushort4*)(dst + fragoff(r + roff, k, npk)) = h;
}

// =========================================================================
// k_gemm_frag: C[M,620] (bf16) = A * B^T; A and B single bf16 (rne).
// NO LDS, NO barriers. XCD-ownership swizzle. 4 MFMA / 5 loads per k-step.
// =========================================================================
__global__ __launch_bounds__(256, 3)
void k_gemm_frag(const unsigned short* __restrict__ Ab,
                 const unsigned short* __restrict__ Bb,
                 unsigned short* __restrict__ C, long ldc, int M, int N, int nk, int nrb)
{
    const int lane = threadIdx.x & 63;
    const int wid  = threadIdx.x >> 6;
    const int lin  = blockIdx.x;
    const int xcd  = lin & 7;
    const int m    = lin >> 3;
    const int col0 = (m % 5) * 128;
    const int rb   = xcd + ((m / 5) << 3);
    if (rb >= nrb) return;
    const int row0 = rb * 128 + wid * 32;

    const long cs = (long)nk * 512;
    const unsigned short* pA = Ab + (long)(row0 >> 5) * cs + lane * 8;
    const unsigned short* pB = Bb + (long)(col0 >> 5) * cs + lane * 8;

    f32x16 acc[4];
    #pragma unroll
    for (int c = 0; c < 4; ++c) acc[c] = (f32x16)0.0f;

    u16x8 pa, pb0, pb1, pb2, pb3;
    u16x8 qa, qb0, qb1, qb2, qb3;

    #define LOADP(t_) { long o = (long)(t_)*512;                                   \
        pa  = *(const u16x8*)(pA + o);                                             \
        pb0 = *(const u16x8*)(pB + o);        pb1 = *(const u16x8*)(pB + cs + o);  \
        pb2 = *(const u16x8*)(pB + 2*cs + o); pb3 = *(const u16x8*)(pB + 3*cs + o); }
    #define LOADQ(t_) { long o = (long)(t_)*512;                                   \
        qa  = *(const u16x8*)(pA + o);                                             \
        qb0 = *(const u16x8*)(pB + o);        qb1 = *(const u16x8*)(pB + cs + o);  \
        qb2 = *(const u16x8*)(pB + 2*cs + o); qb3 = *(const u16x8*)(pB + 3*cs + o); }
    #define STEPP {                                                                 \
        MFMA32(acc[0], pa, pb0); MFMA32(acc[1], pa, pb1);                           \
        MFMA32(acc[2], pa, pb2); MFMA32(acc[3], pa, pb3); }
    #define STEPQ {                                                                 \
        MFMA32(acc[0], qa, qb0); MFMA32(acc[1], qa, qb1);                           \
        MFMA32(acc[2], qa, qb2); MFMA32(acc[3], qa, qb3); }

    LOADP(0);
    int t = 0;
    for (;;) {
        bool m1 = (t + 1 < nk);
        if (m1) LOADQ(t + 1);
        STEPP;
        if (!m1) break;
        bool m2 = (t + 2 < nk);
        if (m2) LOADP(t + 2);
        STEPQ;
        if (!m2) break;
        t += 2;
    }
    #undef LOADP
    #undef LOADQ
    #undef STEPP
    #undef STEPQ

    const int crow0 = row0 + 4*(lane >> 5);
    const int ccol0 = col0 + (lane & 31);
    #pragma unroll
    for (int c = 0; c < 4; ++c) {
        int col = ccol0 + c*32;
        if (col >= N) continue;
        #pragma unroll
        for (int reg = 0; reg < 16; ++reg) {
            int row = crow0 + (reg & 3) + 8*(reg >> 2);
            if (row < M) C[(long)row*ldc + col] = f2bf_rne(acc[c][reg]);
        }
    }
}

// ---------- small f32 GEMM (tiny R x RH highway gate) ----------
#define GBM 64
#define GBN 64
#define GBK 16
__global__ __launch_bounds__(256)
void k_gemm(const float* __restrict__ A, long lda,
            const float* __restrict__ B, long ldb,
            float* __restrict__ C, long ldc,
            int M, int N, int K)
{
    __shared__ float As[GBK][GBM + 4];
    __shared__ float Bs[GBK][GBN + 4];
    const int tid = threadIdx.x;
    const int tx = tid & 15, ty = tid >> 4;
    const int row0 = blockIdx.y * GBM, col0 = blockIdx.x * GBN;
    float acc[4][4] = {};
    for (int kt = 0; kt < K; kt += GBK) {
        #pragma unroll
        for (int p = 0; p < 4; ++p) {
            int mn = (tid >> 4) + p * 16;
            int k  = tid & 15;
            int gk = kt + k;
            int gr = row0 + mn;
            As[k][mn] = (gr < M && gk < K) ? A[(long)gr * lda + gk] : 0.0f;
            int gc = col0 + mn;
            Bs[k][mn] = (gc < N && gk < K) ? B[(long)gc * ldb + gk] : 0.0f;
        }
        __syncthreads();
        #pragma unroll
        for (int kk = 0; kk < GBK; ++kk) {
            float a0 = As[kk][ty*4+0], a1 = As[kk][ty*4+1];
            float a2 = As[kk][ty*4+2], a3 = As[kk][ty*4+3];
            float b0 = Bs[kk][tx*4+0], b1 = Bs[kk][tx*4+1];
            float b2 = Bs[kk][tx*4+2], b3 = Bs[kk][tx*4+3];
            acc[0][0] += a0*b0; acc[0][1] += a0*b1; acc[0][2] += a0*b2; acc[0][3] += a0*b3;
            acc[1][0] += a1*b0; acc[1][1] += a1*b1; acc[1][2] += a1*b2; acc[1][3] += a1*b3;
            acc[2][0] += a2*b0; acc[2][1] += a2*b1; acc[2][2] += a2*b2; acc[2][3] += a2*b3;
            acc[3][0] += a3*b0; acc[3][1] += a3*b1; acc[3][2] += a3*b2; acc[3][3] += a3*b3;
        }
        __syncthreads();
    }
    #pragma unroll
    for (int i2 = 0; i2 < 4; ++i2)
        #pragma unroll
        for (int j2 = 0; j2 < 4; ++j2) {
            int r = row0 + ty*4 + i2, c = col0 + tx*4 + j2;
            if (r < M && c < N) C[(long)r*ldc + c] = acc[i2][j2];
        }
}

// ================= merged CSR build over 5 graphs =================
// rows: [0,N) A-dest, [N,2N) H, [2N,3N) T, [3N,3N+R) LG-merge-i, [3N+R,3N+2R) LG-tri-i
__global__ void k_hist5(const int* __restrict__ iA, const int* __restrict__ hE,
                        const int* __restrict__ tE, const int* __restrict__ iM,
                        const int* __restrict__ iT, int* __restrict__ cnt,
                        int EA, int E, int LGE, int N, int R) {
    int e = blockIdx.x*blockDim.x + threadIdx.x;
    int tot = EA + 2*E + 2*LGE;
    if (e >= tot) return;
    if (e < EA)                  atomicAdd(&cnt[iA[e]], 1);
    else if (e < EA + E)         atomicAdd(&cnt[N + hE[e - EA]], 1);
    else if (e < EA + 2*E)       atomicAdd(&cnt[2*N + tE[e - EA - E]], 1);
    else if (e < EA + 2*E + LGE) atomicAdd(&cnt[3*N + iM[e - EA - 2*E]], 1);
    else                         atomicAdd(&cnt[3*N + R + iT[e - EA - 2*E - LGE]], 1);
}
__global__ void k_scan1(const int* __restrict__ in, int* __restrict__ out,
                        int* __restrict__ bsum, int n) {
    __shared__ int sh[512];
    int gid = blockIdx.x*512 + threadIdx.x;
    int v = (gid < n) ? in[gid] : 0;
    sh[threadIdx.x] = v; __syncthreads();
    for (int o = 1; o < 512; o <<= 1) {
        int t = (threadIdx.x >= o) ? sh[threadIdx.x - o] : 0;
        __syncthreads();
        sh[threadIdx.x] += t;
        __syncthreads();
    }
    if (gid < n) out[gid] = sh[threadIdx.x] - v;      // exclusive
    if (threadIdx.x == 511) bsum[blockIdx.x] = sh[511];
}
__global__ void k_scan2(int* __restrict__ bsum, int nb) {   // single block, nb <= 1024
    __shared__ int sh[1024];
    int v = (threadIdx.x < nb) ? bsum[threadIdx.x] : 0;
    sh[threadIdx.x] = v; __syncthreads();
    for (int o = 1; o < 1024; o <<= 1) {
        int t = (threadIdx.x >= o) ? sh[threadIdx.x - o] : 0;
        __syncthreads();
        sh[threadIdx.x] += t;
        __syncthreads();
    }
    if (threadIdx.x < nb) bsum[threadIdx.x] = sh[threadIdx.x] - v;  // exclusive
}
__global__ void k_scan3(int* __restrict__ out, const int* __restrict__ bsum, int n) {
    int gid = blockIdx.x*512 + threadIdx.x;
    if (gid < n) out[gid] += bsum[blockIdx.x];
}
// fused fill: place edge at CSR slot AND write jp/nm (A) + relp (A/H/T)
// + lgjp/slotOf (LG regions; slots relative to lgbase).
__global__ void k_fill5f(const int* __restrict__ iA, const int* __restrict__ jA,
                         const int* __restrict__ hE, const int* __restrict__ tE,
                         const int* __restrict__ iM, const int* __restrict__ jM,
                         const int* __restrict__ iT, const int* __restrict__ jT,
                         const int* __restrict__ rel_all, const int* __restrict__ rel,
                         const int* __restrict__ rowptr, const int* __restrict__ cnt,
                         int* __restrict__ cursor,
                         int* __restrict__ jp, float* __restrict__ nm,
                         int* __restrict__ relp,
                         int* __restrict__ lgjp, int* __restrict__ slotOf,
                         int EA, int E, int LGE, int N, int R, int lgbase) {
    int e = blockIdx.x*blockDim.x + threadIdx.x;
    int tot = EA + 2*E + 2*LGE;
    if (e >= tot) return;
    if (e < EA) {
        int le = e;
        int i = iA[le];
        int p = rowptr[i] + atomicAdd(&cursor[i], 1);
        int j = jA[le];
        jp[p] = j;
        float di = rsqrtf((float)cnt[i]);
        int cj = cnt[j];
        float dj = (cj > 0) ? rsqrtf((float)cj) : 0.0f;
        nm[p] = di * dj;
        relp[p] = rel_all[le] % R;
    } else if (e < EA + E) {
        int le = e - EA;
        int key = N + hE[le];
        int p = rowptr[key] + atomicAdd(&cursor[key], 1);
        relp[p] = rel[le];
    } else if (e < EA + 2*E) {
        int le = e - EA - E;
        int key = 2*N + tE[le];
        int p = rowptr[key] + atomicAdd(&cursor[key], 1);
        relp[p] = rel[le];
    } else if (e < EA + 2*E + LGE) {
        int le = e - EA - 2*E;
        int key = 3*N + iM[le];
        int p = rowptr[key] + atomicAdd(&cursor[key], 1) - lgbase;
        lgjp[p] = jM[le];
        slotOf[le] = p;
    } else {
        int le = e - EA - 2*E - LGE;
        int key = 3*N + R + iT[le];
        int p = rowptr[key] + atomicAdd(&cursor[key], 1) - lgbase;
        lgjp[p] = jT[le] + R;
        slotOf[LGE + le] = p;
    }
}

// =========================================================================
// k_gather_hw: fused GCN gather (bf16 src, 8/4/1 edge unroll) + relu +
// highway + extras. x1 from f32 (x1f) or xbf bf16 stride XBS (x1b).
// =========================================================================
__global__ void k_gather_hw(const unsigned short* __restrict__ xg, long ldx,
                            const unsigned short* __restrict__ gl,
                            const float* __restrict__ x1f,
                            const unsigned short* __restrict__ x1b,
                            const float* __restrict__ bias,
                            const int* __restrict__ jp, const float* __restrict__ nm,
                            const int* __restrict__ rowptr, const int* __restrict__ cnt,
                            float* __restrict__ outp, long ldo,
                            unsigned short* __restrict__ pk,
                            unsigned short* __restrict__ xbf,
                            const float* __restrict__ ai, const float* __restrict__ aj,
                            float* __restrict__ sa, float* __restrict__ sb,
                            int npk, int n)
{
    int w = (blockIdx.x*blockDim.x + threadIdx.x) >> 6;
    int lane = threadIdx.x & 63;
    if (w >= n) return;
    int beg = rowptr[w], end = beg + cnt[w];
    const int i0 = lane, i1 = lane + 64, i2 = lane + 128;
    const bool t3 = (lane < 22);
    float2 a0 = {0,0}, a1 = {0,0}, a2 = {0,0};
    int e = beg;
    for (; e + 8 <= end; e += 8) {
        long jj[8]; float wt[8];
        #pragma unroll
        for (int u = 0; u < 8; ++u) { jj[u] = jp[e+u]; wt[u] = nm[e+u]; }
        #pragma unroll
        for (int u = 0; u < 8; ++u) {
            float2 v = bfp2f(((const ushort2*)(xg + jj[u]*ldx))[i0]);
            a0.x += wt[u]*v.x; a0.y += wt[u]*v.y;
        }
        #pragma unroll
        for (int u = 0; u < 8; ++u) {
            float2 v = bfp2f(((const ushort2*)(xg + jj[u]*ldx))[i1]);
            a1.x += wt[u]*v.x; a1.y += wt[u]*v.y;
        }
        if (t3) {
            #pragma unroll
            for (int u = 0; u < 8; ++u) {
                float2 v = bfp2f(((const ushort2*)(xg + jj[u]*ldx))[i2]);
                a2.x += wt[u]*v.x; a2.y += wt[u]*v.y;
            }
        }
    }
    for (; e + 4 <= end; e += 4) {
        long jj[4]; float wt[4];
        #pragma unroll
        for (int u = 0; u < 4; ++u) { jj[u] = jp[e+u]; wt[u] = nm[e+u]; }
        #pragma unroll
        for (int u = 0; u < 4; ++u) {
            float2 v = bfp2f(((const ushort2*)(xg + jj[u]*ldx))[i0]);
            a0.x += wt[u]*v.x; a0.y += wt[u]*v.y;
        }
        #pragma unroll
        for (int u = 0; u < 4; ++u) {
            float2 v = bfp2f(((const ushort2*)(xg + jj[u]*ldx))[i1]);
            a1.x += wt[u]*v.x; a1.y += wt[u]*v.y;
        }
        if (t3) {
            #pragma unroll
            for (int u = 0; u < 4; ++u) {
                float2 v = bfp2f(((const ushort2*)(xg + jj[u]*ldx))[i2]);
                a2.x += wt[u]*v.x; a2.y += wt[u]*v.y;
            }
        }
    }
    for (; e < end; ++e) {
        long j0 = jp[e]; float w0 = nm[e];
        float2 v;
        v = bfp2f(((const ushort2*)(xg + j0*ldx))[i0]); a0.x += w0*v.x; a0.y += w0*v.y;
        v = bfp2f(((const ushort2*)(xg + j0*ldx))[i1]); a1.x += w0*v.x; a1.y += w0*v.y;
        if (t3) { v = bfp2f(((const ushort2*)(xg + j0*ldx))[i2]); a2.x += w0*v.x; a2.y += w0*v.y; }
    }
    // highway: o = sig(gl+b)*relu(acc) + (1-sig)*x1
    const ushort2* glr = (const ushort2*)(gl + (long)w*ldx);
    const float2*  x1r = (const float2*)(x1f + (long)w*300);
    const ushort2* x1r2 = (const ushort2*)(x1b + (long)w*XBS);
    const float2*  br  = (const float2*)bias;
    float2 o0 = {0,0}, o1 = {0,0}, o2 = {0,0};
    {
        float2 gv = bfp2f(glr[i0]); float2 bv = br[i0];
        float2 xv = x1f ? x1r[i0] : bfp2f(x1r2[i0]);
        float g0 = sigm(gv.x + bv.x), g1 = sigm(gv.y + bv.y);
        o0.x = g0*fmaxf(a0.x,0.0f) + (1.0f-g0)*xv.x;
        o0.y = g1*fmaxf(a0.y,0.0f) + (1.0f-g1)*xv.y;
    }
    {
        float2 gv = bfp2f(glr[i1]); float2 bv = br[i1];
        float2 xv = x1f ? x1r[i1] : bfp2f(x1r2[i1]);
        float g0 = sigm(gv.x + bv.x), g1 = sigm(gv.y + bv.y);
        o1.x = g0*fmaxf(a1.x,0.0f) + (1.0f-g0)*xv.x;
        o1.y = g1*fmaxf(a1.y,0.0f) + (1.0f-g1)*xv.y;
    }
    if (t3) {
        float2 gv = bfp2f(glr[i2]); float2 bv = br[i2];
        float2 xv = x1f ? x1r[i2] : bfp2f(x1r2[i2]);
        float g0 = sigm(gv.x + bv.x), g1 = sigm(gv.y + bv.y);
        o2.x = g0*fmaxf(a2.x,0.0f) + (1.0f-g0)*xv.x;
        o2.y = g1*fmaxf(a2.y,0.0f) + (1.0f-g1)*xv.y;
    }
    if (outp) {
        float2* dst = (float2*)(outp + (long)w*ldo);
        dst[i0] = o0; dst[i1] = o1;
        if (t3) dst[i2] = o2;
    }
    if (pk) {
        auto pack2 = [&](int k, float2 o) {
            ushort2 hv; hv.x = f2bf_rne(o.x); hv.y = f2bf_rne(o.y);
            *(ushort2*)(pk + fragoff(w, k, npk)) = hv;
        };
        pack2(2*lane, o0);
        pack2(128 + 2*lane, o1);
        if (t3) pack2(256 + 2*lane, o2);
        else if (lane < 24) {
            ushort2 z = {0,0};
            *(ushort2*)(pk + fragoff(w, 256 + 2*lane, npk)) = z;
        }
    }
    if (xbf) {
        ushort2* xw = (ushort2*)(xbf + (long)w*XBS);
        ushort2 t;
        t.x = f2bf_rne(o0.x); t.y = f2bf_rne(o0.y); xw[i0] = t;
        t.x = f2bf_rne(o1.x); t.y = f2bf_rne(o1.y); xw[i1] = t;
        if (t3) { t.x = f2bf_rne(o2.x); t.y = f2bf_rne(o2.y); xw[i2] = t; }
    }
    if (sa) {
        const float2* ai2 = (const float2*)ai;
        const float2* aj2 = (const float2*)aj;
        float2 A0 = ai2[i0], A1 = ai2[i1], J0 = aj2[i0], J1 = aj2[i1];
        float sva = o0.x*A0.x + o0.y*A0.y + o1.x*A1.x + o1.y*A1.y;
        float svb = o0.x*J0.x + o0.y*J0.y + o1.x*J1.x + o1.y*J1.y;
        if (t3) {
            float2 A2 = ai2[i2], J2 = aj2[i2];
            sva += o2.x*A2.x + o2.y*A2.y;
            svb += o2.x*J2.x + o2.y*J2.y;
        }
        #pragma unroll
        for (int o = 32; o > 0; o >>= 1) {
            sva += __shfl_down(sva, o);
            svb += __shfl_down(svb, o);
        }
        if (lane == 0) { sa[w] = sva; sb[w] = svb; }
    }
}

// =========================================================================
// k_gat300: fused edge score + segment softmax + weighted gather (bf16,
// 8/4/1 unroll) + relu -> out cols 300..599, PLUS r2e score dots AND the
// full r2e h/t softmax-gathers (out cols 600..799) using svh/svt in-wave.
// `out` is the BASE [N,800] pointer.
// =========================================================================
__global__ void k_gat300(const unsigned short* __restrict__ xbf,
                         const float* __restrict__ sA, const float* __restrict__ sB,
                         const float* __restrict__ rsc,
                         const int* __restrict__ jp, const int* __restrict__ relp,
                         const int* __restrict__ rowptr, const int* __restrict__ cnt,
                         float* __restrict__ out, long ldo,
                         const float* __restrict__ ah, const float* __restrict__ at,
                         const unsigned short* __restrict__ xrb,
                         const float* __restrict__ srel,
                         const int* __restrict__ rowptrH, const int* __restrict__ cntH,
                         const int* __restrict__ rowptrT, const int* __restrict__ cntT,
                         int n)
{
    int w = (blockIdx.x*blockDim.x + threadIdx.x) >> 6;
    int lane = threadIdx.x & 63;
    if (w >= n) return;
    int beg = rowptr[w], c = cnt[w];
    const int i0 = lane, i1 = lane + 64, i2 = lane + 128;
    const bool t3 = (lane < 22);
    float2 a0 = {0,0}, a1 = {0,0}, a2 = {0,0};
    if (c > 0) {
        float base = sA[w];
        int   jc = 0;
        float sval = -3.4e38f;
        if (lane < c) {
            jc = jp[beg + lane];
            sval = leaky(base + sB[jc] + rsc[relp[beg + lane]]);
        }
        float mx = sval;
        for (int t = 64 + lane; t < c; t += 64)
            mx = fmaxf(mx, leaky(base + sB[jp[beg+t]] + rsc[relp[beg+t]]));
        #pragma unroll
        for (int o = 32; o > 0; o >>= 1) mx = fmaxf(mx, __shfl_xor(mx, o));
        float pexp = (lane < c) ? expf(sval - mx) : 0.0f;
        float ss = pexp;
        for (int t = 64 + lane; t < c; t += 64)
            ss += expf(leaky(base + sB[jp[beg+t]] + rsc[relp[beg+t]]) - mx);
        #pragma unroll
        for (int o = 32; o > 0; o >>= 1) ss += __shfl_xor(ss, o);
        float inv = 1.0f / (ss + 1e-16f);
        int q = 0;
        int cc = (c < 64) ? c : 64;
        for (; q + 8 <= cc; q += 8) {
            float al[8]; long jj[8];
            #pragma unroll
            for (int u = 0; u < 8; ++u) {
                al[u] = __shfl(pexp, q+u) * inv;
                jj[u] = __shfl(jc, q+u);
            }
            #pragma unroll
            for (int u = 0; u < 8; ++u) {
                float2 v = bfp2f(((const ushort2*)(xbf + jj[u]*XBS))[i0]);
                a0.x += al[u]*v.x; a0.y += al[u]*v.y;
            }
            #pragma unroll
            for (int u = 0; u < 8; ++u) {
                float2 v = bfp2f(((const ushort2*)(xbf + jj[u]*XBS))[i1]);
                a1.x += al[u]*v.x; a1.y += al[u]*v.y;
            }
            if (t3) {
                #pragma unroll
                for (int u = 0; u < 8; ++u) {
                    float2 v = bfp2f(((const ushort2*)(xbf + jj[u]*XBS))[i2]);
                    a2.x += al[u]*v.x; a2.y += al[u]*v.y;
                }
            }
        }
        for (; q + 4 <= cc; q += 4) {
            float al[4]; long jj[4];
            #pragma unroll
            for (int u = 0; u < 4; ++u) {
                al[u] = __shfl(pexp, q+u) * inv;
                jj[u] = __shfl(jc, q+u);
            }
            #pragma unroll
            for (int u = 0; u < 4; ++u) {
                float2 v = bfp2f(((const ushort2*)(xbf + jj[u]*XBS))[i0]);
                a0.x += al[u]*v.x; a0.y += al[u]*v.y;
            }
            #pragma unroll
            for (int u = 0; u < 4; ++u) {
                float2 v = bfp2f(((const ushort2*)(xbf + jj[u]*XBS))[i1]);
                a1.x += al[u]*v.x; a1.y += al[u]*v.y;
            }
            if (t3) {
                #pragma unroll
                for (int u = 0; u < 4; ++u) {
                    float2 v = bfp2f(((const ushort2*)(xbf + jj[u]*XBS))[i2]);
                    a2.x += al[u]*v.x; a2.y += al[u]*v.y;
                }
            }
        }
        for (; q < c; ++q) {
            float al; long j0;
            if (q < 64) { al = __shfl(pexp, q) * inv; j0 = __shfl(jc, q); }
            else {
                j0 = jp[beg + q];
                al = expf(leaky(base + sB[(int)j0] + rsc[relp[beg+q]]) - mx) * inv;
            }
            float2 v;
            v = bfp2f(((const ushort2*)(xbf + j0*XBS))[i0]); a0.x += al*v.x; a0.y += al*v.y;
            v = bfp2f(((const ushort2*)(xbf + j0*XBS))[i1]); a1.x += al*v.x; a1.y += al*v.y;
            if (t3) { v = bfp2f(((const ushort2*)(xbf + j0*XBS))[i2]); a2.x += al*v.x; a2.y += al*v.y; }
        }
    }
    a0.x = fmaxf(a0.x, 0.0f); a0.y = fmaxf(a0.y, 0.0f);
    a1.x = fmaxf(a1.x, 0.0f); a1.y = fmaxf(a1.y, 0.0f);
    a2.x = fmaxf(a2.x, 0.0f); a2.y = fmaxf(a2.y, 0.0f);
    float2* dst = (float2*)(out + 300 + (long)w*ldo);
    dst[i0] = a0; dst[i1] = a1;
    if (t3) dst[i2] = a2;
    // ===== r2e score dots over x6 = [x(0..299) from xbf row w, gat output] =====
    float svh, svt;
    {
        const ushort2* xw = (const ushort2*)(xbf + (long)w*XBS);
        const float2* ahL = (const float2*)ah;
        const float2* atL = (const float2*)at;
        const float2* ahH = (const float2*)(ah + 300);
        const float2* atH = (const float2*)(at + 300);
        float2 x0 = bfp2f(xw[i0]), x1v = bfp2f(xw[i1]);
        svh = x0.x*ahL[i0].x + x0.y*ahL[i0].y + x1v.x*ahL[i1].x + x1v.y*ahL[i1].y
            + a0.x*ahH[i0].x + a0.y*ahH[i0].y + a1.x*ahH[i1].x + a1.y*ahH[i1].y;
        svt = x0.x*atL[i0].x + x0.y*atL[i0].y + x1v.x*atL[i1].x + x1v.y*atL[i1].y
            + a0.x*atH[i0].x + a0.y*atH[i0].y + a1.x*atH[i1].x + a1.y*atH[i1].y;
        if (t3) {
            float2 x2v = bfp2f(xw[i2]);
            svh += x2v.x*ahL[i2].x + x2v.y*ahL[i2].y + a2.x*ahH[i2].x + a2.y*ahH[i2].y;
            svt += x2v.x*atL[i2].x + x2v.y*atL[i2].y + a2.x*atH[i2].x + a2.y*atH[i2].y;
        }
        #pragma unroll
        for (int o = 32; o > 0; o >>= 1) {
            svh += __shfl_down(svh, o);
            svt += __shfl_down(svt, o);
        }
        svh = __shfl(svh, 0);
        svt = __shfl(svt, 0);
    }
    // ===== r2e h/t softmax-gathers (xrb bf16 [R][128], L2-resident) =====
    const bool t0 = (lane < 50);
    auto relgather = [&](float base, const int* rp, const int* ct, int colo) {
        int rbeg = rp[w], rc = ct[w];
        float2 racc = {0,0};
        if (rc > 0) {
            int   idx = 0;
            float sval = -3.4e38f;
            if (lane < rc) {
                idx = relp[rbeg + lane];
                sval = leaky(base + srel[idx]);
            }
            float mx = sval;
            for (int t = 64 + lane; t < rc; t += 64)
                mx = fmaxf(mx, leaky(base + srel[relp[rbeg+t]]));
            #pragma unroll
            for (int o = 32; o > 0; o >>= 1) mx = fmaxf(mx, __shfl_xor(mx, o));
            float pexp = (lane < rc) ? expf(sval - mx) : 0.0f;
            float ss = pexp;
            for (int t = 64 + lane; t < rc; t += 64)
                ss += expf(leaky(base + srel[relp[rbeg+t]]) - mx);
            #pragma unroll
            for (int o = 32; o > 0; o >>= 1) ss += __shfl_xor(ss, o);
            float inv = 1.0f / (ss + 1e-16f);
            int q = 0;
            int cc2 = (rc < 64) ? rc : 64;
            for (; q + 4 <= cc2; q += 4) {
                float al0 = __shfl(pexp, q)   * inv;
                float al1 = __shfl(pexp, q+1) * inv;
                float al2 = __shfl(pexp, q+2) * inv;
                float al3 = __shfl(pexp, q+3) * inv;
                long r0i = __shfl(idx, q), r1i = __shfl(idx, q+1);
                long r2i = __shfl(idx, q+2), r3i = __shfl(idx, q+3);
                if (t0) {
                    float2 v;
                    v = bfp2f(((const ushort2*)(xrb + r0i*128))[lane]); racc.x += al0*v.x; racc.y += al0*v.y;
                    v = bfp2f(((const ushort2*)(xrb + r1i*128))[lane]); racc.x += al1*v.x; racc.y += al1*v.y;
                    v = bfp2f(((const ushort2*)(xrb + r2i*128))[lane]); racc.x += al2*v.x; racc.y += al2*v.y;
                    v = bfp2f(((const ushort2*)(xrb + r3i*128))[lane]); racc.x += al3*v.x; racc.y += al3*v.y;
                }
            }
            for (; q < rc; ++q) {
                float al; long r0i;
                if (q < 64) { al = __shfl(pexp, q) * inv; r0i = __shfl(idx, q); }
                else {
                    r0i = relp[rbeg + q];
                    al = expf(leaky(base + srel[(int)r0i]) - mx) * inv;
                }
                if (t0) {
                    float2 v = bfp2f(((const ushort2*)(xrb + r0i*128))[lane]);
                    racc.x += al*v.x; racc.y += al*v.y;
                }
            }
        }
        if (t0) ((float2*)(out + colo + (long)w*ldo))[lane] = racc;
    };
    relgather(svh, rowptrH, cntH, 600);
    relgather(svt, rowptrT, cntT, 700);
}

// ================= merged l_gat over both line graphs =================
__global__ void k_lgat_max(const float* __restrict__ mval, const float* __restrict__ tval,
                           const int* __restrict__ iM, const int* __restrict__ jM,
                           const int* __restrict__ iT, const int* __restrict__ jT,
                           unsigned* __restrict__ mi, unsigned* __restrict__ mj,
                           int LGE, int R)
{
    int e = blockIdx.x*blockDim.x + threadIdx.x;
    if (e >= 2*LGE) return;
    bool g1 = e >= LGE; int le = g1 ? e - LGE : e;
    float v = g1 ? tval[le] : mval[le];
    int i = (g1 ? iT[le] : iM[le]) + (g1 ? R : 0);
    int j = (g1 ? jT[le] : jM[le]) + (g1 ? R : 0);
    unsigned mv = f2mono(v);
    atomicMax(&mi[i], mv);
    atomicMax(&mj[j], mv);
}
__global__ void k_lgat_sum(const float* __restrict__ mval, const float* __restrict__ tval,
                           const int* __restrict__ iM, const int* __restrict__ jM,
                           const int* __restrict__ iT, const int* __restrict__ jT,
                           const unsigned* __restrict__ mi, const unsigned* __restrict__ mj,
                           float* __restrict__ si, float* __restrict__ sj,
                           int LGE, int R)
{
    int e = blockIdx.x*blockDim.x + threadIdx.x;
    if (e >= 2*LGE) return;
    bool g1 = e >= LGE; int le = g1 ? e - LGE : e;
    float v = g1 ? tval[le] : mval[le];
    int i = (g1 ? iT[le] : iM[le]) + (g1 ? R : 0);
    int j = (g1 ? jT[le] : jM[le]) + (g1 ? R : 0);
    atomicAdd(&si[i], expf(v - mono2f(mi[i])));
    atomicAdd(&sj[j], expf(v - mono2f(mj[j])));
}
// vsum written in CSR-slot order via slotOf
__global__ void k_lgat_vsum2(const float* __restrict__ mval, const float* __restrict__ tval,
                             const int* __restrict__ iM, const int* __restrict__ jM,
                             const int* __restrict__ iT, const int* __restrict__ jT,
                             const unsigned* __restrict__ mi, const float* __restrict__ si,
                             const unsigned* __restrict__ mj, const float* __restrict__ sj,
                             const int* __restrict__ slotOf,
                             float* __restrict__ vsumC, int LGE, int R)
{
    int e = blockIdx.x*blockDim.x + threadIdx.x;
    if (e >= 2*LGE) return;
    bool g1 = e >= LGE; int le = g1 ? e - LGE : e;
    float v = g1 ? tval[le] : mval[le];
    int i = (g1 ? iT[le] : iM[le]) + (g1 ? R : 0);
    int j = (g1 ? jT[le] : jM[le]) + (g1 ? R : 0);
    float pi = expf(v - mono2f(mi[i])) / (si[i] + 1e-16f);
    float pj = expf(v - mono2f(mj[j])) / (sj[j] + 1e-16f);
    vsumC[slotOf[e]] = pi + pj;
}
// stats for second softmax, iterated in CSR order (lgjp has graph offset)
__global__ void k_lgat_max2C(const float* __restrict__ vsumC, const int* __restrict__ lgjp,
                             unsigned* __restrict__ m2, int tot)
{
    int p = blockIdx.x*blockDim.x + threadIdx.x;
    if (p >= tot) return;
    atomicMax(&m2[lgjp[p]], f2mono(vsumC[p]));
}
__global__ void k_lgat_sum2C(const float* __restrict__ vsumC, const int* __restrict__ lgjp,
                             const unsigned* __restrict__ m2, float* __restrict__ s2, int tot)
{
    int p = blockIdx.x*blockDim.x + threadIdx.x;
    if (p >= tot) return;
    int j = lgjp[p];
    atomicAdd(&s2[j], expf(vsumC[p] - mono2f(m2[j])));
}
// GATHER aggregation: wave per output row gw in [0,2R); relu fused.
__global__ void k_lgat_gather(const float* __restrict__ vsumC, const int* __restrict__ lgjp,
                              const unsigned* __restrict__ m2, const float* __restrict__ s2,
                              const int* __restrict__ rowptr, const int* __restrict__ cnt,
                              const float* __restrict__ remb1, const float* __restrict__ remb2,
                              float* __restrict__ obuf, int lgbase, int R, int RH)
{
    int gw = (blockIdx.x*blockDim.x + threadIdx.x) >> 6;
    int lane = threadIdx.x & 63;
    if (gw >= 2*R) return;
    int beg = rowptr[gw] - lgbase, end = beg + cnt[gw];
    float4 acc = {0,0,0,0};
    const bool act = (lane < 25);
    for (int p = beg; p < end; ++p) {
        int j = lgjp[p];
        float alpha = expf(vsumC[p] - mono2f(m2[j])) / (s2[j] + 1e-16f);
        if (act) {
            const float* x = (j < R) ? (remb1 + (long)j*RH) : (remb2 + (long)(j - R)*RH);
            float4 v = ((const float4*)x)[lane];
            acc.x += alpha*v.x; acc.y += alpha*v.y;
            acc.z += alpha*v.z; acc.w += alpha*v.w;
        }
    }
    if (act) {
        acc.x = fmaxf(acc.x, 0.0f); acc.y = fmaxf(acc.y, 0.0f);
        acc.z = fmaxf(acc.z, 0.0f); acc.w = fmaxf(acc.w, 0.0f);
        ((float4*)(obuf + (long)gw*RH))[lane] = acc;
    }
}

// ---------- highway combine (small R x RH path) ----------
__global__ void k_highway(const float* __restrict__ x1, long ld1,
                          const float* __restrict__ gl, long ldg,
                          const float* __restrict__ x2, long ld2,
                          const float* __restrict__ bias,
                          float* __restrict__ out, long ldo,
                          long rows, int F, int relu_x2)
{
    long idx = (long)blockIdx.x*blockDim.x + threadIdx.x;
    if (idx >= rows * (long)F) return;
    long r = idx / F; int c = (int)(idx % F);
    float g = 1.0f / (1.0f + expf(-(gl[r*ldg+c] + bias[c])));
    float v2 = x2[r*ld2+c]; if (relu_x2) v2 = fmaxf(v2, 0.0f);
    float v1 = x1[r*ld1+c];
    out[r*ldo+c] = g*v2 + (1.0f-g)*v1;
}

// merged: waves 0..R-1: rsc[r]; waves R..2R-1: srel[r] + xrb emit
__global__ void k_rs2(const float* __restrict__ mg, const float* __restrict__ tr,
                      const float* __restrict__ ar,
                      const float* __restrict__ xr, const float* __restrict__ g2e_ar,
                      float* __restrict__ rsc, float* __restrict__ srel,
                      unsigned short* __restrict__ xrb, int R, int RH)
{
    int gw = (blockIdx.x*blockDim.x + threadIdx.x) >> 6;
    int lane = threadIdx.x & 63;
    if (gw >= 2*R) return;
    float s = 0.0f;
    if (gw < R) {
        for (int k = lane; k < RH; k += WAVE)
            s += mg[(long)gw*RH+k]*ar[k] + tr[(long)gw*RH+k]*ar[RH+k];
        #pragma unroll
        for (int off = 32; off > 0; off >>= 1) s += __shfl_down(s, off);
        if (lane == 0) rsc[gw] = s;
    } else {
        int r = gw - R;
        #pragma unroll
        for (int t = 0; t < 2; ++t) {
            int k = lane + t*64;
            if (k < RH) {
                float v = xr[(long)r*RH + k];
                s += v * g2e_ar[k];
                xrb[(long)r*128 + k] = f2bf_rne(v);
            }
        }
        #pragma unroll
        for (int off = 32; off > 0; off >>= 1) s += __shfl_down(s, off);
        if (lane == 0) srel[r] = s;
    }
}

extern "C" void kernel_launch(void* const* d_in, const int* in_sizes, int n_in,
                              void* d_out, int out_size, void* d_ws, size_t ws_size,
                              hipStream_t stream)
{
    const float* x_e   = (const float*)d_in[0];
    const float* mval  = (const float*)d_in[1];
    const float* tval  = (const float*)d_in[2];
    const float* g1w   = (const float*)d_in[3];
    const float* h1w   = (const float*)d_in[4];
    const float* h1b   = (const float*)d_in[5];
    const float* g2w   = (const float*)d_in[6];
    const float* h2w   = (const float*)d_in[7];
    const float* h2b   = (const float*)d_in[8];
    const float* remb1 = (const float*)d_in[9];
    const float* remb2 = (const float*)d_in[10];
    const float* hrw   = (const float*)d_in[11];
    const float* hrb   = (const float*)d_in[12];
    const float* gat_ai= (const float*)d_in[13];
    const float* gat_aj= (const float*)d_in[14];
    const float* gat_ar= (const float*)d_in[15];
    const float* g2e_ah= (const float*)d_in[16];
    const float* g2e_at= (const float*)d_in[17];
    const float* g2e_ar= (const float*)d_in[18];
    const int* edge_index     = (const int*)d_in[19];
    const int* rel            = (const int*)d_in[20];
    const int* edge_index_all = (const int*)d_in[21];
    const int* rel_all        = (const int*)d_in[22];
    const int* lg_merge       = (const int*)d_in[23];
    const int* lg_tri         = (const int*)d_in[24];

    const int F    = 300;
    const int RH   = 100;
    const int Kp   = 304;
    const int npk  = Kp / 16;              // 19
    const int N    = in_sizes[0] / F;      // 100000
    const int E    = in_sizes[20];         // 400000
    const int EA   = in_sizes[22];         // 800000
    const int LGE  = in_sizes[1];          // 60000
    const int R    = in_sizes[9] / RH;     // 2000
    const long OUTC = 800;
    const int Mpad = CDIV(N, 128) * 128;
    const int NB   = 640;
    const long LDC = 640;

    const int* jA = edge_index_all;
    const int* iA = edge_index_all + EA;
    const int* hE = edge_index;
    const int* tE = edge_index + E;
    const int* jM = lg_merge;  const int* iM = lg_merge + LGE;
    const int* jT = lg_tri;    const int* iT = lg_tri  + LGE;

    float* ws = (float*)d_ws;
    size_t off = 0;
    auto alloc = [&](size_t n) { float* p = ws + off; off += (n + 15) & ~(size_t)15; return p; };
    unsigned short* Ascr = (unsigned short*)alloc((size_t)N*NB/2);
    unsigned short* Axb = (unsigned short*)alloc((size_t)Mpad*Kp/2);
    unsigned short* xbf = (unsigned short*)alloc((size_t)N*XBS/2);
    unsigned short* Wb  = (unsigned short*)alloc((size_t)2*NB*Kp/2);
    unsigned short* W0 = Wb;
    unsigned short* W1 = Wb + (size_t)NB*Kp;
    unsigned short* xrb = (unsigned short*)alloc((size_t)R*128/2);
    float*    sA_  = alloc(N);
    float*    sB_  = alloc(N);
    float*    xr   = alloc((size_t)R*RH);
    float*    xrg  = alloc((size_t)R*RH);
    float*    lg   = alloc((size_t)12*R + (size_t)2*R*RH);
    unsigned* lmi  = (unsigned*)lg;          float* lsi = lg + 2*R;
    unsigned* lmj  = (unsigned*)(lg + 4*R);  float* lsj = lg + 6*R;
    unsigned* lm2  = (unsigned*)(lg + 8*R);  float* ls2 = lg + 10*R;
    float*    obuf = lg + 12*R;              // [2R][RH]: mrg then tri
    float*    mrg  = obuf;
    float*    tri  = obuf + (size_t)R*RH;
    float*    vsumC = alloc((size_t)2*LGE);
    float*    rsc  = alloc(R);
    float*    srel = alloc(R);
    int*   bsum    = (int*)alloc(1024);
    const int NR   = 3*N + 2*R;
    int*   cntAll  = (int*)alloc((size_t)2*NR);
    int*   curAll  = cntAll + NR;
    int*   rowptrG = (int*)alloc((size_t)NR);
    int*   relpAll = (int*)alloc((size_t)EA + 2*E);
    int*   jpA     = (int*)alloc(EA);
    float* nmA     = alloc(EA);
    int*   lgjp    = (int*)alloc((size_t)2*LGE);
    int*   slotOf  = (int*)alloc((size_t)2*LGE);

    float* out = (float*)d_out;              // [N, 800]

    const int  nrb = CDIV(N, 128);
    const int  gemmBlocks = 8 * CDIV(nrb, 8) * 5;
    const int  gatherGrid = CDIV(N, 4);
    const int  cvtBigGrid = CDIV((long)N * (Kp/4), 256);
    const int  cvtW4Grid  = CDIV((long)4 * 300 * (Kp/4), 256);
    const int  ETOT = EA + 2*E + 2*LGE;
    const int  lgbase = EA + 2*E;
    const int  nbNR = CDIV(NR, 512);

    // ===== converts (weights merged + x_e), pads zeroed =====
    hipMemsetAsync(Wb, 0, (size_t)2*NB*Kp*2, stream);
    hipMemsetAsync(Axb + (size_t)N*Kp, 0, (size_t)(Mpad-N)*Kp*2, stream);
    k_cvt_w4<<<cvtW4Grid,256,0,stream>>>(g1w, h1w, g2w, h2w, npk, W0, W1);
    k_cvt_pack1<<<cvtBigGrid,256,0,stream>>>(x_e, 300, N, 300, npk, 0, Axb);

    // ===== merged CSR build (A, H, T, LG-M, LG-T) with fused placement =====
    hipMemsetAsync(cntAll, 0, (size_t)2*NR*4, stream);
    k_hist5<<<CDIV(ETOT,256),256,0,stream>>>(iA, hE, tE, iM, iT, cntAll, EA, E, LGE, N, R);
    k_scan1<<<nbNR,512,0,stream>>>(cntAll, rowptrG, bsum, NR);
    k_scan2<<<1,1024,0,stream>>>(bsum, nbNR);
    k_scan3<<<nbNR,512,0,stream>>>(rowptrG, bsum, NR);
    k_fill5f<<<CDIV(ETOT,256),256,0,stream>>>(iA, jA, hE, tE, iM, jM, iT, jT, rel_all, rel,
                                              rowptrG, cntAll, curAll,
                                              jpA, nmA, relpAll, lgjp, slotOf,
                                              EA, E, LGE, N, R, lgbase);

    // ===== GCN layer 1 =====
    k_gemm_frag<<<gemmBlocks,256,0,stream>>>(Axb, W0, Ascr, LDC, N, 620, npk, nrb);
    k_gather_hw<<<gatherGrid,256,0,stream>>>(Ascr, LDC, Ascr+320,
                                             x_e, (const unsigned short*)nullptr, h1b,
                                             jpA, nmA, rowptrG, cntAll,
                                             (float*)nullptr, OUTC, Axb, xbf,
                                             (const float*)nullptr, (const float*)nullptr,
                                             (float*)nullptr, (float*)nullptr, npk, N);

    // ===== GCN layer 2 =====
    k_gemm_frag<<<gemmBlocks,256,0,stream>>>(Axb, W1, Ascr, LDC, N, 620, npk, nrb);
    k_gather_hw<<<gatherGrid,256,0,stream>>>(Ascr, LDC, Ascr+320,
                                             (const float*)nullptr, xbf, h2b,
                                             jpA, nmA, rowptrG, cntAll,
                                             out, OUTC, (unsigned short*)nullptr, xbf,
                                             gat_ai, gat_aj, sA_, sB_, npk, N);

    // ===== merged l_gat (stats atomics + CSR gather aggregation) =====
    hipMemsetAsync(lg, 0, (size_t)12*R*4, stream);
    const int lgGrid = CDIV(2*LGE, 256);
    k_lgat_max  <<<lgGrid,256,0,stream>>>(mval, tval, iM, jM, iT, jT, lmi, lmj, LGE, R);
    k_lgat_sum  <<<lgGrid,256,0,stream>>>(mval, tval, iM, jM, iT, jT, lmi, lmj, lsi, lsj, LGE, R);
    k_lgat_vsum2<<<lgGrid,256,0,stream>>>(mval, tval, iM, jM, iT, jT, lmi, lsi, lmj, lsj,
                                          slotOf, vsumC, LGE, R);
    k_lgat_max2C<<<lgGrid,256,0,stream>>>(vsumC, lgjp, lm2, 2*LGE);
    k_lgat_sum2C<<<lgGrid,256,0,stream>>>(vsumC, lgjp, lm2, ls2, 2*LGE);
    k_lgat_gather<<<CDIV(2*R*64,256),256,0,stream>>>(vsumC, lgjp, lm2, ls2,
                                                     rowptrG + 3*N, cntAll + 3*N,
                                                     remb1, remb2, obuf, lgbase, R, RH);

    // ===== x_r = highway(mrg, tri, hrw, hrb) =====
    dim3 gridR(CDIV(RH,GBN), CDIV(R,GBM));
    k_gemm<<<gridR,256,0,stream>>>(mrg, RH, hrw, RH, xrg, RH, R, RH, RH);
    k_highway<<<CDIV((long)R*RH,256),256,0,stream>>>(mrg, RH, xrg, RH, tri, RH, hrb, xr, RH, R, RH, 0);

    // merged relscore + srel (+ xrb emit)
    k_rs2<<<CDIV((long)2*R*64,256),256,0,stream>>>(mrg, tri, gat_ar, xr, g2e_ar,
                                                   rsc, srel, xrb, R, RH);

    // ===== GAT (cols 300..599) + full r2e (cols 600..799), single kernel =====
    k_gat300<<<gatherGrid,256,0,stream>>>(xbf, sA_, sB_, rsc, jpA, relpAll,
                                          rowptrG, cntAll, out, OUTC,
                                          g2e_ah, g2e_at,
                                          xrb, srel,
                                          rowptrG + N, cntAll + N,
                                          rowptrG + 2*N, cntAll + 2*N, N);
}